// Round 5
// baseline (1413.723 us; speedup 1.0000x reference)
//
#include <hip/hip_runtime.h>
#include <math.h>

typedef unsigned short u16;
typedef unsigned int   u32;
typedef __attribute__((ext_vector_type(8))) unsigned short ushort8;
typedef __attribute__((ext_vector_type(8))) short short8v;   // 8 bf16 (4 VGPRs)
typedef __attribute__((ext_vector_type(4))) float f32x4;

__device__ __forceinline__ float gelu_f(float x) {
    const float c = 0.7978845608028654f;   // sqrt(2/pi)
    float x3 = x * x * x;
    float t = tanhf(c * (x + 0.044715f * x3));
    return 0.5f * x * (1.0f + t);
}

// f32 -> bf16 RNE
__device__ __forceinline__ u16 f2b(float f) {
    u32 u = __float_as_uint(f);
    return (u16)((u + 0x7FFFu + ((u >> 16) & 1u)) >> 16);
}

// split f32 -> bf16 hi + bf16 lo (hi+lo ~ 16-bit mantissa)
__device__ __forceinline__ void split_bf16(float f, u16& h, u16& l) {
    u32 u = __float_as_uint(f);
    u32 r = (u + 0x7FFFu + ((u >> 16) & 1u)) >> 16;
    h = (u16)r;
    float hf = __uint_as_float(r << 16);
    float d = f - hf;
    u32 u2 = __float_as_uint(d);
    l = (u16)((u2 + 0x7FFFu + ((u2 >> 16) & 1u)) >> 16);
}

// ---------------------------------------------------------------------------
// zero-fill kernels (graph-capture-safe)
// ---------------------------------------------------------------------------
__global__ __launch_bounds__(256) void zero_f32(float* __restrict__ p, size_t n) {
    size_t i = (size_t)blockIdx.x * 256 + threadIdx.x;
    size_t st = (size_t)gridDim.x * 256;
    for (; i < n; i += st) p[i] = 0.0f;
}
__global__ __launch_bounds__(256) void zero_i32(int* __restrict__ p, int n) {
    int i = blockIdx.x * 256 + threadIdx.x;
    if (i < n) p[i] = 0;
}

// ---------------------------------------------------------------------------
// Weight pre-pass: transpose [K][N] f32 -> [N][K] split bf16 hi/lo
// ---------------------------------------------------------------------------
struct TEntry { const float* src; u16* dh; u16* dl; int K; int N; };
struct TDesc  { TEntry e[29]; };

__global__ __launch_bounds__(256) void transpose_split(TDesc desc) {
    __shared__ float tile[32][33];
    TEntry en = desc.e[blockIdx.y];
    int tk = en.K >> 5, tn = en.N >> 5;
    int bx = blockIdx.x;
    if (bx >= tk * tn) return;
    int k0 = (bx % tk) * 32, n0 = (bx / tk) * 32;
    int tx = threadIdx.x & 31, ty = threadIdx.x >> 5;   // 32 x 8
    #pragma unroll
    for (int yy = 0; yy < 32; yy += 8)
        tile[ty + yy][tx] = en.src[(size_t)(k0 + ty + yy) * en.N + (n0 + tx)];
    __syncthreads();
    #pragma unroll
    for (int yy = 0; yy < 32; yy += 8) {
        int n = n0 + ty + yy, k = k0 + tx;
        float f = tile[tx][ty + yy];
        u16 h, l;
        split_bf16(f, h, l);
        en.dh[(size_t)n * en.K + k] = h;
        en.dl[(size_t)n * en.K + k] = l;
    }
}

// ---------------------------------------------------------------------------
// RBF lookup table: table[k][m] = sum_r sin(d_k*(r+1)*pi/6)/d_k * env(d_k) *
// W_rbf[r][m], d_k = k*6/4096, k in [0,4096]. One table per layer.
// ---------------------------------------------------------------------------
__global__ __launch_bounds__(128) void build_rbf_table(
    const float* __restrict__ Wrbf_l, float* __restrict__ table)
{
    int k = blockIdx.x, m = threadIdx.x;
    const float PI = 3.14159265358979323846f;
    float d = fmaxf((float)k * (6.0f / 4096.0f), 1e-9f);
    float th = d * (PI / 6.0f);
    float s1, c1;
    __sincosf(th, &s1, &c1);
    float env = 0.5f * c1 + 0.5f;
    float invd = 1.0f / d;
    float two_c = 2.0f * c1;
    float sp = 0.f, sc = s1, dot = 0.f;
    #pragma unroll
    for (int r = 0; r < 32; ++r) {
        dot = fmaf(sc, Wrbf_l[r * 128 + m], dot);
        float sn = fmaf(two_c, sc, -sp);
        sp = sc; sc = sn;
    }
    table[(size_t)k * 128 + m] = dot * invd * env;
}

// ---------------------------------------------------------------------------
// MFMA GEMM: C[M,N] = act(A[M,K] @ B[K,N] (+bias)), optional += (ACCUM)
// A f32 row-major (converted to bf16 in staging); B pre-transposed + split:
// BH/BL are [N][K] bf16.  C ~= A_bf16 * (Bh + Bl).
// Block tile 128x128, BK=32, 256 threads = 4 waves, 64x64 per wave.
// Requires K%32==0, N%128==0; M guarded.
// ---------------------------------------------------------------------------
template<bool ACCUM, bool BIAS, bool DOGELU>
__global__ __launch_bounds__(256) void mfma_gemm(
    const float* __restrict__ A, const u16* __restrict__ BH,
    const u16* __restrict__ BL, const float* __restrict__ bias,
    float* __restrict__ C, int Mrows, int K, int Nc)
{
    __shared__ __align__(16) u16 sA [128][40];
    __shared__ __align__(16) u16 sBh[128][40];
    __shared__ __align__(16) u16 sBl[128][40];

    const int t = threadIdx.x;
    const int lane = t & 63, wid = t >> 6;
    const int r0 = blockIdx.y * 128, c0 = blockIdx.x * 128;
    const int wr = (wid >> 1) * 64, wc = (wid & 1) * 64;

    f32x4 acc[4][4] = {};

    const int srow = t >> 1;            // staging row 0..127
    const int skc  = (t & 1) * 16;      // staging k-offset 0/16

    for (int k0 = 0; k0 < K; k0 += 32) {
        // ---- stage A (f32 -> bf16) ----
        {
            int gr = r0 + srow;
            float v[16];
            if (gr < Mrows) {
                const float* p = A + (size_t)gr * K + (k0 + skc);
                float4 q0 = *(const float4*)(p + 0);
                float4 q1 = *(const float4*)(p + 4);
                float4 q2 = *(const float4*)(p + 8);
                float4 q3 = *(const float4*)(p + 12);
                v[0]=q0.x; v[1]=q0.y; v[2]=q0.z; v[3]=q0.w;
                v[4]=q1.x; v[5]=q1.y; v[6]=q1.z; v[7]=q1.w;
                v[8]=q2.x; v[9]=q2.y; v[10]=q2.z; v[11]=q2.w;
                v[12]=q3.x; v[13]=q3.y; v[14]=q3.z; v[15]=q3.w;
            } else {
                #pragma unroll
                for (int j = 0; j < 16; ++j) v[j] = 0.f;
            }
            ushort8 h0, h1;
            #pragma unroll
            for (int j = 0; j < 8; ++j) h0[j] = f2b(v[j]);
            #pragma unroll
            for (int j = 0; j < 8; ++j) h1[j] = f2b(v[8 + j]);
            *(ushort8*)&sA[srow][skc]     = h0;
            *(ushort8*)&sA[srow][skc + 8] = h1;
        }
        // ---- stage B (already split, copy) ----
        {
            int cg = c0 + srow;
            const u16* ph = BH + (size_t)cg * K + (k0 + skc);
            const u16* pl = BL + (size_t)cg * K + (k0 + skc);
            *(ushort8*)&sBh[srow][skc]     = *(const ushort8*)(ph);
            *(ushort8*)&sBh[srow][skc + 8] = *(const ushort8*)(ph + 8);
            *(ushort8*)&sBl[srow][skc]     = *(const ushort8*)(pl);
            *(ushort8*)&sBl[srow][skc + 8] = *(const ushort8*)(pl + 8);
        }
        __syncthreads();

        // ---- compute: wave tile 64x64 = 4x4 fragments of 16x16, K=32 ----
        const int arow = wr + (lane & 15);
        const int koff = (lane >> 4) * 8;
        short8v ah[4];
        #pragma unroll
        for (int fr = 0; fr < 4; ++fr)
            ah[fr] = *(const short8v*)&sA[arow + fr * 16][koff];
        #pragma unroll
        for (int fc = 0; fc < 4; ++fc) {
            int bcol = wc + fc * 16 + (lane & 15);
            short8v bh = *(const short8v*)&sBh[bcol][koff];
            short8v bl = *(const short8v*)&sBl[bcol][koff];
            #pragma unroll
            for (int fr = 0; fr < 4; ++fr) {
                acc[fr][fc] = __builtin_amdgcn_mfma_f32_16x16x32_bf16(ah[fr], bh, acc[fr][fc], 0, 0, 0);
                acc[fr][fc] = __builtin_amdgcn_mfma_f32_16x16x32_bf16(ah[fr], bl, acc[fr][fc], 0, 0, 0);
            }
        }
        __syncthreads();
    }

    // ---- epilogue: C/D layout col=lane&15, row=(lane>>4)*4+reg ----
    #pragma unroll
    for (int fr = 0; fr < 4; ++fr) {
        int rbase = r0 + wr + fr * 16 + (lane >> 4) * 4;
        #pragma unroll
        for (int fc = 0; fc < 4; ++fc) {
            int col = c0 + wc + fc * 16 + (lane & 15);
            #pragma unroll
            for (int reg = 0; reg < 4; ++reg) {
                int gr = rbase + reg;
                if (gr >= Mrows) continue;
                float v = acc[fr][fc][reg];
                if (BIAS)   v += bias[col];
                if (DOGELU) v = gelu_f(v);
                float* pc = C + (size_t)gr * Nc + col;
                if (ACCUM)  v += *pc;
                *pc = v;
            }
        }
    }
}

// ---------------------------------------------------------------------------
// CSR construction
// ---------------------------------------------------------------------------
__global__ void hist_edges(const int* __restrict__ ei, int* __restrict__ deg, int E_) {
    int e = blockIdx.x * 256 + threadIdx.x;
    if (e < E_) atomicAdd(&deg[ei[E_ + e]], 1);   // dst row
}
__global__ void hist_nodes(const int* __restrict__ batch, int* __restrict__ gcnt, int n) {
    int i = blockIdx.x * 256 + threadIdx.x;
    if (i < n) atomicAdd(&gcnt[batch[i]], 1);
}

__global__ __launch_bounds__(1024) void scan_kernel(
    const int* __restrict__ cnt, int n, int* __restrict__ out, int* __restrict__ cursor)
{
    __shared__ int part[1024];
    int t = threadIdx.x;
    int chunk = (n + 1023) / 1024;
    int base = t * chunk;
    int s = 0;
    for (int k = 0; k < chunk; ++k) { int i = base + k; if (i < n) s += cnt[i]; }
    part[t] = s;
    __syncthreads();
    for (int off = 1; off < 1024; off <<= 1) {
        int u = (t >= off) ? part[t - off] : 0;
        __syncthreads();
        part[t] += u;
        __syncthreads();
    }
    int run = part[t] - s;
    for (int k = 0; k < chunk; ++k) {
        int i = base + k;
        if (i < n) {
            out[i] = run;
            if (cursor) cursor[i] = run;
            run += cnt[i];
        }
    }
    if (t == 1023) out[n] = part[1023];
}

__global__ void scatter_kernel(const int* __restrict__ ei, int* __restrict__ cursor,
                               int* __restrict__ perm, int E_) {
    int e = blockIdx.x * 256 + threadIdx.x;
    if (e < E_) {
        int p = atomicAdd(&cursor[ei[E_ + e]], 1);
        perm[p] = e;
    }
}

// ---------------------------------------------------------------------------
// Edge geometry: distance + unit vector
// ---------------------------------------------------------------------------
__global__ __launch_bounds__(256) void geom_kernel(
    const float* __restrict__ pos, const int* __restrict__ ei,
    float* __restrict__ dist, float* __restrict__ unitv, int E_)
{
    int e = blockIdx.x * 256 + threadIdx.x;
    if (e >= E_) return;
    int s = ei[e], dn = ei[E_ + e];
    float dx = pos[s * 3 + 0] - pos[dn * 3 + 0];
    float dy = pos[s * 3 + 1] - pos[dn * 3 + 1];
    float dz = pos[s * 3 + 2] - pos[dn * 3 + 2];
    float d = sqrtf(dx * dx + dy * dy + dz * dz + 1e-12f);
    float invd = 1.0f / d;
    dist[e] = d;
    unitv[(size_t)e * 3 + 0] = dx * invd;
    unitv[(size_t)e * 3 + 1] = dy * invd;
    unitv[(size_t)e * 3 + 2] = dz * invd;
}

// ---------------------------------------------------------------------------
// h init: concat(emb[z], pos) @ W_in + b_in
// ---------------------------------------------------------------------------
__global__ __launch_bounds__(256) void init_h_kernel(
    const int* __restrict__ z, const float* __restrict__ pos,
    const float* __restrict__ emb, const float* __restrict__ W_in,
    const float* __restrict__ b_in, float* __restrict__ h)
{
    int i = blockIdx.x, d = threadIdx.x;
    float acc = b_in[d];
    int zi = z[i];
    #pragma unroll 8
    for (int k = 0; k < 32; ++k)
        acc += emb[zi * 32 + k] * W_in[k * 256 + d];
    #pragma unroll
    for (int x = 0; x < 3; ++x)
        acc += pos[i * 3 + x] * W_in[(32 + x) * 256 + d];
    h[(size_t)i * 256 + d] = acc;
}

// ---------------------------------------------------------------------------
// Per-dst-node edge attention, online softmax. Block = dst node,
// 128 threads = message channels, head = m/32.
// ew from per-layer lookup table (lerp); uniform loads via readfirstlane.
// ---------------------------------------------------------------------------
__global__ __launch_bounds__(128) void edge_attn_kernel(
    const int* __restrict__ rowptr, const int* __restrict__ perm,
    const int* __restrict__ ei,
    const float* __restrict__ qkv,
    const float* __restrict__ dist, const float* __restrict__ unitv,
    const float* __restrict__ table_l,
    float* __restrict__ msg, float* __restrict__ U)
{
    int m = threadIdx.x;
    int i = blockIdx.x;

    int p0 = rowptr[i], p1 = rowptr[i + 1];
    float q = qkv[(size_t)i * 384 + m];
    float Mx = -1e30f, S = 0.f, am = 0.f, a0 = 0.f, a1 = 0.f, a2 = 0.f;

    if (p0 < p1) {
        int e = __builtin_amdgcn_readfirstlane(perm[p0]);
        for (int p = p0; p < p1; ++p) {
            int enext = (p + 1 < p1) ? perm[p + 1] : e;
            int j = __builtin_amdgcn_readfirstlane(ei[e]);
            float kv = qkv[(size_t)j * 384 + 128 + m];
            float vv = qkv[(size_t)j * 384 + 256 + m];
            float d  = dist[e];
            float ux = unitv[(size_t)e * 3 + 0];
            float uy = unitv[(size_t)e * 3 + 1];
            float uz = unitv[(size_t)e * 3 + 2];

            float pr = q * kv;
            #pragma unroll
            for (int off = 16; off; off >>= 1) pr += __shfl_xor(pr, off);
            float logit = pr * 0.1767766952966369f;   // 1/sqrt(32)

            float ew = 0.f;
            if (d < 6.0f) {
                float x = d * (4096.0f / 6.0f);
                int b = (int)x;
                float tf = x - (float)b;
                float f0 = table_l[(size_t)b * 128 + m];
                float f1 = table_l[(size_t)(b + 1) * 128 + m];
                ew = fmaf(tf, f1 - f0, f0);
            }

            float vve = vv * ew;
            float nM = fmaxf(Mx, logit);
            float scale = __expf(Mx - nM);
            float w = __expf(logit - nM);
            S = S * scale + w;
            float wv = w * vve;
            am = am * scale + wv;
            a0 = a0 * scale + wv * ux;
            a1 = a1 * scale + wv * uy;
            a2 = a2 * scale + wv * uz;
            Mx = nM;
            e = __builtin_amdgcn_readfirstlane(enext);
        }
    }
    float inv = 1.0f / (S + 1e-12f);
    msg[(size_t)i * 128 + m] = am * inv;
    U[((size_t)i * 3 + 0) * 128 + m] = a0 * inv;
    U[((size_t)i * 3 + 1) * 128 + m] = a1 * inv;
    U[((size_t)i * 3 + 2) * 128 + m] = a2 * inv;
}

// ---------------------------------------------------------------------------
// vnorm[i,d] = sqrt(sum_xyz vfeat[i,x,d]^2 + 1e-8)
// ---------------------------------------------------------------------------
__global__ __launch_bounds__(256) void vnorm_kernel(
    const float* __restrict__ vfeat, float* __restrict__ vn)
{
    int i = blockIdx.x, d = threadIdx.x;
    float v0 = vfeat[((size_t)i * 3 + 0) * 256 + d];
    float v1 = vfeat[((size_t)i * 3 + 1) * 256 + d];
    float v2 = vfeat[((size_t)i * 3 + 2) * 256 + d];
    vn[(size_t)i * 256 + d] = sqrtf(v0 * v0 + v1 * v1 + v2 * v2 + 1e-8f);
}

// ---------------------------------------------------------------------------
// h = layernorm(h + add) * gamma
// ---------------------------------------------------------------------------
__global__ __launch_bounds__(256) void ln_kernel(
    float* __restrict__ h, const float* __restrict__ add, const float* __restrict__ gamma_l)
{
    __shared__ float lds[4];
    int i = blockIdx.x, d = threadIdx.x;
    size_t idx = (size_t)i * 256 + d;
    float x = h[idx] + add[idx];
    float s = x;
    #pragma unroll
    for (int off = 32; off; off >>= 1) s += __shfl_xor(s, off);
    if ((d & 63) == 0) lds[d >> 6] = s;
    __syncthreads();
    float mu = (lds[0] + lds[1] + lds[2] + lds[3]) * (1.0f / 256.0f);
    __syncthreads();
    float xc = x - mu;
    float v = xc * xc;
    #pragma unroll
    for (int off = 32; off; off >>= 1) v += __shfl_xor(v, off);
    if ((d & 63) == 0) lds[d >> 6] = v;
    __syncthreads();
    float var = (lds[0] + lds[1] + lds[2] + lds[3]) * (1.0f / 256.0f);
    h[idx] = xc * rsqrtf(var + 1e-5f) * gamma_l[d];
}

// ---------------------------------------------------------------------------
// Graph pooling: softmax(h @ w_att) weighted sum per graph (batch sorted)
// ---------------------------------------------------------------------------
__global__ __launch_bounds__(256) void pool_kernel(
    const float* __restrict__ h, const float* __restrict__ w_att,
    const int* __restrict__ gptr, float* __restrict__ pooled)
{
    __shared__ float lds[4];
    int g = blockIdx.x, d = threadIdx.x;
    float wa = w_att[d];
    int n0 = gptr[g], n1 = gptr[g + 1];
    float M = -1e30f, S = 0.f, acc = 0.f;
    for (int i = n0; i < n1; ++i) {
        float hv = h[(size_t)i * 256 + d];
        float p = hv * wa;
        #pragma unroll
        for (int off = 32; off; off >>= 1) p += __shfl_xor(p, off);
        if ((d & 63) == 0) lds[d >> 6] = p;
        __syncthreads();
        float logit = lds[0] + lds[1] + lds[2] + lds[3];
        __syncthreads();
        float nM = fmaxf(M, logit);
        float sc = __expf(M - nM);
        float w  = __expf(logit - nM);
        S = S * sc + w;
        acc = acc * sc + w * hv;
        M = nM;
    }
    pooled[(size_t)g * 256 + d] = acc / (S + 1e-12f);
}

// ---------------------------------------------------------------------------
extern "C" void kernel_launch(void* const* d_in, const int* in_sizes, int n_in,
                              void* d_out, int out_size, void* d_ws, size_t ws_size,
                              hipStream_t stream)
{
    const float* pos   = (const float*)d_in[0];
    const int*   z     = (const int*)d_in[1];
    const int*   batch = (const int*)d_in[2];
    const int*   ei    = (const int*)d_in[3];
    const float* emb   = (const float*)d_in[4];
    const float* W_in  = (const float*)d_in[5];
    const float* b_in  = (const float*)d_in[6];
    const float* Wq    = (const float*)d_in[7];
    const float* Wk    = (const float*)d_in[8];
    const float* Wv    = (const float*)d_in[9];
    const float* W_rbf = (const float*)d_in[10];
    const float* W_msg = (const float*)d_in[11];
    const float* W_vg  = (const float*)d_in[12];
    const float* W_vs  = (const float*)d_in[13];
    const float* W_nd  = (const float*)d_in[14];
    const float* b_nd  = (const float*)d_in[15];
    const float* gam   = (const float*)d_in[16];
    const float* watt  = (const float*)d_in[17];
    const float* W_out = (const float*)d_in[18];
    const float* b_out = (const float*)d_in[19];

    const int N = in_sizes[0] / 3;      // 20000
    const int E = in_sizes[3] / 2;      // 320000
    const int G = out_size / 512;       // 500

    char* ws = (char*)d_ws;
    size_t o = 0;
    auto alloc = [&](size_t bytes) -> char* {
        o = (o + 255) & ~(size_t)255;
        char* r = ws + o;
        o += bytes;
        return r;
    };
    float* f_dist  = (float*)alloc((size_t)E * 4);
    float* f_unit  = (float*)alloc((size_t)E * 3 * 4);
    float* f_h     = (float*)alloc((size_t)N * 256 * 4);
    float* f_vf    = (float*)alloc((size_t)N * 3 * 256 * 4);
    float* f_qkv   = (float*)alloc((size_t)N * 384 * 4);
    float* f_msg   = (float*)alloc((size_t)N * 128 * 4);
    float* f_U     = (float*)alloc((size_t)N * 3 * 128 * 4);
    float* f_pool  = (float*)alloc((size_t)G * 256 * 4);
    float* f_table = (float*)alloc((size_t)4 * 4097 * 128 * 4);   // 8.4 MB
    // split weights per layer {qkvT 384x256, vgT 256x128, msgT 256x128,
    //                          ndT 256x256, vsT 256x256} + global outT 512x256
    const size_t LS = 384 * 256 + 2 * (256 * 128) + 2 * (256 * 256);   // 294912
    const size_t OFF_QKV = 0, OFF_VG = 384 * 256, OFF_MSG = OFF_VG + 256 * 128,
                 OFF_ND = OFF_MSG + 256 * 128, OFF_VS = OFF_ND + 256 * 256;
    const size_t OFF_OUT = LS * 4;     // after the 4 layers
    u16* whi = (u16*)alloc((LS * 4 + 512 * 256) * sizeof(u16));
    u16* wlo = (u16*)alloc((LS * 4 + 512 * 256) * sizeof(u16));
    int* i_deg  = (int*)alloc((size_t)N * 4);
    int* i_rowp = (int*)alloc((size_t)(N + 1) * 4);
    int* i_cur  = (int*)alloc((size_t)(N + 1) * 4);
    int* i_perm = (int*)alloc((size_t)E * 4);
    int* i_gcnt = (int*)alloc((size_t)G * 4);
    int* i_gptr = (int*)alloc((size_t)(G + 1) * 4);

    // aliases over dead regions:
    float* f_b1 = f_U;      // [N,256]: written after U consumed by vgate GEMM
    float* f_b2 = f_qkv;    // [N,256]: written after qkv consumed by edge_attn

    // ---- weight pre-pass descriptor ----
    TDesc td;
    int idx = 0;
    for (int l = 0; l < 4; ++l) {
        u16* bh = whi + (size_t)l * LS;
        u16* bl = wlo + (size_t)l * LS;
        td.e[idx++] = { Wq   + (size_t)l * 256 * 128, bh + OFF_QKV,             bl + OFF_QKV,             256, 128 };
        td.e[idx++] = { Wk   + (size_t)l * 256 * 128, bh + OFF_QKV + 128 * 256, bl + OFF_QKV + 128 * 256, 256, 128 };
        td.e[idx++] = { Wv   + (size_t)l * 256 * 128, bh + OFF_QKV + 256 * 256, bl + OFF_QKV + 256 * 256, 256, 128 };
        td.e[idx++] = { W_vg + (size_t)l * 128 * 256, bh + OFF_VG,  bl + OFF_VG,  128, 256 };
        td.e[idx++] = { W_msg+ (size_t)l * 128 * 256, bh + OFF_MSG, bl + OFF_MSG, 128, 256 };
        td.e[idx++] = { W_nd + (size_t)l * 256 * 256, bh + OFF_ND,  bl + OFF_ND,  256, 256 };
        td.e[idx++] = { W_vs + (size_t)l * 256 * 256, bh + OFF_VS,  bl + OFF_VS,  256, 256 };
    }
    td.e[idx++] = { W_out, whi + OFF_OUT, wlo + OFF_OUT, 256, 512 };

    // ---- setup ----
    zero_i32<<<(N + 255) / 256, 256, 0, stream>>>(i_deg, N);
    zero_i32<<<(G + 255) / 256, 256, 0, stream>>>(i_gcnt, G);
    zero_f32<<<2048, 256, 0, stream>>>(f_vf, (size_t)N * 3 * 256);
    transpose_split<<<dim3(128, 29), 256, 0, stream>>>(td);
    for (int l = 0; l < 4; ++l)
        build_rbf_table<<<4097, 128, 0, stream>>>(
            W_rbf + (size_t)l * 32 * 128, f_table + (size_t)l * 4097 * 128);

    hist_edges<<<(E + 255) / 256, 256, 0, stream>>>(ei, i_deg, E);
    scan_kernel<<<1, 1024, 0, stream>>>(i_deg, N, i_rowp, i_cur);
    scatter_kernel<<<(E + 255) / 256, 256, 0, stream>>>(ei, i_cur, i_perm, E);
    hist_nodes<<<(N + 255) / 256, 256, 0, stream>>>(batch, i_gcnt, N);
    scan_kernel<<<1, 1024, 0, stream>>>(i_gcnt, G, i_gptr, (int*)nullptr);
    geom_kernel<<<(E + 255) / 256, 256, 0, stream>>>(pos, ei, f_dist, f_unit, E);
    init_h_kernel<<<N, 256, 0, stream>>>(z, pos, emb, W_in, b_in, f_h);

    const int MB  = (N + 127) / 128;          // 157
    const int MB3 = (3 * N + 127) / 128;      // 469

    // ---- layers ----
    for (int l = 0; l < 4; ++l) {
        u16* bh = whi + (size_t)l * LS;
        u16* bl = wlo + (size_t)l * LS;
        const float* bnd_l = b_nd + (size_t)l * 256;
        const float* gam_l = gam  + (size_t)l * 256;
        const float* tbl_l = f_table + (size_t)l * 4097 * 128;

        // qkv = h @ [Wq|Wk|Wv]   [N,256]@[256,384]
        mfma_gemm<false,false,false><<<dim3(3, MB), 256, 0, stream>>>(
            f_h, bh + OFF_QKV, bl + OFF_QKV, nullptr, f_qkv, N, 256, 384);

        edge_attn_kernel<<<N, 128, 0, stream>>>(i_rowp, i_perm, ei, f_qkv,
                                                f_dist, f_unit, tbl_l, f_msg, f_U);

        // vfeat += U @ W_vgate   [3N,128]@[128,256]
        mfma_gemm<true,false,false><<<dim3(2, MB3), 256, 0, stream>>>(
            f_U, bh + OFF_VG, bl + OFF_VG, nullptr, f_vf, 3 * N, 128, 256);

        // b1 = gelu(msg @ W_msg)  (overwrites dead U)
        mfma_gemm<false,false,true><<<dim3(2, MB), 256, 0, stream>>>(
            f_msg, bh + OFF_MSG, bl + OFF_MSG, nullptr, f_b1, N, 128, 256);
        // b2 = gelu(b1 @ W_node + b_node)  (overwrites dead qkv)
        mfma_gemm<false,true,true><<<dim3(2, MB), 256, 0, stream>>>(
            f_b1, bh + OFF_ND, bl + OFF_ND, bnd_l, f_b2, N, 256, 256);
        // b1 = vnorm(vfeat)
        vnorm_kernel<<<N, 256, 0, stream>>>(f_vf, f_b1);
        // b2 += vnorm @ W_vs
        mfma_gemm<true,false,false><<<dim3(2, MB), 256, 0, stream>>>(
            f_b1, bh + OFF_VS, bl + OFF_VS, nullptr, f_b2, N, 256, 256);

        ln_kernel<<<N, 256, 0, stream>>>(f_h, f_b2, gam_l);
    }

    // ---- readout ----
    pool_kernel<<<G, 256, 0, stream>>>(f_h, watt, i_gptr, f_pool);
    // out = pooled @ W_out + b_out   [500,256]@[256,512]
    mfma_gemm<false,true,false><<<dim3(4, (G + 127) / 128), 256, 0, stream>>>(
        f_pool, whi + OFF_OUT, wlo + OFF_OUT, b_out, (float*)d_out, G, 256, 512);
}

// Round 6
// 1168.803 us; speedup vs baseline: 1.2095x; 1.2095x over previous
//
#include <hip/hip_runtime.h>
#include <math.h>

typedef unsigned short u16;
typedef unsigned int   u32;
typedef __attribute__((ext_vector_type(8))) unsigned short ushort8;
typedef __attribute__((ext_vector_type(8))) short short8v;   // 8 bf16 (4 VGPRs)
typedef __attribute__((ext_vector_type(4))) float f32x4;

__device__ __forceinline__ float gelu_f(float x) {
    const float c = 0.7978845608028654f;   // sqrt(2/pi)
    float x3 = x * x * x;
    float t = tanhf(c * (x + 0.044715f * x3));
    return 0.5f * x * (1.0f + t);
}

// f32 -> bf16 RNE
__device__ __forceinline__ u16 f2b(float f) {
    u32 u = __float_as_uint(f);
    return (u16)((u + 0x7FFFu + ((u >> 16) & 1u)) >> 16);
}
__device__ __forceinline__ float b2f(u16 u) {
    u32 x = ((u32)u) << 16;
    return __uint_as_float(x);
}

// split f32 -> bf16 hi + bf16 lo (hi+lo ~ 16-bit mantissa)
__device__ __forceinline__ void split_bf16(float f, u16& h, u16& l) {
    u32 u = __float_as_uint(f);
    u32 r = (u + 0x7FFFu + ((u >> 16) & 1u)) >> 16;
    h = (u16)r;
    float hf = __uint_as_float(r << 16);
    float d = f - hf;
    u32 u2 = __float_as_uint(d);
    l = (u16)((u2 + 0x7FFFu + ((u2 >> 16) & 1u)) >> 16);
}

// ---------------------------------------------------------------------------
__global__ __launch_bounds__(256) void zero_i32(int* __restrict__ p, int n) {
    int i = blockIdx.x * 256 + threadIdx.x;
    if (i < n) p[i] = 0;
}

// ---------------------------------------------------------------------------
// Weight pre-pass: transpose [K][N] f32 -> [N][K] split bf16 hi/lo
// ---------------------------------------------------------------------------
struct TEntry { const float* src; u16* dh; u16* dl; int K; int N; };
struct TDesc  { TEntry e[29]; };

__global__ __launch_bounds__(256) void transpose_split(TDesc desc) {
    __shared__ float tile[32][33];
    TEntry en = desc.e[blockIdx.y];
    int tk = en.K >> 5, tn = en.N >> 5;
    int bx = blockIdx.x;
    if (bx >= tk * tn) return;
    int k0 = (bx % tk) * 32, n0 = (bx / tk) * 32;
    int tx = threadIdx.x & 31, ty = threadIdx.x >> 5;   // 32 x 8
    #pragma unroll
    for (int yy = 0; yy < 32; yy += 8)
        tile[ty + yy][tx] = en.src[(size_t)(k0 + ty + yy) * en.N + (n0 + tx)];
    __syncthreads();
    #pragma unroll
    for (int yy = 0; yy < 32; yy += 8) {
        int n = n0 + ty + yy, k = k0 + tx;
        float f = tile[tx][ty + yy];
        u16 h, l;
        split_bf16(f, h, l);
        en.dh[(size_t)n * en.K + k] = h;
        en.dl[(size_t)n * en.K + k] = l;
    }
}

// ---------------------------------------------------------------------------
// RBF lookup table: table[k][m] = sum_r sin(d_k*(r+1)*pi/6)/d_k * env(d_k) *
// W_rbf[r][m], d_k = k*6/4096, k in [0,4096]. One table per layer.
// ---------------------------------------------------------------------------
__global__ __launch_bounds__(128) void build_rbf_table(
    const float* __restrict__ Wrbf_l, float* __restrict__ table)
{
    int k = blockIdx.x, m = threadIdx.x;
    const float PI = 3.14159265358979323846f;
    float d = fmaxf((float)k * (6.0f / 4096.0f), 1e-9f);
    float th = d * (PI / 6.0f);
    float s1, c1;
    __sincosf(th, &s1, &c1);
    float env = 0.5f * c1 + 0.5f;
    float invd = 1.0f / d;
    float two_c = 2.0f * c1;
    float sp = 0.f, sc = s1, dot = 0.f;
    #pragma unroll
    for (int r = 0; r < 32; ++r) {
        dot = fmaf(sc, Wrbf_l[r * 128 + m], dot);
        float sn = fmaf(two_c, sc, -sp);
        sp = sc; sc = sn;
    }
    table[(size_t)k * 128 + m] = dot * invd * env;
}

// ---------------------------------------------------------------------------
// MFMA GEMM: C[M,N] = act(A[M,K] @ B[K,N] (+bias)), optional += (ACCUM, f32)
// A bf16 [M][K] row-major (pre-converted); B pre-transposed + split:
// BH/BL are [N][K] bf16.  C ~= A * (Bh + Bl).
// Block tile 128x128, BK=32, 256 threads = 4 waves, 64x64 per wave.
// Requires K%32==0, N%128==0; M guarded.  OUTB16: write bf16 (no ACCUM).
// ---------------------------------------------------------------------------
template<bool ACCUM, bool BIAS, bool DOGELU, bool OUTB16>
__global__ __launch_bounds__(256) void mfma_gemm(
    const u16* __restrict__ A, const u16* __restrict__ BH,
    const u16* __restrict__ BL, const float* __restrict__ bias,
    void* __restrict__ Cv, int Mrows, int K, int Nc)
{
    __shared__ __align__(16) u16 sA [128][40];
    __shared__ __align__(16) u16 sBh[128][40];
    __shared__ __align__(16) u16 sBl[128][40];

    const int t = threadIdx.x;
    const int lane = t & 63, wid = t >> 6;
    const int r0 = blockIdx.y * 128, c0 = blockIdx.x * 128;
    const int wr = (wid >> 1) * 64, wc = (wid & 1) * 64;

    f32x4 acc[4][4] = {};

    const int srow = t >> 1;            // staging row 0..127
    const int skc  = (t & 1) * 16;      // staging k-offset 0/16

    for (int k0 = 0; k0 < K; k0 += 32) {
        // ---- stage A (bf16 copy) ----
        {
            int gr = r0 + srow;
            ushort8 h0, h1;
            if (gr < Mrows) {
                const u16* p = A + (size_t)gr * K + (k0 + skc);
                h0 = *(const ushort8*)p;
                h1 = *(const ushort8*)(p + 8);
            } else {
                #pragma unroll
                for (int j = 0; j < 8; ++j) { h0[j] = 0; h1[j] = 0; }
            }
            *(ushort8*)&sA[srow][skc]     = h0;
            *(ushort8*)&sA[srow][skc + 8] = h1;
        }
        // ---- stage B (already split, copy) ----
        {
            int cg = c0 + srow;
            const u16* ph = BH + (size_t)cg * K + (k0 + skc);
            const u16* pl = BL + (size_t)cg * K + (k0 + skc);
            *(ushort8*)&sBh[srow][skc]     = *(const ushort8*)(ph);
            *(ushort8*)&sBh[srow][skc + 8] = *(const ushort8*)(ph + 8);
            *(ushort8*)&sBl[srow][skc]     = *(const ushort8*)(pl);
            *(ushort8*)&sBl[srow][skc + 8] = *(const ushort8*)(pl + 8);
        }
        __syncthreads();

        // ---- compute: wave tile 64x64 = 4x4 fragments of 16x16, K=32 ----
        const int arow = wr + (lane & 15);
        const int koff = (lane >> 4) * 8;
        short8v ah[4];
        #pragma unroll
        for (int fr = 0; fr < 4; ++fr)
            ah[fr] = *(const short8v*)&sA[arow + fr * 16][koff];
        #pragma unroll
        for (int fc = 0; fc < 4; ++fc) {
            int bcol = wc + fc * 16 + (lane & 15);
            short8v bh = *(const short8v*)&sBh[bcol][koff];
            short8v bl = *(const short8v*)&sBl[bcol][koff];
            #pragma unroll
            for (int fr = 0; fr < 4; ++fr) {
                acc[fr][fc] = __builtin_amdgcn_mfma_f32_16x16x32_bf16(ah[fr], bh, acc[fr][fc], 0, 0, 0);
                acc[fr][fc] = __builtin_amdgcn_mfma_f32_16x16x32_bf16(ah[fr], bl, acc[fr][fc], 0, 0, 0);
            }
        }
        __syncthreads();
    }

    // ---- epilogue: C/D layout col=lane&15, row=(lane>>4)*4+reg ----
    #pragma unroll
    for (int fr = 0; fr < 4; ++fr) {
        int rbase = r0 + wr + fr * 16 + (lane >> 4) * 4;
        #pragma unroll
        for (int fc = 0; fc < 4; ++fc) {
            int col = c0 + wc + fc * 16 + (lane & 15);
            #pragma unroll
            for (int reg = 0; reg < 4; ++reg) {
                int gr = rbase + reg;
                if (gr >= Mrows) continue;
                float v = acc[fr][fc][reg];
                if (BIAS)   v += bias[col];
                if (DOGELU) v = gelu_f(v);
                if (OUTB16) {
                    u16* pc = (u16*)Cv + (size_t)gr * Nc + col;
                    *pc = f2b(v);
                } else {
                    float* pc = (float*)Cv + (size_t)gr * Nc + col;
                    if (ACCUM) v += *pc;
                    *pc = v;
                }
            }
        }
    }
}

// ---------------------------------------------------------------------------
// CSR construction
// ---------------------------------------------------------------------------
__global__ void hist_edges(const int* __restrict__ ei, int* __restrict__ deg, int E_) {
    int e = blockIdx.x * 256 + threadIdx.x;
    if (e < E_) atomicAdd(&deg[ei[E_ + e]], 1);   // dst row
}
__global__ void hist_nodes(const int* __restrict__ batch, int* __restrict__ gcnt, int n) {
    int i = blockIdx.x * 256 + threadIdx.x;
    if (i < n) atomicAdd(&gcnt[batch[i]], 1);
}

__global__ __launch_bounds__(1024) void scan_kernel(
    const int* __restrict__ cnt, int n, int* __restrict__ out, int* __restrict__ cursor)
{
    __shared__ int part[1024];
    int t = threadIdx.x;
    int chunk = (n + 1023) / 1024;
    int base = t * chunk;
    int s = 0;
    for (int k = 0; k < chunk; ++k) { int i = base + k; if (i < n) s += cnt[i]; }
    part[t] = s;
    __syncthreads();
    for (int off = 1; off < 1024; off <<= 1) {
        int u = (t >= off) ? part[t - off] : 0;
        __syncthreads();
        part[t] += u;
        __syncthreads();
    }
    int run = part[t] - s;
    for (int k = 0; k < chunk; ++k) {
        int i = base + k;
        if (i < n) {
            out[i] = run;
            if (cursor) cursor[i] = run;
            run += cnt[i];
        }
    }
    if (t == 1023) out[n] = part[1023];
}

__global__ void scatter_kernel(const int* __restrict__ ei, int* __restrict__ cursor,
                               int* __restrict__ perm, int E_) {
    int e = blockIdx.x * 256 + threadIdx.x;
    if (e < E_) {
        int p = atomicAdd(&cursor[ei[E_ + e]], 1);
        perm[p] = e;
    }
}

// ---------------------------------------------------------------------------
// Edge geometry: distance + unit vector
// ---------------------------------------------------------------------------
__global__ __launch_bounds__(256) void geom_kernel(
    const float* __restrict__ pos, const int* __restrict__ ei,
    float* __restrict__ dist, float* __restrict__ unitv, int E_)
{
    int e = blockIdx.x * 256 + threadIdx.x;
    if (e >= E_) return;
    int s = ei[e], dn = ei[E_ + e];
    float dx = pos[s * 3 + 0] - pos[dn * 3 + 0];
    float dy = pos[s * 3 + 1] - pos[dn * 3 + 1];
    float dz = pos[s * 3 + 2] - pos[dn * 3 + 2];
    float d = sqrtf(dx * dx + dy * dy + dz * dz + 1e-12f);
    float invd = 1.0f / d;
    dist[e] = d;
    unitv[(size_t)e * 3 + 0] = dx * invd;
    unitv[(size_t)e * 3 + 1] = dy * invd;
    unitv[(size_t)e * 3 + 2] = dz * invd;
}

// ---------------------------------------------------------------------------
// h init: concat(emb[z], pos) @ W_in + b_in   (writes f32 h and bf16 h16)
// ---------------------------------------------------------------------------
__global__ __launch_bounds__(256) void init_h_kernel(
    const int* __restrict__ z, const float* __restrict__ pos,
    const float* __restrict__ emb, const float* __restrict__ W_in,
    const float* __restrict__ b_in, float* __restrict__ h, u16* __restrict__ h16)
{
    int i = blockIdx.x, d = threadIdx.x;
    float acc = b_in[d];
    int zi = z[i];
    #pragma unroll 8
    for (int k = 0; k < 32; ++k)
        acc += emb[zi * 32 + k] * W_in[k * 256 + d];
    #pragma unroll
    for (int x = 0; x < 3; ++x)
        acc += pos[i * 3 + x] * W_in[(32 + x) * 256 + d];
    h[(size_t)i * 256 + d] = acc;
    h16[(size_t)i * 256 + d] = f2b(acc);
}

// ---------------------------------------------------------------------------
// Per-dst-node edge attention, online softmax, 4 edges per iteration.
// Block = dst node, 128 threads = message channels, head = m/32.
// qkv is bf16 [N][384] = [q|k|v]; ew from per-layer f32 lookup table.
// Outputs msg[N,128] and U[N,3,128] as bf16, softmax-normalized.
// ---------------------------------------------------------------------------
__global__ __launch_bounds__(128) void edge_attn_kernel(
    const int* __restrict__ rowptr, const int* __restrict__ perm,
    const int* __restrict__ ei,
    const u16* __restrict__ qkv,
    const float* __restrict__ dist, const float* __restrict__ unitv,
    const float* __restrict__ table_l,
    u16* __restrict__ msg, u16* __restrict__ U)
{
    int m = threadIdx.x;
    int i = blockIdx.x;

    int p0 = rowptr[i], p1 = rowptr[i + 1];
    float q = b2f(qkv[(size_t)i * 384 + m]);
    float Mx = -1e30f, S = 0.f, am = 0.f, a0 = 0.f, a1 = 0.f, a2 = 0.f;

    for (int p = p0; p < p1; p += 4) {
        int rem = p1 - p;
        int pA = p;
        int pB = p + (rem > 1 ? 1 : 0);
        int pC = p + (rem > 2 ? 2 : 0);
        int pD = p + (rem > 3 ? 3 : 0);
        int eA = __builtin_amdgcn_readfirstlane(perm[pA]);
        int eB = __builtin_amdgcn_readfirstlane(perm[pB]);
        int eC = __builtin_amdgcn_readfirstlane(perm[pC]);
        int eD = __builtin_amdgcn_readfirstlane(perm[pD]);
        int jA = __builtin_amdgcn_readfirstlane(ei[eA]);
        int jB = __builtin_amdgcn_readfirstlane(ei[eB]);
        int jC = __builtin_amdgcn_readfirstlane(ei[eC]);
        int jD = __builtin_amdgcn_readfirstlane(ei[eD]);

        // issue all gathers together (8 vector loads in flight)
        float kA = b2f(qkv[(size_t)jA * 384 + 128 + m]);
        float kB = b2f(qkv[(size_t)jB * 384 + 128 + m]);
        float kC = b2f(qkv[(size_t)jC * 384 + 128 + m]);
        float kD = b2f(qkv[(size_t)jD * 384 + 128 + m]);
        float vA = b2f(qkv[(size_t)jA * 384 + 256 + m]);
        float vB = b2f(qkv[(size_t)jB * 384 + 256 + m]);
        float vC = b2f(qkv[(size_t)jC * 384 + 256 + m]);
        float vD = b2f(qkv[(size_t)jD * 384 + 256 + m]);
        float dA = dist[eA], dB = dist[eB], dC = dist[eC], dD = dist[eD];
        float xA = unitv[(size_t)eA * 3 + 0], yA = unitv[(size_t)eA * 3 + 1], zA = unitv[(size_t)eA * 3 + 2];
        float xB = unitv[(size_t)eB * 3 + 0], yB = unitv[(size_t)eB * 3 + 1], zB = unitv[(size_t)eB * 3 + 2];
        float xC = unitv[(size_t)eC * 3 + 0], yC = unitv[(size_t)eC * 3 + 1], zC = unitv[(size_t)eC * 3 + 2];
        float xD = unitv[(size_t)eD * 3 + 0], yD = unitv[(size_t)eD * 3 + 1], zD = unitv[(size_t)eD * 3 + 2];

        // logits (per-head 32-lane reduce)
        float prA = q * kA, prB = q * kB, prC = q * kC, prD = q * kD;
        #pragma unroll
        for (int off = 16; off; off >>= 1) {
            prA += __shfl_xor(prA, off);
            prB += __shfl_xor(prB, off);
            prC += __shfl_xor(prC, off);
            prD += __shfl_xor(prD, off);
        }
        const float iscale = 0.1767766952966369f;   // 1/sqrt(32)
        float lA = prA * iscale, lB = prB * iscale, lC = prC * iscale, lD = prD * iscale;

        // table lerp for ew
        auto LERP = [&](float d) -> float {
            if (d >= 6.0f) return 0.0f;
            float x = d * (4096.0f / 6.0f);
            int b = (int)x;
            float tf = x - (float)b;
            float f0 = table_l[(size_t)b * 128 + m];
            float f1 = table_l[(size_t)(b + 1) * 128 + m];
            return fmaf(tf, f1 - f0, f0);
        };
        float ewA = LERP(dA), ewB = LERP(dB), ewC = LERP(dC), ewD = LERP(dD);

        // batched online softmax (duplicated tail edges can't raise the max)
        float Mb = fmaxf(Mx, fmaxf(fmaxf(lA, lB), fmaxf(lC, lD)));
        float sc = __expf(Mx - Mb);
        float wA = __expf(lA - Mb);
        float wB = (rem > 1) ? __expf(lB - Mb) : 0.f;
        float wC = (rem > 2) ? __expf(lC - Mb) : 0.f;
        float wD = (rem > 3) ? __expf(lD - Mb) : 0.f;
        float wvA = wA * vA * ewA, wvB = wB * vB * ewB;
        float wvC = wC * vC * ewC, wvD = wD * vD * ewD;
        S  = S  * sc + (wA + wB + wC + wD);
        am = am * sc + (wvA + wvB + wvC + wvD);
        a0 = a0 * sc + (wvA * xA + wvB * xB + wvC * xC + wvD * xD);
        a1 = a1 * sc + (wvA * yA + wvB * yB + wvC * yC + wvD * yD);
        a2 = a2 * sc + (wvA * zA + wvB * zB + wvC * zC + wvD * zD);
        Mx = Mb;
    }
    float inv = 1.0f / (S + 1e-12f);
    msg[(size_t)i * 128 + m] = f2b(am * inv);
    U[((size_t)i * 3 + 0) * 128 + m] = f2b(a0 * inv);
    U[((size_t)i * 3 + 1) * 128 + m] = f2b(a1 * inv);
    U[((size_t)i * 3 + 2) * 128 + m] = f2b(a2 * inv);
}

// ---------------------------------------------------------------------------
// vnorm[i,d] = sqrt(sum_xyz vfeat[i,x,d]^2 + 1e-8)  -> bf16
// ---------------------------------------------------------------------------
__global__ __launch_bounds__(256) void vnorm_kernel(
    const float* __restrict__ vfeat, u16* __restrict__ vn)
{
    int i = blockIdx.x, d = threadIdx.x;
    float v0 = vfeat[((size_t)i * 3 + 0) * 256 + d];
    float v1 = vfeat[((size_t)i * 3 + 1) * 256 + d];
    float v2 = vfeat[((size_t)i * 3 + 2) * 256 + d];
    vn[(size_t)i * 256 + d] = f2b(sqrtf(v0 * v0 + v1 * v1 + v2 * v2 + 1e-8f));
}

// ---------------------------------------------------------------------------
// h = layernorm(h + add) * gamma    (writes f32 h and bf16 h16)
// ---------------------------------------------------------------------------
__global__ __launch_bounds__(256) void ln_kernel(
    float* __restrict__ h, const float* __restrict__ add,
    const float* __restrict__ gamma_l, u16* __restrict__ h16)
{
    __shared__ float lds[4];
    int i = blockIdx.x, d = threadIdx.x;
    size_t idx = (size_t)i * 256 + d;
    float x = h[idx] + add[idx];
    float s = x;
    #pragma unroll
    for (int off = 32; off; off >>= 1) s += __shfl_xor(s, off);
    if ((d & 63) == 0) lds[d >> 6] = s;
    __syncthreads();
    float mu = (lds[0] + lds[1] + lds[2] + lds[3]) * (1.0f / 256.0f);
    __syncthreads();
    float xc = x - mu;
    float v = xc * xc;
    #pragma unroll
    for (int off = 32; off; off >>= 1) v += __shfl_xor(v, off);
    if ((d & 63) == 0) lds[d >> 6] = v;
    __syncthreads();
    float var = (lds[0] + lds[1] + lds[2] + lds[3]) * (1.0f / 256.0f);
    float r = xc * rsqrtf(var + 1e-5f) * gamma_l[d];
    h[idx] = r;
    h16[idx] = f2b(r);
}

// ---------------------------------------------------------------------------
// Graph pooling: softmax(h @ w_att) weighted sum per graph (batch sorted)
// ---------------------------------------------------------------------------
__global__ __launch_bounds__(256) void pool_kernel(
    const float* __restrict__ h, const float* __restrict__ w_att,
    const int* __restrict__ gptr, u16* __restrict__ pooled)
{
    __shared__ float lds[4];
    int g = blockIdx.x, d = threadIdx.x;
    float wa = w_att[d];
    int n0 = gptr[g], n1 = gptr[g + 1];
    float M = -1e30f, S = 0.f, acc = 0.f;
    for (int i = n0; i < n1; ++i) {
        float hv = h[(size_t)i * 256 + d];
        float p = hv * wa;
        #pragma unroll
        for (int off = 32; off; off >>= 1) p += __shfl_xor(p, off);
        if ((d & 63) == 0) lds[d >> 6] = p;
        __syncthreads();
        float logit = lds[0] + lds[1] + lds[2] + lds[3];
        __syncthreads();
        float nM = fmaxf(M, logit);
        float sc = __expf(M - nM);
        float w  = __expf(logit - nM);
        S = S * sc + w;
        acc = acc * sc + w * hv;
        M = nM;
    }
    pooled[(size_t)g * 256 + d] = f2b(acc / (S + 1e-12f));
}

// ---------------------------------------------------------------------------
extern "C" void kernel_launch(void* const* d_in, const int* in_sizes, int n_in,
                              void* d_out, int out_size, void* d_ws, size_t ws_size,
                              hipStream_t stream)
{
    const float* pos   = (const float*)d_in[0];
    const int*   z     = (const int*)d_in[1];
    const int*   batch = (const int*)d_in[2];
    const int*   ei    = (const int*)d_in[3];
    const float* emb   = (const float*)d_in[4];
    const float* W_in  = (const float*)d_in[5];
    const float* b_in  = (const float*)d_in[6];
    const float* Wq    = (const float*)d_in[7];
    const float* Wk    = (const float*)d_in[8];
    const float* Wv    = (const float*)d_in[9];
    const float* W_rbf = (const float*)d_in[10];
    const float* W_msg = (const float*)d_in[11];
    const float* W_vg  = (const float*)d_in[12];
    const float* W_vs  = (const float*)d_in[13];
    const float* W_nd  = (const float*)d_in[14];
    const float* b_nd  = (const float*)d_in[15];
    const float* gam   = (const float*)d_in[16];
    const float* watt  = (const float*)d_in[17];
    const float* W_out = (const float*)d_in[18];
    const float* b_out = (const float*)d_in[19];

    const int N = in_sizes[0] / 3;      // 20000
    const int E = in_sizes[3] / 2;      // 320000
    const int G = out_size / 512;       // 500

    char* ws = (char*)d_ws;
    size_t o = 0;
    auto alloc = [&](size_t bytes) -> char* {
        o = (o + 255) & ~(size_t)255;
        char* r = ws + o;
        o += bytes;
        return r;
    };
    float* f_dist  = (float*)alloc((size_t)E * 4);                  //  1.3 MB
    float* f_unit  = (float*)alloc((size_t)E * 3 * 4);              //  3.8 MB
    float* f_h     = (float*)alloc((size_t)N * 256 * 4);            // 20.5 MB
    u16*   h16     = (u16*)  alloc((size_t)N * 256 * 2);            // 10.2 MB
    float* f_vf    = (float*)alloc((size_t)N * 3 * 256 * 4);        // 61.4 MB
    u16*   qkv16   = (u16*)  alloc((size_t)N * 384 * 2);            // 15.4 MB
    u16*   umb     = (u16*)  alloc((size_t)N * 4 * 128 * 2);        // 20.5 MB
    u16*   vn16    = (u16*)  alloc((size_t)N * 256 * 2);            // 10.2 MB
    u16*   pool16  = (u16*)  alloc((size_t)G * 256 * 2);
    float* f_table = (float*)alloc((size_t)4 * 4097 * 128 * 4);     //  8.4 MB
    const size_t LS = 384 * 256 + 2 * (256 * 128) + 2 * (256 * 256);   // 294912
    const size_t OFF_QKV = 0, OFF_VG = 384 * 256, OFF_MSG = OFF_VG + 256 * 128,
                 OFF_ND = OFF_MSG + 256 * 128, OFF_VS = OFF_ND + 256 * 256;
    const size_t OFF_OUT = LS * 4;
    u16* whi = (u16*)alloc((LS * 4 + 512 * 256) * sizeof(u16));     //  2.6 MB
    u16* wlo = (u16*)alloc((LS * 4 + 512 * 256) * sizeof(u16));     //  2.6 MB
    int* i_deg  = (int*)alloc((size_t)N * 4);
    int* i_rowp = (int*)alloc((size_t)(N + 1) * 4);
    int* i_cur  = (int*)alloc((size_t)(N + 1) * 4);
    int* i_perm = (int*)alloc((size_t)E * 4);
    int* i_gcnt = (int*)alloc((size_t)G * 4);
    int* i_gptr = (int*)alloc((size_t)(G + 1) * 4);
    // total ~160 MB

    // sub-buffers / aliases (lifetimes verified per-layer):
    u16*   U16   = umb;                         // [3N,128] bf16, edge->vgate
    u16*   msg16 = umb + (size_t)3 * N * 128;   // [N,128]  bf16, edge->msgGEMM
    float* f_b2  = (float*)umb;                 // [N,256]  f32, node->vs->ln
                                                // (over U16+msg16, both dead)
    u16*   b1_16 = qkv16;                       // [N,256] bf16, msgGEMM->node
                                                // (qkv dead after edge_attn)

    // ---- weight pre-pass descriptor ----
    TDesc td;
    int idx = 0;
    for (int l = 0; l < 4; ++l) {
        u16* bh = whi + (size_t)l * LS;
        u16* bl = wlo + (size_t)l * LS;
        td.e[idx++] = { Wq   + (size_t)l * 256 * 128, bh + OFF_QKV,             bl + OFF_QKV,             256, 128 };
        td.e[idx++] = { Wk   + (size_t)l * 256 * 128, bh + OFF_QKV + 128 * 256, bl + OFF_QKV + 128 * 256, 256, 128 };
        td.e[idx++] = { Wv   + (size_t)l * 256 * 128, bh + OFF_QKV + 256 * 256, bl + OFF_QKV + 256 * 256, 256, 128 };
        td.e[idx++] = { W_vg + (size_t)l * 128 * 256, bh + OFF_VG,  bl + OFF_VG,  128, 256 };
        td.e[idx++] = { W_msg+ (size_t)l * 128 * 256, bh + OFF_MSG, bl + OFF_MSG, 128, 256 };
        td.e[idx++] = { W_nd + (size_t)l * 256 * 256, bh + OFF_ND,  bl + OFF_ND,  256, 256 };
        td.e[idx++] = { W_vs + (size_t)l * 256 * 256, bh + OFF_VS,  bl + OFF_VS,  256, 256 };
    }
    td.e[idx++] = { W_out, whi + OFF_OUT, wlo + OFF_OUT, 256, 512 };

    // ---- setup ----
    zero_i32<<<(N + 255) / 256, 256, 0, stream>>>(i_deg, N);
    zero_i32<<<(G + 255) / 256, 256, 0, stream>>>(i_gcnt, G);
    transpose_split<<<dim3(128, 29), 256, 0, stream>>>(td);
    for (int l = 0; l < 4; ++l)
        build_rbf_table<<<4097, 128, 0, stream>>>(
            W_rbf + (size_t)l * 32 * 128, f_table + (size_t)l * 4097 * 128);

    hist_edges<<<(E + 255) / 256, 256, 0, stream>>>(ei, i_deg, E);
    scan_kernel<<<1, 1024, 0, stream>>>(i_deg, N, i_rowp, i_cur);
    scatter_kernel<<<(E + 255) / 256, 256, 0, stream>>>(ei, i_cur, i_perm, E);
    hist_nodes<<<(N + 255) / 256, 256, 0, stream>>>(batch, i_gcnt, N);
    scan_kernel<<<1, 1024, 0, stream>>>(i_gcnt, G, i_gptr, (int*)nullptr);
    geom_kernel<<<(E + 255) / 256, 256, 0, stream>>>(pos, ei, f_dist, f_unit, E);
    init_h_kernel<<<N, 256, 0, stream>>>(z, pos, emb, W_in, b_in, f_h, h16);

    const int MB  = (N + 127) / 128;          // 157
    const int MB3 = (3 * N + 127) / 128;      // 469

    // ---- layers ----
    for (int l = 0; l < 4; ++l) {
        u16* bh = whi + (size_t)l * LS;
        u16* bl = wlo + (size_t)l * LS;
        const float* bnd_l = b_nd + (size_t)l * 256;
        const float* gam_l = gam  + (size_t)l * 256;
        const float* tbl_l = f_table + (size_t)l * 4097 * 128;

        // qkv16 = bf16(h @ [Wq|Wk|Wv])   [N,256]@[256,384]
        mfma_gemm<false,false,false,true><<<dim3(3, MB), 256, 0, stream>>>(
            h16, bh + OFF_QKV, bl + OFF_QKV, nullptr, qkv16, N, 256, 384);

        edge_attn_kernel<<<N, 128, 0, stream>>>(i_rowp, i_perm, ei, qkv16,
                                                f_dist, f_unit, tbl_l, msg16, U16);

        // vfeat (+)= U @ W_vgate   [3N,128]@[128,256]; layer0 writes directly
        if (l == 0)
            mfma_gemm<false,false,false,false><<<dim3(2, MB3), 256, 0, stream>>>(
                U16, bh + OFF_VG, bl + OFF_VG, nullptr, f_vf, 3 * N, 128, 256);
        else
            mfma_gemm<true,false,false,false><<<dim3(2, MB3), 256, 0, stream>>>(
                U16, bh + OFF_VG, bl + OFF_VG, nullptr, f_vf, 3 * N, 128, 256);

        // b1 = bf16(gelu(msg @ W_msg))   (overwrites dead qkv16)
        mfma_gemm<false,false,true,true><<<dim3(2, MB), 256, 0, stream>>>(
            msg16, bh + OFF_MSG, bl + OFF_MSG, nullptr, b1_16, N, 128, 256);
        // b2 = gelu(b1 @ W_node + b_node)  f32  (overwrites dead U16/msg16)
        mfma_gemm<false,true,true,false><<<dim3(2, MB), 256, 0, stream>>>(
            b1_16, bh + OFF_ND, bl + OFF_ND, bnd_l, f_b2, N, 256, 256);
        // vn16 = bf16(vnorm(vfeat))
        vnorm_kernel<<<N, 256, 0, stream>>>(f_vf, vn16);
        // b2 += vnorm @ W_vs
        mfma_gemm<true,false,false,false><<<dim3(2, MB), 256, 0, stream>>>(
            vn16, bh + OFF_VS, bl + OFF_VS, nullptr, f_b2, N, 256, 256);

        ln_kernel<<<N, 256, 0, stream>>>(f_h, f_b2, gam_l, h16);
    }

    // ---- readout ----
    pool_kernel<<<G, 256, 0, stream>>>(f_h, watt, i_gptr, pool16);
    // out = pooled @ W_out + b_out   [500,256]@[256,512]  f32 out
    mfma_gemm<false,true,false,false><<<dim3(4, (G + 127) / 128), 256, 0, stream>>>(
        pool16, whi + OFF_OUT, wlo + OFF_OUT, b_out, (float*)d_out, G, 256, 512);
}

// Round 7
// 1136.415 us; speedup vs baseline: 1.2440x; 1.0285x over previous
//
#include <hip/hip_runtime.h>
#include <math.h>

typedef unsigned char  u8;
typedef unsigned short u16;
typedef unsigned int   u32;
typedef __attribute__((ext_vector_type(8))) unsigned short ushort8;
typedef __attribute__((ext_vector_type(8))) short short8v;   // 8 bf16 (4 VGPRs)
typedef __attribute__((ext_vector_type(4))) float f32x4;

__device__ __forceinline__ float gelu_f(float x) {
    const float c = 0.7978845608028654f;   // sqrt(2/pi)
    float x3 = x * x * x;
    float t = tanhf(c * (x + 0.044715f * x3));
    return 0.5f * x * (1.0f + t);
}

// f32 -> bf16 RNE
__device__ __forceinline__ u16 f2b(float f) {
    u32 u = __float_as_uint(f);
    return (u16)((u + 0x7FFFu + ((u >> 16) & 1u)) >> 16);
}
__device__ __forceinline__ float b2f(u16 u) {
    return __uint_as_float(((u32)u) << 16);
}

// f32 -> fp8 e4m3fn (RNE, clamp 448, subnormal support)
__device__ __forceinline__ u32 f2fp8(float f) {
    u32 u = __float_as_uint(f);
    u32 s = (u >> 31) << 7;
    float af = fabsf(f);
    if (af >= 448.0f) return s | 0x7E;
    if (af < 0.015625f) {                 // subnormal: m * 2^-9
        int m = __float2int_rn(af * 512.0f);
        if (m >= 8) return s | 0x08;
        return s | (u32)m;
    }
    u32 a = __float_as_uint(af);
    u32 r = a + 0xFFFFFu + ((a >> 20) & 1u);
    int e8 = (int)(r >> 23) - 120;
    u32 m3 = (r >> 20) & 7u;
    if (e8 >= 16) return s | 0x7E;
    return s | ((u32)e8 << 3) | m3;
}
// fp8 e4m3fn -> f32
__device__ __forceinline__ float fp8d(u32 b) {
    u32 lo = b & 0x7Fu;
    u32 nb = (lo << 20) + 0x3C000000u;            // rebias: e8 + 120
    float n = __uint_as_float(nb | ((b & 0x80u) << 24));
    float sub = (float)(b & 7u) * 0.001953125f;   // m * 2^-9
    sub = (b & 0x80u) ? -sub : sub;
    return (lo & 0x78u) ? n : sub;
}

// split f32 -> bf16 hi + lo
__device__ __forceinline__ void split_bf16(float f, u16& h, u16& l) {
    u32 u = __float_as_uint(f);
    u32 r = (u + 0x7FFFu + ((u >> 16) & 1u)) >> 16;
    h = (u16)r;
    float hf = __uint_as_float(r << 16);
    float d = f - hf;
    u32 u2 = __float_as_uint(d);
    l = (u16)((u2 + 0x7FFFu + ((u2 >> 16) & 1u)) >> 16);
}

// ---------------------------------------------------------------------------
__global__ __launch_bounds__(256) void zero_i32(int* __restrict__ p, int n) {
    int i = blockIdx.x * 256 + threadIdx.x;
    if (i < n) p[i] = 0;
}

// ---------------------------------------------------------------------------
// Weight pre-pass: transpose [K][N] f32 -> [N][K] split bf16 hi/lo
// ---------------------------------------------------------------------------
struct TEntry { const float* src; u16* dh; u16* dl; int K; int N; };
struct TDesc  { TEntry e[29]; };

__global__ __launch_bounds__(256) void transpose_split(TDesc desc) {
    __shared__ float tile[32][33];
    TEntry en = desc.e[blockIdx.y];
    int tk = en.K >> 5, tn = en.N >> 5;
    int bx = blockIdx.x;
    if (bx >= tk * tn) return;
    int k0 = (bx % tk) * 32, n0 = (bx / tk) * 32;
    int tx = threadIdx.x & 31, ty = threadIdx.x >> 5;   // 32 x 8
    #pragma unroll
    for (int yy = 0; yy < 32; yy += 8)
        tile[ty + yy][tx] = en.src[(size_t)(k0 + ty + yy) * en.N + (n0 + tx)];
    __syncthreads();
    #pragma unroll
    for (int yy = 0; yy < 32; yy += 8) {
        int n = n0 + ty + yy, k = k0 + tx;
        float f = tile[tx][ty + yy];
        u16 h, l;
        split_bf16(f, h, l);
        en.dh[(size_t)n * en.K + k] = h;
        en.dl[(size_t)n * en.K + k] = l;
    }
}

// ---------------------------------------------------------------------------
// RBF lookup tables (all 4 layers in one launch)
// ---------------------------------------------------------------------------
__global__ __launch_bounds__(128) void build_rbf_table(
    const float* __restrict__ W_rbf, float* __restrict__ table)
{
    int k = blockIdx.x, l = blockIdx.y, m = threadIdx.x;
    const float* Wrbf_l = W_rbf + (size_t)l * 32 * 128;
    float* tbl = table + (size_t)l * 4097 * 128;
    const float PI = 3.14159265358979323846f;
    float d = fmaxf((float)k * (6.0f / 4096.0f), 1e-9f);
    float th = d * (PI / 6.0f);
    float s1, c1;
    __sincosf(th, &s1, &c1);
    float env = 0.5f * c1 + 0.5f;
    float invd = 1.0f / d;
    float two_c = 2.0f * c1;
    float sp = 0.f, sc = s1, dot = 0.f;
    #pragma unroll
    for (int r = 0; r < 32; ++r) {
        dot = fmaf(sc, Wrbf_l[r * 128 + m], dot);
        float sn = fmaf(two_c, sc, -sp);
        sp = sc; sc = sn;
    }
    tbl[(size_t)k * 128 + m] = dot * invd * env;
}

// ---------------------------------------------------------------------------
// MFMA GEMM. A bf16 [M][K]; BH/BL pre-transposed split bf16 [N][K].
// C ~= A * (Bh + Bl). Block 128x128, BK=32, 4 waves.
// OMODE: 0 = f32 out (ACCUM = f32 +=), 1 = bf16 out,
//        2 = bf16 out with bf16 accum, 3 = qkv mixed (Q bf16 / K,V fp8 pairs)
// ---------------------------------------------------------------------------
template<int OMODE, bool ACCUM, bool BIAS, bool DOGELU>
__global__ __launch_bounds__(256) void mfma_gemm(
    const u16* __restrict__ A, const u16* __restrict__ BH,
    const u16* __restrict__ BL, const float* __restrict__ bias,
    void* __restrict__ Cv, void* __restrict__ Cv2,
    int Mrows, int K, int Nc)
{
    __shared__ __align__(16) u16 sA [128][40];
    __shared__ __align__(16) u16 sBh[128][40];
    __shared__ __align__(16) u16 sBl[128][40];

    const int t = threadIdx.x;
    const int lane = t & 63, wid = t >> 6;
    const int r0 = blockIdx.y * 128, c0 = blockIdx.x * 128;
    const int wr = (wid >> 1) * 64, wc = (wid & 1) * 64;

    f32x4 acc[4][4] = {};

    const int srow = t >> 1;
    const int skc  = (t & 1) * 16;

    for (int k0 = 0; k0 < K; k0 += 32) {
        {
            int gr = r0 + srow;
            ushort8 h0, h1;
            if (gr < Mrows) {
                const u16* p = A + (size_t)gr * K + (k0 + skc);
                h0 = *(const ushort8*)p;
                h1 = *(const ushort8*)(p + 8);
            } else {
                #pragma unroll
                for (int j = 0; j < 8; ++j) { h0[j] = 0; h1[j] = 0; }
            }
            *(ushort8*)&sA[srow][skc]     = h0;
            *(ushort8*)&sA[srow][skc + 8] = h1;
        }
        {
            int cg = c0 + srow;
            const u16* ph = BH + (size_t)cg * K + (k0 + skc);
            const u16* pl = BL + (size_t)cg * K + (k0 + skc);
            *(ushort8*)&sBh[srow][skc]     = *(const ushort8*)(ph);
            *(ushort8*)&sBh[srow][skc + 8] = *(const ushort8*)(ph + 8);
            *(ushort8*)&sBl[srow][skc]     = *(const ushort8*)(pl);
            *(ushort8*)&sBl[srow][skc + 8] = *(const ushort8*)(pl + 8);
        }
        __syncthreads();

        const int arow = wr + (lane & 15);
        const int koff = (lane >> 4) * 8;
        short8v ah[4];
        #pragma unroll
        for (int fr = 0; fr < 4; ++fr)
            ah[fr] = *(const short8v*)&sA[arow + fr * 16][koff];
        #pragma unroll
        for (int fc = 0; fc < 4; ++fc) {
            int bcol = wc + fc * 16 + (lane & 15);
            short8v bh = *(const short8v*)&sBh[bcol][koff];
            short8v bl = *(const short8v*)&sBl[bcol][koff];
            #pragma unroll
            for (int fr = 0; fr < 4; ++fr) {
                acc[fr][fc] = __builtin_amdgcn_mfma_f32_16x16x32_bf16(ah[fr], bh, acc[fr][fc], 0, 0, 0);
                acc[fr][fc] = __builtin_amdgcn_mfma_f32_16x16x32_bf16(ah[fr], bl, acc[fr][fc], 0, 0, 0);
            }
        }
        __syncthreads();
    }

    #pragma unroll
    for (int fr = 0; fr < 4; ++fr) {
        int rbase = r0 + wr + fr * 16 + (lane >> 4) * 4;
        #pragma unroll
        for (int fc = 0; fc < 4; ++fc) {
            int col = c0 + wc + fc * 16 + (lane & 15);
            #pragma unroll
            for (int reg = 0; reg < 4; ++reg) {
                int gr = rbase + reg;
                if (gr >= Mrows) continue;
                float v = acc[fr][fc][reg];
                if (BIAS)   v += bias[col];
                if (DOGELU) v = gelu_f(v);
                if (OMODE == 0) {
                    float* pc = (float*)Cv + (size_t)gr * Nc + col;
                    if (ACCUM) v += *pc;
                    *pc = v;
                } else if (OMODE == 1) {
                    ((u16*)Cv)[(size_t)gr * Nc + col] = f2b(v);
                } else if (OMODE == 2) {
                    u16* pc = (u16*)Cv + (size_t)gr * Nc + col;
                    *pc = f2b(v + b2f(*pc));
                } else {   // OMODE 3: qkv mixed
                    if (col < 128)
                        ((u16*)Cv)[(size_t)gr * 128 + col] = f2b(v);
                    else if (col < 256)
                        ((u8*)Cv2)[(size_t)gr * 256 + (col - 128) * 2] = (u8)f2fp8(v);
                    else
                        ((u8*)Cv2)[(size_t)gr * 256 + (col - 256) * 2 + 1] = (u8)f2fp8(v);
                }
            }
        }
    }
}

// ---------------------------------------------------------------------------
// CSR construction
// ---------------------------------------------------------------------------
__global__ void hist_edges(const int* __restrict__ ei, int* __restrict__ deg, int E_) {
    int e = blockIdx.x * 256 + threadIdx.x;
    if (e < E_) atomicAdd(&deg[ei[E_ + e]], 1);
}
__global__ void hist_nodes(const int* __restrict__ batch, int* __restrict__ gcnt, int n) {
    int i = blockIdx.x * 256 + threadIdx.x;
    if (i < n) atomicAdd(&gcnt[batch[i]], 1);
}

__global__ __launch_bounds__(1024) void scan_kernel(
    const int* __restrict__ cnt, int n, int* __restrict__ out, int* __restrict__ cursor)
{
    __shared__ int part[1024];
    int t = threadIdx.x;
    int chunk = (n + 1023) / 1024;
    int base = t * chunk;
    int s = 0;
    for (int k = 0; k < chunk; ++k) { int i = base + k; if (i < n) s += cnt[i]; }
    part[t] = s;
    __syncthreads();
    for (int off = 1; off < 1024; off <<= 1) {
        int u = (t >= off) ? part[t - off] : 0;
        __syncthreads();
        part[t] += u;
        __syncthreads();
    }
    int run = part[t] - s;
    for (int k = 0; k < chunk; ++k) {
        int i = base + k;
        if (i < n) {
            out[i] = run;
            if (cursor) cursor[i] = run;
            run += cnt[i];
        }
    }
    if (t == 1023) out[n] = part[1023];
}

__global__ void scatter_kernel(const int* __restrict__ ei, int* __restrict__ cursor,
                               int* __restrict__ perm, int E_) {
    int e = blockIdx.x * 256 + threadIdx.x;
    if (e < E_) {
        int p = atomicAdd(&cursor[ei[E_ + e]], 1);
        perm[p] = e;
    }
}

// ---------------------------------------------------------------------------
// Edge geometry packed: eg[e] = (ux, uy, uz, dist)
// ---------------------------------------------------------------------------
__global__ __launch_bounds__(256) void geom_kernel(
    const float* __restrict__ pos, const int* __restrict__ ei,
    float4* __restrict__ eg, int E_)
{
    int e = blockIdx.x * 256 + threadIdx.x;
    if (e >= E_) return;
    int s = ei[e], dn = ei[E_ + e];
    float dx = pos[s * 3 + 0] - pos[dn * 3 + 0];
    float dy = pos[s * 3 + 1] - pos[dn * 3 + 1];
    float dz = pos[s * 3 + 2] - pos[dn * 3 + 2];
    float d = sqrtf(dx * dx + dy * dy + dz * dz + 1e-12f);
    float invd = 1.0f / d;
    eg[e] = make_float4(dx * invd, dy * invd, dz * invd, d);
}

// ---------------------------------------------------------------------------
// h init -> bf16
// ---------------------------------------------------------------------------
__global__ __launch_bounds__(256) void init_h_kernel(
    const int* __restrict__ z, const float* __restrict__ pos,
    const float* __restrict__ emb, const float* __restrict__ W_in,
    const float* __restrict__ b_in, u16* __restrict__ h16)
{
    int i = blockIdx.x, d = threadIdx.x;
    float acc = b_in[d];
    int zi = z[i];
    #pragma unroll 8
    for (int k = 0; k < 32; ++k)
        acc += emb[zi * 32 + k] * W_in[k * 256 + d];
    #pragma unroll
    for (int x = 0; x < 3; ++x)
        acc += pos[i * 3 + x] * W_in[(32 + x) * 256 + d];
    h16[(size_t)i * 256 + d] = f2b(acc);
}

// ---------------------------------------------------------------------------
// Per-dst-node edge attention, online softmax, 4 edges/iter.
// q16 bf16 [N][128]; kv8 fp8 pairs [N][128] u16 (lo=K_m, hi=V_m).
// ---------------------------------------------------------------------------
__global__ __launch_bounds__(128) void edge_attn_kernel(
    const int* __restrict__ rowptr, const int* __restrict__ perm,
    const int* __restrict__ ei,
    const u16* __restrict__ q16, const u16* __restrict__ kv8,
    const float4* __restrict__ eg, const float* __restrict__ table_l,
    u16* __restrict__ msg, u16* __restrict__ U)
{
    int m = threadIdx.x;
    int i = blockIdx.x;

    int p0 = rowptr[i], p1 = rowptr[i + 1];
    float q = b2f(q16[(size_t)i * 128 + m]);
    float Mx = -1e30f, S = 0.f, am = 0.f, a0 = 0.f, a1 = 0.f, a2 = 0.f;

    for (int p = p0; p < p1; p += 4) {
        int rem = p1 - p;
        int pA = p;
        int pB = p + (rem > 1 ? 1 : 0);
        int pC = p + (rem > 2 ? 2 : 0);
        int pD = p + (rem > 3 ? 3 : 0);
        int eA = __builtin_amdgcn_readfirstlane(perm[pA]);
        int eB = __builtin_amdgcn_readfirstlane(perm[pB]);
        int eC = __builtin_amdgcn_readfirstlane(perm[pC]);
        int eD = __builtin_amdgcn_readfirstlane(perm[pD]);
        int jA = __builtin_amdgcn_readfirstlane(ei[eA]);
        int jB = __builtin_amdgcn_readfirstlane(ei[eB]);
        int jC = __builtin_amdgcn_readfirstlane(ei[eC]);
        int jD = __builtin_amdgcn_readfirstlane(ei[eD]);

        // one u16 gather per edge (K|V fp8 pair) + one float4 geometry
        u32 kvA = kv8[(size_t)jA * 128 + m];
        u32 kvB = kv8[(size_t)jB * 128 + m];
        u32 kvC = kv8[(size_t)jC * 128 + m];
        u32 kvD = kv8[(size_t)jD * 128 + m];
        float4 gA = eg[eA], gB = eg[eB], gC = eg[eC], gD = eg[eD];

        float kA = fp8d(kvA & 0xFF), vA = fp8d(kvA >> 8);
        float kB = fp8d(kvB & 0xFF), vB = fp8d(kvB >> 8);
        float kC = fp8d(kvC & 0xFF), vC = fp8d(kvC >> 8);
        float kD = fp8d(kvD & 0xFF), vD = fp8d(kvD >> 8);

        float prA = q * kA, prB = q * kB, prC = q * kC, prD = q * kD;
        #pragma unroll
        for (int off = 16; off; off >>= 1) {
            prA += __shfl_xor(prA, off);
            prB += __shfl_xor(prB, off);
            prC += __shfl_xor(prC, off);
            prD += __shfl_xor(prD, off);
        }
        const float iscale = 0.1767766952966369f;   // 1/sqrt(32)
        float lA = prA * iscale, lB = prB * iscale, lC = prC * iscale, lD = prD * iscale;

        auto LERP = [&](float d) -> float {
            if (d >= 6.0f) return 0.0f;
            float x = d * (4096.0f / 6.0f);
            int b = (int)x;
            float tf = x - (float)b;
            float f0 = table_l[(size_t)b * 128 + m];
            float f1 = table_l[(size_t)(b + 1) * 128 + m];
            return fmaf(tf, f1 - f0, f0);
        };
        float ewA = LERP(gA.w), ewB = LERP(gB.w), ewC = LERP(gC.w), ewD = LERP(gD.w);

        float Mb = fmaxf(Mx, fmaxf(fmaxf(lA, lB), fmaxf(lC, lD)));
        float sc = __expf(Mx - Mb);
        float wA = __expf(lA - Mb);
        float wB = (rem > 1) ? __expf(lB - Mb) : 0.f;
        float wC = (rem > 2) ? __expf(lC - Mb) : 0.f;
        float wD = (rem > 3) ? __expf(lD - Mb) : 0.f;
        float wvA = wA * vA * ewA, wvB = wB * vB * ewB;
        float wvC = wC * vC * ewC, wvD = wD * vD * ewD;
        S  = S  * sc + (wA + wB + wC + wD);
        am = am * sc + (wvA + wvB + wvC + wvD);
        a0 = a0 * sc + (wvA * gA.x + wvB * gB.x + wvC * gC.x + wvD * gD.x);
        a1 = a1 * sc + (wvA * gA.y + wvB * gB.y + wvC * gC.y + wvD * gD.y);
        a2 = a2 * sc + (wvA * gA.z + wvB * gB.z + wvC * gC.z + wvD * gD.z);
        Mx = Mb;
    }
    float inv = 1.0f / (S + 1e-12f);
    msg[(size_t)i * 128 + m] = f2b(am * inv);
    U[((size_t)i * 3 + 0) * 128 + m] = f2b(a0 * inv);
    U[((size_t)i * 3 + 1) * 128 + m] = f2b(a1 * inv);
    U[((size_t)i * 3 + 2) * 128 + m] = f2b(a2 * inv);
}

// ---------------------------------------------------------------------------
// vnorm from bf16 vfeat -> bf16
// ---------------------------------------------------------------------------
__global__ __launch_bounds__(256) void vnorm_kernel(
    const u16* __restrict__ vf16, u16* __restrict__ vn)
{
    int i = blockIdx.x, d = threadIdx.x;
    float v0 = b2f(vf16[((size_t)i * 3 + 0) * 256 + d]);
    float v1 = b2f(vf16[((size_t)i * 3 + 1) * 256 + d]);
    float v2 = b2f(vf16[((size_t)i * 3 + 2) * 256 + d]);
    vn[(size_t)i * 256 + d] = f2b(sqrtf(v0 * v0 + v1 * v1 + v2 * v2 + 1e-8f));
}

// ---------------------------------------------------------------------------
// h16 = bf16(layernorm(h16 + add) * gamma)
// ---------------------------------------------------------------------------
__global__ __launch_bounds__(256) void ln_kernel(
    u16* __restrict__ h16, const float* __restrict__ add,
    const float* __restrict__ gamma_l)
{
    __shared__ float lds[4];
    int i = blockIdx.x, d = threadIdx.x;
    size_t idx = (size_t)i * 256 + d;
    float x = b2f(h16[idx]) + add[idx];
    float s = x;
    #pragma unroll
    for (int off = 32; off; off >>= 1) s += __shfl_xor(s, off);
    if ((d & 63) == 0) lds[d >> 6] = s;
    __syncthreads();
    float mu = (lds[0] + lds[1] + lds[2] + lds[3]) * (1.0f / 256.0f);
    __syncthreads();
    float xc = x - mu;
    float v = xc * xc;
    #pragma unroll
    for (int off = 32; off; off >>= 1) v += __shfl_xor(v, off);
    if ((d & 63) == 0) lds[d >> 6] = v;
    __syncthreads();
    float var = (lds[0] + lds[1] + lds[2] + lds[3]) * (1.0f / 256.0f);
    h16[idx] = f2b(xc * rsqrtf(var + 1e-5f) * gamma_l[d]);
}

// ---------------------------------------------------------------------------
// Graph pooling (h bf16)
// ---------------------------------------------------------------------------
__global__ __launch_bounds__(256) void pool_kernel(
    const u16* __restrict__ h16, const float* __restrict__ w_att,
    const int* __restrict__ gptr, u16* __restrict__ pooled)
{
    __shared__ float lds[4];
    int g = blockIdx.x, d = threadIdx.x;
    float wa = w_att[d];
    int n0 = gptr[g], n1 = gptr[g + 1];
    float M = -1e30f, S = 0.f, acc = 0.f;
    for (int i = n0; i < n1; ++i) {
        float hv = b2f(h16[(size_t)i * 256 + d]);
        float p = hv * wa;
        #pragma unroll
        for (int off = 32; off; off >>= 1) p += __shfl_xor(p, off);
        if ((d & 63) == 0) lds[d >> 6] = p;
        __syncthreads();
        float logit = lds[0] + lds[1] + lds[2] + lds[3];
        __syncthreads();
        float nM = fmaxf(M, logit);
        float sc = __expf(M - nM);
        float w  = __expf(logit - nM);
        S = S * sc + w;
        acc = acc * sc + w * hv;
        M = nM;
    }
    pooled[(size_t)g * 256 + d] = f2b(acc / (S + 1e-12f));
}

// ---------------------------------------------------------------------------
extern "C" void kernel_launch(void* const* d_in, const int* in_sizes, int n_in,
                              void* d_out, int out_size, void* d_ws, size_t ws_size,
                              hipStream_t stream)
{
    const float* pos   = (const float*)d_in[0];
    const int*   z     = (const int*)d_in[1];
    const int*   batch = (const int*)d_in[2];
    const int*   ei    = (const int*)d_in[3];
    const float* emb   = (const float*)d_in[4];
    const float* W_in  = (const float*)d_in[5];
    const float* b_in  = (const float*)d_in[6];
    const float* Wq    = (const float*)d_in[7];
    const float* Wk    = (const float*)d_in[8];
    const float* Wv    = (const float*)d_in[9];
    const float* W_rbf = (const float*)d_in[10];
    const float* W_msg = (const float*)d_in[11];
    const float* W_vg  = (const float*)d_in[12];
    const float* W_vs  = (const float*)d_in[13];
    const float* W_nd  = (const float*)d_in[14];
    const float* b_nd  = (const float*)d_in[15];
    const float* gam   = (const float*)d_in[16];
    const float* watt  = (const float*)d_in[17];
    const float* W_out = (const float*)d_in[18];
    const float* b_out = (const float*)d_in[19];

    const int N = in_sizes[0] / 3;      // 20000
    const int E = in_sizes[3] / 2;      // 320000
    const int G = out_size / 512;       // 500

    char* ws = (char*)d_ws;
    size_t o = 0;
    auto alloc = [&](size_t bytes) -> char* {
        o = (o + 255) & ~(size_t)255;
        char* r = ws + o;
        o += bytes;
        return r;
    };
    float4* f_eg   = (float4*)alloc((size_t)E * 16);               //  5.1 MB
    u16*   h16     = (u16*)  alloc((size_t)N * 256 * 2);           // 10.2 MB
    u16*   vf16    = (u16*)  alloc((size_t)N * 3 * 256 * 2);       // 30.7 MB
    u16*   q16     = (u16*)  alloc((size_t)N * 128 * 2);           //  5.1 MB
    u16*   kv8     = (u16*)  alloc((size_t)N * 128 * 2);           //  5.1 MB (fp8 pairs)
    u16*   umb     = (u16*)  alloc((size_t)N * 4 * 128 * 2);       // 20.5 MB
    u16*   b1_16   = (u16*)  alloc((size_t)N * 256 * 2);           // 10.2 MB
    float* f_b2    = (float*)alloc((size_t)N * 256 * 4);           // 20.5 MB
    u16*   vn16    = (u16*)  alloc((size_t)N * 256 * 2);           // 10.2 MB
    u16*   pool16  = (u16*)  alloc((size_t)G * 256 * 2);
    float* f_table = (float*)alloc((size_t)4 * 4097 * 128 * 4);    //  8.4 MB
    const size_t LS = 384 * 256 + 2 * (256 * 128) + 2 * (256 * 256);
    const size_t OFF_QKV = 0, OFF_VG = 384 * 256, OFF_MSG = OFF_VG + 256 * 128,
                 OFF_ND = OFF_MSG + 256 * 128, OFF_VS = OFF_ND + 256 * 256;
    const size_t OFF_OUT = LS * 4;
    u16* whi = (u16*)alloc((LS * 4 + 512 * 256) * sizeof(u16));
    u16* wlo = (u16*)alloc((LS * 4 + 512 * 256) * sizeof(u16));
    int* i_deg  = (int*)alloc((size_t)N * 4);
    int* i_rowp = (int*)alloc((size_t)(N + 1) * 4);
    int* i_cur  = (int*)alloc((size_t)(N + 1) * 4);
    int* i_perm = (int*)alloc((size_t)E * 4);
    int* i_gcnt = (int*)alloc((size_t)G * 4);
    int* i_gptr = (int*)alloc((size_t)(G + 1) * 4);
    // total ~134 MB

    u16* U16   = umb;                         // [3N,128]
    u16* msg16 = umb + (size_t)3 * N * 128;   // [N,128]

    // ---- weight pre-pass descriptor ----
    TDesc td;
    int idx = 0;
    for (int l = 0; l < 4; ++l) {
        u16* bh = whi + (size_t)l * LS;
        u16* bl = wlo + (size_t)l * LS;
        td.e[idx++] = { Wq   + (size_t)l * 256 * 128, bh + OFF_QKV,             bl + OFF_QKV,             256, 128 };
        td.e[idx++] = { Wk   + (size_t)l * 256 * 128, bh + OFF_QKV + 128 * 256, bl + OFF_QKV + 128 * 256, 256, 128 };
        td.e[idx++] = { Wv   + (size_t)l * 256 * 128, bh + OFF_QKV + 256 * 256, bl + OFF_QKV + 256 * 256, 256, 128 };
        td.e[idx++] = { W_vg + (size_t)l * 128 * 256, bh + OFF_VG,  bl + OFF_VG,  128, 256 };
        td.e[idx++] = { W_msg+ (size_t)l * 128 * 256, bh + OFF_MSG, bl + OFF_MSG, 128, 256 };
        td.e[idx++] = { W_nd + (size_t)l * 256 * 256, bh + OFF_ND,  bl + OFF_ND,  256, 256 };
        td.e[idx++] = { W_vs + (size_t)l * 256 * 256, bh + OFF_VS,  bl + OFF_VS,  256, 256 };
    }
    td.e[idx++] = { W_out, whi + OFF_OUT, wlo + OFF_OUT, 256, 512 };

    // ---- setup ----
    zero_i32<<<(N + 255) / 256, 256, 0, stream>>>(i_deg, N);
    zero_i32<<<(G + 255) / 256, 256, 0, stream>>>(i_gcnt, G);
    transpose_split<<<dim3(128, 29), 256, 0, stream>>>(td);
    build_rbf_table<<<dim3(4097, 4), 128, 0, stream>>>(W_rbf, f_table);

    hist_edges<<<(E + 255) / 256, 256, 0, stream>>>(ei, i_deg, E);
    scan_kernel<<<1, 1024, 0, stream>>>(i_deg, N, i_rowp, i_cur);
    scatter_kernel<<<(E + 255) / 256, 256, 0, stream>>>(ei, i_cur, i_perm, E);
    hist_nodes<<<(N + 255) / 256, 256, 0, stream>>>(batch, i_gcnt, N);
    scan_kernel<<<1, 1024, 0, stream>>>(i_gcnt, G, i_gptr, (int*)nullptr);
    geom_kernel<<<(E + 255) / 256, 256, 0, stream>>>(pos, ei, f_eg, E);
    init_h_kernel<<<N, 256, 0, stream>>>(z, pos, emb, W_in, b_in, h16);

    const int MB  = (N + 127) / 128;          // 157
    const int MB3 = (3 * N + 127) / 128;      // 469

    // ---- layers ----
    for (int l = 0; l < 4; ++l) {
        u16* bh = whi + (size_t)l * LS;
        u16* bl = wlo + (size_t)l * LS;
        const float* bnd_l = b_nd + (size_t)l * 256;
        const float* gam_l = gam  + (size_t)l * 256;
        const float* tbl_l = f_table + (size_t)l * 4097 * 128;

        // q16/kv8 = h @ [Wq|Wk|Wv]   (mixed bf16 / fp8 epilogue)
        mfma_gemm<3,false,false,false><<<dim3(3, MB), 256, 0, stream>>>(
            h16, bh + OFF_QKV, bl + OFF_QKV, nullptr, q16, kv8, N, 256, 384);

        edge_attn_kernel<<<N, 128, 0, stream>>>(i_rowp, i_perm, ei, q16, kv8,
                                                f_eg, tbl_l, msg16, U16);

        // vfeat (+)= U @ W_vgate   (bf16 accumulate; layer0 plain write)
        if (l == 0)
            mfma_gemm<1,false,false,false><<<dim3(2, MB3), 256, 0, stream>>>(
                U16, bh + OFF_VG, bl + OFF_VG, nullptr, vf16, nullptr, 3 * N, 128, 256);
        else
            mfma_gemm<2,false,false,false><<<dim3(2, MB3), 256, 0, stream>>>(
                U16, bh + OFF_VG, bl + OFF_VG, nullptr, vf16, nullptr, 3 * N, 128, 256);

        // b1 = bf16(gelu(msg @ W_msg))
        mfma_gemm<1,false,false,true><<<dim3(2, MB), 256, 0, stream>>>(
            msg16, bh + OFF_MSG, bl + OFF_MSG, nullptr, b1_16, nullptr, N, 128, 256);
        // b2 = gelu(b1 @ W_node + b_node)   f32
        mfma_gemm<0,false,true,true><<<dim3(2, MB), 256, 0, stream>>>(
            b1_16, bh + OFF_ND, bl + OFF_ND, bnd_l, f_b2, nullptr, N, 256, 256);
        // vn16 = bf16(vnorm(vfeat))
        vnorm_kernel<<<N, 256, 0, stream>>>(vf16, vn16);
        // b2 += vnorm @ W_vs
        mfma_gemm<0,true,false,false><<<dim3(2, MB), 256, 0, stream>>>(
            vn16, bh + OFF_VS, bl + OFF_VS, nullptr, f_b2, nullptr, N, 256, 256);

        ln_kernel<<<N, 256, 0, stream>>>(h16, f_b2, gam_l);
    }

    // ---- readout ----
    pool_kernel<<<G, 256, 0, stream>>>(h16, watt, i_gptr, pool16);
    mfma_gemm<0,false,true,false><<<dim3(4, (G + 127) / 128), 256, 0, stream>>>(
        pool16, whi + OFF_OUT, wlo + OFF_OUT, b_out, (float*)d_out, nullptr, G, 256, 512);
}

// Round 8
// 1030.574 us; speedup vs baseline: 1.3718x; 1.1027x over previous
//
#include <hip/hip_runtime.h>
#include <math.h>

typedef unsigned char  u8;
typedef unsigned short u16;
typedef unsigned int   u32;
typedef __attribute__((ext_vector_type(8))) unsigned short ushort8;
typedef __attribute__((ext_vector_type(4))) unsigned short ushort4v;
typedef __attribute__((ext_vector_type(8))) short short8v;   // 8 bf16 (4 VGPRs)
typedef __attribute__((ext_vector_type(4))) float f32x4;
typedef __attribute__((ext_vector_type(2))) float f32x2;

__device__ __forceinline__ float gelu_f(float x) {
    const float c = 0.7978845608028654f;   // sqrt(2/pi)
    float x3 = x * x * x;
    float t = tanhf(c * (x + 0.044715f * x3));
    return 0.5f * x * (1.0f + t);
}

// f32 -> bf16 RNE
__device__ __forceinline__ u16 f2b(float f) {
    u32 u = __float_as_uint(f);
    return (u16)((u + 0x7FFFu + ((u >> 16) & 1u)) >> 16);
}
__device__ __forceinline__ float b2f(u16 u) {
    return __uint_as_float(((u32)u) << 16);
}

// f32 -> fp8 e4m3fn (RNE, clamp 448, subnormal support) — software fallback
__device__ __forceinline__ u32 f2fp8_sw(float f) {
    u32 u = __float_as_uint(f);
    u32 s = (u >> 31) << 7;
    float af = fabsf(f);
    if (af >= 448.0f) return s | 0x7E;
    if (af < 0.015625f) {
        int m = __float2int_rn(af * 512.0f);
        if (m >= 8) return s | 0x08;
        return s | (u32)m;
    }
    u32 a = __float_as_uint(af);
    u32 r = a + 0xFFFFFu + ((a >> 20) & 1u);
    int e8 = (int)(r >> 23) - 120;
    u32 m3 = (r >> 20) & 7u;
    if (e8 >= 16) return s | 0x7E;
    return s | ((u32)e8 << 3) | m3;
}
__device__ __forceinline__ float fp8d_sw(u32 b) {
    u32 lo = b & 0x7Fu;
    u32 nb = (lo << 20) + 0x3C000000u;
    float n = __uint_as_float(nb | ((b & 0x80u) << 24));
    float sub = (float)(b & 7u) * 0.001953125f;
    sub = (b & 0x80u) ? -sub : sub;
    return (lo & 0x78u) ? n : sub;
}

// hw-accelerated encode (single value -> one fp8 byte)
__device__ __forceinline__ u8 f2fp8(float v) {
#if __has_builtin(__builtin_amdgcn_cvt_pk_fp8_f32)
    return (u8)(__builtin_amdgcn_cvt_pk_fp8_f32(v, v, 0, false) & 0xFF);
#else
    return (u8)f2fp8_sw(v);
#endif
}
// hw-accelerated decode of a packed (K,V) fp8 pair in the low u16
__device__ __forceinline__ f32x2 kvdec(u32 pair) {
#if __has_builtin(__builtin_amdgcn_cvt_pk_f32_fp8)
    return __builtin_amdgcn_cvt_pk_f32_fp8((int)pair, false);
#else
    f32x2 r;
    r[0] = fp8d_sw(pair & 0xFF);
    r[1] = fp8d_sw((pair >> 8) & 0xFF);
    return r;
#endif
}

// split f32 -> bf16 hi + lo
__device__ __forceinline__ void split_bf16(float f, u16& h, u16& l) {
    u32 u = __float_as_uint(f);
    u32 r = (u + 0x7FFFu + ((u >> 16) & 1u)) >> 16;
    h = (u16)r;
    float hf = __uint_as_float(r << 16);
    float d = f - hf;
    u32 u2 = __float_as_uint(d);
    l = (u16)((u2 + 0x7FFFu + ((u2 >> 16) & 1u)) >> 16);
}

// ---------------------------------------------------------------------------
__global__ __launch_bounds__(256) void zero_i32(int* __restrict__ p, int n) {
    int i = blockIdx.x * 256 + threadIdx.x;
    if (i < n) p[i] = 0;
}

// ---------------------------------------------------------------------------
// Weight pre-pass: transpose [K][N] f32 -> [N][K] split bf16 hi/lo
// ---------------------------------------------------------------------------
struct TEntry { const float* src; u16* dh; u16* dl; int K; int N; };
struct TDesc  { TEntry e[29]; };

__global__ __launch_bounds__(256) void transpose_split(TDesc desc) {
    __shared__ float tile[32][33];
    TEntry en = desc.e[blockIdx.y];
    int tk = en.K >> 5, tn = en.N >> 5;
    int bx = blockIdx.x;
    if (bx >= tk * tn) return;
    int k0 = (bx % tk) * 32, n0 = (bx / tk) * 32;
    int tx = threadIdx.x & 31, ty = threadIdx.x >> 5;
    #pragma unroll
    for (int yy = 0; yy < 32; yy += 8)
        tile[ty + yy][tx] = en.src[(size_t)(k0 + ty + yy) * en.N + (n0 + tx)];
    __syncthreads();
    #pragma unroll
    for (int yy = 0; yy < 32; yy += 8) {
        int n = n0 + ty + yy, k = k0 + tx;
        float f = tile[tx][ty + yy];
        u16 h, l;
        split_bf16(f, h, l);
        en.dh[(size_t)n * en.K + k] = h;
        en.dl[(size_t)n * en.K + k] = l;
    }
}

// ---------------------------------------------------------------------------
// RBF lookup tables (all 4 layers)
// ---------------------------------------------------------------------------
__global__ __launch_bounds__(128) void build_rbf_table(
    const float* __restrict__ W_rbf, float* __restrict__ table)
{
    int k = blockIdx.x, l = blockIdx.y, m = threadIdx.x;
    const float* Wrbf_l = W_rbf + (size_t)l * 32 * 128;
    float* tbl = table + (size_t)l * 4097 * 128;
    const float PI = 3.14159265358979323846f;
    float d = fmaxf((float)k * (6.0f / 4096.0f), 1e-9f);
    float th = d * (PI / 6.0f);
    float s1, c1;
    __sincosf(th, &s1, &c1);
    float env = 0.5f * c1 + 0.5f;
    float invd = 1.0f / d;
    float two_c = 2.0f * c1;
    float sp = 0.f, sc = s1, dot = 0.f;
    #pragma unroll
    for (int r = 0; r < 32; ++r) {
        dot = fmaf(sc, Wrbf_l[r * 128 + m], dot);
        float sn = fmaf(two_c, sc, -sp);
        sp = sc; sc = sn;
    }
    tbl[(size_t)k * 128 + m] = dot * invd * env;
}

// ---------------------------------------------------------------------------
// MFMA GEMM. A bf16 [M][K]; BH (and BL if SPLITB) pre-transposed bf16 [N][K].
// C ~= A * (Bh [+ Bl]). Block 128x128, BK=32, 4 waves.
// OMODE: 0 f32 out (ACCUM f32 +=), 1 bf16 out, 2 bf16 out + bf16 accum,
//        3 qkv mixed (Q bf16 / K,V fp8 pairs)
// ---------------------------------------------------------------------------
template<int OMODE, bool ACCUM, bool BIAS, bool DOGELU, bool SPLITB>
__global__ __launch_bounds__(256) void mfma_gemm(
    const u16* __restrict__ A, const u16* __restrict__ BH,
    const u16* __restrict__ BL, const float* __restrict__ bias,
    void* __restrict__ Cv, void* __restrict__ Cv2,
    int Mrows, int K, int Nc)
{
    __shared__ __align__(16) u16 sA [128][40];
    __shared__ __align__(16) u16 sBh[128][40];
    __shared__ __align__(16) u16 sBl[SPLITB ? 128 : 1][SPLITB ? 40 : 1];

    const int t = threadIdx.x;
    const int lane = t & 63, wid = t >> 6;
    const int r0 = blockIdx.y * 128, c0 = blockIdx.x * 128;
    const int wr = (wid >> 1) * 64, wc = (wid & 1) * 64;

    f32x4 acc[4][4] = {};

    const int srow = t >> 1;
    const int skc  = (t & 1) * 16;

    for (int k0 = 0; k0 < K; k0 += 32) {
        {
            int gr = r0 + srow;
            ushort8 h0, h1;
            if (gr < Mrows) {
                const u16* p = A + (size_t)gr * K + (k0 + skc);
                h0 = *(const ushort8*)p;
                h1 = *(const ushort8*)(p + 8);
            } else {
                #pragma unroll
                for (int j = 0; j < 8; ++j) { h0[j] = 0; h1[j] = 0; }
            }
            *(ushort8*)&sA[srow][skc]     = h0;
            *(ushort8*)&sA[srow][skc + 8] = h1;
        }
        {
            int cg = c0 + srow;
            const u16* ph = BH + (size_t)cg * K + (k0 + skc);
            *(ushort8*)&sBh[srow][skc]     = *(const ushort8*)(ph);
            *(ushort8*)&sBh[srow][skc + 8] = *(const ushort8*)(ph + 8);
            if constexpr (SPLITB) {
                const u16* pl = BL + (size_t)cg * K + (k0 + skc);
                *(ushort8*)&sBl[srow][skc]     = *(const ushort8*)(pl);
                *(ushort8*)&sBl[srow][skc + 8] = *(const ushort8*)(pl + 8);
            }
        }
        __syncthreads();

        const int arow = wr + (lane & 15);
        const int koff = (lane >> 4) * 8;
        short8v ah[4];
        #pragma unroll
        for (int fr = 0; fr < 4; ++fr)
            ah[fr] = *(const short8v*)&sA[arow + fr * 16][koff];
        #pragma unroll
        for (int fc = 0; fc < 4; ++fc) {
            int bcol = wc + fc * 16 + (lane & 15);
            short8v bh = *(const short8v*)&sBh[bcol][koff];
            #pragma unroll
            for (int fr = 0; fr < 4; ++fr)
                acc[fr][fc] = __builtin_amdgcn_mfma_f32_16x16x32_bf16(ah[fr], bh, acc[fr][fc], 0, 0, 0);
            if constexpr (SPLITB) {
                short8v bl = *(const short8v*)&sBl[bcol][koff];
                #pragma unroll
                for (int fr = 0; fr < 4; ++fr)
                    acc[fr][fc] = __builtin_amdgcn_mfma_f32_16x16x32_bf16(ah[fr], bl, acc[fr][fc], 0, 0, 0);
            }
        }
        __syncthreads();
    }

    #pragma unroll
    for (int fr = 0; fr < 4; ++fr) {
        int rbase = r0 + wr + fr * 16 + (lane >> 4) * 4;
        #pragma unroll
        for (int fc = 0; fc < 4; ++fc) {
            int col = c0 + wc + fc * 16 + (lane & 15);
            #pragma unroll
            for (int reg = 0; reg < 4; ++reg) {
                int gr = rbase + reg;
                if (gr >= Mrows) continue;
                float v = acc[fr][fc][reg];
                if (BIAS)   v += bias[col];
                if (DOGELU) v = gelu_f(v);
                if (OMODE == 0) {
                    float* pc = (float*)Cv + (size_t)gr * Nc + col;
                    if (ACCUM) v += *pc;
                    *pc = v;
                } else if (OMODE == 1) {
                    ((u16*)Cv)[(size_t)gr * Nc + col] = f2b(v);
                } else if (OMODE == 2) {
                    u16* pc = (u16*)Cv + (size_t)gr * Nc + col;
                    *pc = f2b(v + b2f(*pc));
                } else {   // OMODE 3: qkv mixed
                    if (col < 128)
                        ((u16*)Cv)[(size_t)gr * 128 + col] = f2b(v);
                    else if (col < 256)
                        ((u8*)Cv2)[(size_t)gr * 256 + (col - 128) * 2] = f2fp8(v);
                    else
                        ((u8*)Cv2)[(size_t)gr * 256 + (col - 256) * 2 + 1] = f2fp8(v);
                }
            }
        }
    }
}

// ---------------------------------------------------------------------------
// CSR construction
// ---------------------------------------------------------------------------
__global__ void hist_edges(const int* __restrict__ ei, int* __restrict__ deg, int E_) {
    int e = blockIdx.x * 256 + threadIdx.x;
    if (e < E_) atomicAdd(&deg[ei[E_ + e]], 1);
}
__global__ void hist_nodes(const int* __restrict__ batch, int* __restrict__ gcnt, int n) {
    int i = blockIdx.x * 256 + threadIdx.x;
    if (i < n) atomicAdd(&gcnt[batch[i]], 1);
}

__global__ __launch_bounds__(1024) void scan_kernel(
    const int* __restrict__ cnt, int n, int* __restrict__ out, int* __restrict__ cursor)
{
    __shared__ int part[1024];
    int t = threadIdx.x;
    int chunk = (n + 1023) / 1024;
    int base = t * chunk;
    int s = 0;
    for (int k = 0; k < chunk; ++k) { int i = base + k; if (i < n) s += cnt[i]; }
    part[t] = s;
    __syncthreads();
    for (int off = 1; off < 1024; off <<= 1) {
        int u = (t >= off) ? part[t - off] : 0;
        __syncthreads();
        part[t] += u;
        __syncthreads();
    }
    int run = part[t] - s;
    for (int k = 0; k < chunk; ++k) {
        int i = base + k;
        if (i < n) {
            out[i] = run;
            if (cursor) cursor[i] = run;
            run += cnt[i];
        }
    }
    if (t == 1023) out[n] = part[1023];
}

__global__ void scatter_kernel(const int* __restrict__ ei, int* __restrict__ cursor,
                               int* __restrict__ perm, int E_) {
    int e = blockIdx.x * 256 + threadIdx.x;
    if (e < E_) {
        int p = atomicAdd(&cursor[ei[E_ + e]], 1);
        perm[p] = e;
    }
}

// ---------------------------------------------------------------------------
// Edge geometry packed: eg[e] = (ux, uy, uz, dist)
// ---------------------------------------------------------------------------
__global__ __launch_bounds__(256) void geom_kernel(
    const float* __restrict__ pos, const int* __restrict__ ei,
    float4* __restrict__ eg, int E_)
{
    int e = blockIdx.x * 256 + threadIdx.x;
    if (e >= E_) return;
    int s = ei[e], dn = ei[E_ + e];
    float dx = pos[s * 3 + 0] - pos[dn * 3 + 0];
    float dy = pos[s * 3 + 1] - pos[dn * 3 + 1];
    float dz = pos[s * 3 + 2] - pos[dn * 3 + 2];
    float d = sqrtf(dx * dx + dy * dy + dz * dz + 1e-12f);
    float invd = 1.0f / d;
    eg[e] = make_float4(dx * invd, dy * invd, dz * invd, d);
}

// ---------------------------------------------------------------------------
// h init -> bf16
// ---------------------------------------------------------------------------
__global__ __launch_bounds__(256) void init_h_kernel(
    const int* __restrict__ z, const float* __restrict__ pos,
    const float* __restrict__ emb, const float* __restrict__ W_in,
    const float* __restrict__ b_in, u16* __restrict__ h16)
{
    int i = blockIdx.x, d = threadIdx.x;
    float acc = b_in[d];
    int zi = z[i];
    #pragma unroll 8
    for (int k = 0; k < 32; ++k)
        acc += emb[zi * 32 + k] * W_in[k * 256 + d];
    #pragma unroll
    for (int x = 0; x < 3; ++x)
        acc += pos[i * 3 + x] * W_in[(32 + x) * 256 + d];
    h16[(size_t)i * 256 + d] = f2b(acc);
}

// ---------------------------------------------------------------------------
// Per-dst-node edge attention, online softmax, 4 edges/iter.
// q16 bf16 [N][128]; kv8 fp8 pairs [N][128] u16 (lo=K_m, hi=V_m) — hw decode.
// ---------------------------------------------------------------------------
__global__ __launch_bounds__(128) void edge_attn_kernel(
    const int* __restrict__ rowptr, const int* __restrict__ perm,
    const int* __restrict__ ei,
    const u16* __restrict__ q16, const u16* __restrict__ kv8,
    const float4* __restrict__ eg, const float* __restrict__ table_l,
    u16* __restrict__ msg, u16* __restrict__ U)
{
    int m = threadIdx.x;
    int i = blockIdx.x;

    int p0 = rowptr[i], p1 = rowptr[i + 1];
    float q = b2f(q16[(size_t)i * 128 + m]);
    float Mx = -1e30f, S = 0.f, am = 0.f, a0 = 0.f, a1 = 0.f, a2 = 0.f;

    for (int p = p0; p < p1; p += 4) {
        int rem = p1 - p;
        int pA = p;
        int pB = p + (rem > 1 ? 1 : 0);
        int pC = p + (rem > 2 ? 2 : 0);
        int pD = p + (rem > 3 ? 3 : 0);
        int eA = __builtin_amdgcn_readfirstlane(perm[pA]);
        int eB = __builtin_amdgcn_readfirstlane(perm[pB]);
        int eC = __builtin_amdgcn_readfirstlane(perm[pC]);
        int eD = __builtin_amdgcn_readfirstlane(perm[pD]);
        int jA = __builtin_amdgcn_readfirstlane(ei[eA]);
        int jB = __builtin_amdgcn_readfirstlane(ei[eB]);
        int jC = __builtin_amdgcn_readfirstlane(ei[eC]);
        int jD = __builtin_amdgcn_readfirstlane(ei[eD]);

        u32 kvA = kv8[(size_t)jA * 128 + m];
        u32 kvB = kv8[(size_t)jB * 128 + m];
        u32 kvC = kv8[(size_t)jC * 128 + m];
        u32 kvD = kv8[(size_t)jD * 128 + m];
        float4 gA = eg[eA], gB = eg[eB], gC = eg[eC], gD = eg[eD];

        f32x2 cA = kvdec(kvA), cB = kvdec(kvB), cC = kvdec(kvC), cD = kvdec(kvD);
        float kA = cA[0], vA = cA[1];
        float kB = cB[0], vB = cB[1];
        float kC = cC[0], vC = cC[1];
        float kD = cD[0], vD = cD[1];

        float prA = q * kA, prB = q * kB, prC = q * kC, prD = q * kD;
        #pragma unroll
        for (int off = 16; off; off >>= 1) {
            prA += __shfl_xor(prA, off);
            prB += __shfl_xor(prB, off);
            prC += __shfl_xor(prC, off);
            prD += __shfl_xor(prD, off);
        }
        const float iscale = 0.1767766952966369f;   // 1/sqrt(32)
        float lA = prA * iscale, lB = prB * iscale, lC = prC * iscale, lD = prD * iscale;

        auto LERP = [&](float d) -> float {
            if (d >= 6.0f) return 0.0f;
            float x = d * (4096.0f / 6.0f);
            int b = (int)x;
            float tf = x - (float)b;
            float f0 = table_l[(size_t)b * 128 + m];
            float f1 = table_l[(size_t)(b + 1) * 128 + m];
            return fmaf(tf, f1 - f0, f0);
        };
        float ewA = LERP(gA.w), ewB = LERP(gB.w), ewC = LERP(gC.w), ewD = LERP(gD.w);

        float Mb = fmaxf(Mx, fmaxf(fmaxf(lA, lB), fmaxf(lC, lD)));
        float sc = __expf(Mx - Mb);
        float wA = __expf(lA - Mb);
        float wB = (rem > 1) ? __expf(lB - Mb) : 0.f;
        float wC = (rem > 2) ? __expf(lC - Mb) : 0.f;
        float wD = (rem > 3) ? __expf(lD - Mb) : 0.f;
        float wvA = wA * vA * ewA, wvB = wB * vB * ewB;
        float wvC = wC * vC * ewC, wvD = wD * vD * ewD;
        S  = S  * sc + (wA + wB + wC + wD);
        am = am * sc + (wvA + wvB + wvC + wvD);
        a0 = a0 * sc + (wvA * gA.x + wvB * gB.x + wvC * gC.x + wvD * gD.x);
        a1 = a1 * sc + (wvA * gA.y + wvB * gB.y + wvC * gC.y + wvD * gD.y);
        a2 = a2 * sc + (wvA * gA.z + wvB * gB.z + wvC * gC.z + wvD * gD.z);
        Mx = Mb;
    }
    float inv = 1.0f / (S + 1e-12f);
    msg[(size_t)i * 128 + m] = f2b(am * inv);
    U[((size_t)i * 3 + 0) * 128 + m] = f2b(a0 * inv);
    U[((size_t)i * 3 + 1) * 128 + m] = f2b(a1 * inv);
    U[((size_t)i * 3 + 2) * 128 + m] = f2b(a2 * inv);
}

// ---------------------------------------------------------------------------
// vnorm from bf16 vfeat -> bf16
// ---------------------------------------------------------------------------
__global__ __launch_bounds__(256) void vnorm_kernel(
    const u16* __restrict__ vf16, u16* __restrict__ vn)
{
    int i = blockIdx.x, d = threadIdx.x;
    float v0 = b2f(vf16[((size_t)i * 3 + 0) * 256 + d]);
    float v1 = b2f(vf16[((size_t)i * 3 + 1) * 256 + d]);
    float v2 = b2f(vf16[((size_t)i * 3 + 2) * 256 + d]);
    vn[(size_t)i * 256 + d] = f2b(sqrtf(v0 * v0 + v1 * v1 + v2 * v2 + 1e-8f));
}

// ---------------------------------------------------------------------------
// h16 = bf16(layernorm(h16 + add) * gamma)
// ---------------------------------------------------------------------------
__global__ __launch_bounds__(256) void ln_kernel(
    u16* __restrict__ h16, const float* __restrict__ add,
    const float* __restrict__ gamma_l)
{
    __shared__ float lds[4];
    int i = blockIdx.x, d = threadIdx.x;
    size_t idx = (size_t)i * 256 + d;
    float x = b2f(h16[idx]) + add[idx];
    float s = x;
    #pragma unroll
    for (int off = 32; off; off >>= 1) s += __shfl_xor(s, off);
    if ((d & 63) == 0) lds[d >> 6] = s;
    __syncthreads();
    float mu = (lds[0] + lds[1] + lds[2] + lds[3]) * (1.0f / 256.0f);
    __syncthreads();
    float xc = x - mu;
    float v = xc * xc;
    #pragma unroll
    for (int off = 32; off; off >>= 1) v += __shfl_xor(v, off);
    if ((d & 63) == 0) lds[d >> 6] = v;
    __syncthreads();
    float var = (lds[0] + lds[1] + lds[2] + lds[3]) * (1.0f / 256.0f);
    h16[idx] = f2b(xc * rsqrtf(var + 1e-5f) * gamma_l[d]);
}

// ---------------------------------------------------------------------------
// Graph pooling, wave-parallel: block = graph, wave w handles nodes n0+w+4k,
// lane holds 4 channels. Online-softmax per wave, LDS merge at the end.
// ---------------------------------------------------------------------------
__global__ __launch_bounds__(256) void pool_kernel(
    const u16* __restrict__ h16, const float* __restrict__ w_att,
    const int* __restrict__ gptr, u16* __restrict__ pooled)
{
    __shared__ float sM[4], sS[4];
    __shared__ float sAcc[4][256];
    int g = blockIdx.x;
    int t = threadIdx.x, w = t >> 6, lane = t & 63;
    int c0 = lane * 4;
    int n0 = gptr[g], n1 = gptr[g + 1];
    float4 wa = *(const float4*)(w_att + c0);
    float M = -1e30f, S = 0.f, a0 = 0.f, a1 = 0.f, a2 = 0.f, a3 = 0.f;
    for (int i = n0 + w; i < n1; i += 4) {
        ushort4v hv = *(const ushort4v*)(h16 + (size_t)i * 256 + c0);
        float h0 = b2f(hv[0]), h1 = b2f(hv[1]), h2 = b2f(hv[2]), h3 = b2f(hv[3]);
        float p = h0 * wa.x + h1 * wa.y + h2 * wa.z + h3 * wa.w;
        #pragma unroll
        for (int off = 32; off; off >>= 1) p += __shfl_xor(p, off);
        float nM = fmaxf(M, p);
        float sc = __expf(M - nM), wg = __expf(p - nM);
        S = S * sc + wg;
        a0 = a0 * sc + wg * h0;
        a1 = a1 * sc + wg * h1;
        a2 = a2 * sc + wg * h2;
        a3 = a3 * sc + wg * h3;
        M = nM;
    }
    sAcc[w][c0 + 0] = a0; sAcc[w][c0 + 1] = a1;
    sAcc[w][c0 + 2] = a2; sAcc[w][c0 + 3] = a3;
    if (lane == 0) { sM[w] = M; sS[w] = S; }
    __syncthreads();
    if (w == 0) {
        float Mg = fmaxf(fmaxf(sM[0], sM[1]), fmaxf(sM[2], sM[3]));
        float e0 = __expf(sM[0] - Mg), e1 = __expf(sM[1] - Mg);
        float e2 = __expf(sM[2] - Mg), e3 = __expf(sM[3] - Mg);
        float St = sS[0] * e0 + sS[1] * e1 + sS[2] * e2 + sS[3] * e3;
        float inv = 1.0f / (St + 1e-12f);
        #pragma unroll
        for (int c = 0; c < 4; ++c) {
            float v = sAcc[0][c0 + c] * e0 + sAcc[1][c0 + c] * e1
                    + sAcc[2][c0 + c] * e2 + sAcc[3][c0 + c] * e3;
            pooled[(size_t)g * 256 + c0 + c] = f2b(v * inv);
        }
    }
}

// ---------------------------------------------------------------------------
extern "C" void kernel_launch(void* const* d_in, const int* in_sizes, int n_in,
                              void* d_out, int out_size, void* d_ws, size_t ws_size,
                              hipStream_t stream)
{
    const float* pos   = (const float*)d_in[0];
    const int*   z     = (const int*)d_in[1];
    const int*   batch = (const int*)d_in[2];
    const int*   ei    = (const int*)d_in[3];
    const float* emb   = (const float*)d_in[4];
    const float* W_in  = (const float*)d_in[5];
    const float* b_in  = (const float*)d_in[6];
    const float* Wq    = (const float*)d_in[7];
    const float* Wk    = (const float*)d_in[8];
    const float* Wv    = (const float*)d_in[9];
    const float* W_rbf = (const float*)d_in[10];
    const float* W_msg = (const float*)d_in[11];
    const float* W_vg  = (const float*)d_in[12];
    const float* W_vs  = (const float*)d_in[13];
    const float* W_nd  = (const float*)d_in[14];
    const float* b_nd  = (const float*)d_in[15];
    const float* gam   = (const float*)d_in[16];
    const float* watt  = (const float*)d_in[17];
    const float* W_out = (const float*)d_in[18];
    const float* b_out = (const float*)d_in[19];

    const int N = in_sizes[0] / 3;      // 20000
    const int E = in_sizes[3] / 2;      // 320000
    const int G = out_size / 512;       // 500

    char* ws = (char*)d_ws;
    size_t o = 0;
    auto alloc = [&](size_t bytes) -> char* {
        o = (o + 255) & ~(size_t)255;
        char* r = ws + o;
        o += bytes;
        return r;
    };
    float4* f_eg   = (float4*)alloc((size_t)E * 16);
    u16*   h16     = (u16*)  alloc((size_t)N * 256 * 2);
    u16*   vf16    = (u16*)  alloc((size_t)N * 3 * 256 * 2);
    u16*   q16     = (u16*)  alloc((size_t)N * 128 * 2);
    u16*   kv8     = (u16*)  alloc((size_t)N * 128 * 2);
    u16*   umb     = (u16*)  alloc((size_t)N * 4 * 128 * 2);
    u16*   b1_16   = (u16*)  alloc((size_t)N * 256 * 2);
    float* f_b2    = (float*)alloc((size_t)N * 256 * 4);
    u16*   vn16    = (u16*)  alloc((size_t)N * 256 * 2);
    u16*   pool16  = (u16*)  alloc((size_t)G * 256 * 2);
    float* f_table = (float*)alloc((size_t)4 * 4097 * 128 * 4);
    const size_t LS = 384 * 256 + 2 * (256 * 128) + 2 * (256 * 256);
    const size_t OFF_QKV = 0, OFF_VG = 384 * 256, OFF_MSG = OFF_VG + 256 * 128,
                 OFF_ND = OFF_MSG + 256 * 128, OFF_VS = OFF_ND + 256 * 256;
    const size_t OFF_OUT = LS * 4;
    u16* whi = (u16*)alloc((LS * 4 + 512 * 256) * sizeof(u16));
    u16* wlo = (u16*)alloc((LS * 4 + 512 * 256) * sizeof(u16));
    int* i_deg  = (int*)alloc((size_t)N * 4);
    int* i_rowp = (int*)alloc((size_t)(N + 1) * 4);
    int* i_cur  = (int*)alloc((size_t)(N + 1) * 4);
    int* i_perm = (int*)alloc((size_t)E * 4);
    int* i_gcnt = (int*)alloc((size_t)G * 4);
    int* i_gptr = (int*)alloc((size_t)(G + 1) * 4);

    u16* U16   = umb;                         // [3N,128]
    u16* msg16 = umb + (size_t)3 * N * 128;   // [N,128]

    // ---- weight pre-pass descriptor ----
    TDesc td;
    int idx = 0;
    for (int l = 0; l < 4; ++l) {
        u16* bh = whi + (size_t)l * LS;
        u16* bl = wlo + (size_t)l * LS;
        td.e[idx++] = { Wq   + (size_t)l * 256 * 128, bh + OFF_QKV,             bl + OFF_QKV,             256, 128 };
        td.e[idx++] = { Wk   + (size_t)l * 256 * 128, bh + OFF_QKV + 128 * 256, bl + OFF_QKV + 128 * 256, 256, 128 };
        td.e[idx++] = { Wv   + (size_t)l * 256 * 128, bh + OFF_QKV + 256 * 256, bl + OFF_QKV + 256 * 256, 256, 128 };
        td.e[idx++] = { W_vg + (size_t)l * 128 * 256, bh + OFF_VG,  bl + OFF_VG,  128, 256 };
        td.e[idx++] = { W_msg+ (size_t)l * 128 * 256, bh + OFF_MSG, bl + OFF_MSG, 128, 256 };
        td.e[idx++] = { W_nd + (size_t)l * 256 * 256, bh + OFF_ND,  bl + OFF_ND,  256, 256 };
        td.e[idx++] = { W_vs + (size_t)l * 256 * 256, bh + OFF_VS,  bl + OFF_VS,  256, 256 };
    }
    td.e[idx++] = { W_out, whi + OFF_OUT, wlo + OFF_OUT, 256, 512 };

    // ---- setup ----
    zero_i32<<<(N + 255) / 256, 256, 0, stream>>>(i_deg, N);
    zero_i32<<<(G + 255) / 256, 256, 0, stream>>>(i_gcnt, G);
    transpose_split<<<dim3(128, 29), 256, 0, stream>>>(td);
    build_rbf_table<<<dim3(4097, 4), 128, 0, stream>>>(W_rbf, f_table);

    hist_edges<<<(E + 255) / 256, 256, 0, stream>>>(ei, i_deg, E);
    scan_kernel<<<1, 1024, 0, stream>>>(i_deg, N, i_rowp, i_cur);
    scatter_kernel<<<(E + 255) / 256, 256, 0, stream>>>(ei, i_cur, i_perm, E);
    hist_nodes<<<(N + 255) / 256, 256, 0, stream>>>(batch, i_gcnt, N);
    scan_kernel<<<1, 1024, 0, stream>>>(i_gcnt, G, i_gptr, (int*)nullptr);
    geom_kernel<<<(E + 255) / 256, 256, 0, stream>>>(pos, ei, f_eg, E);
    init_h_kernel<<<N, 256, 0, stream>>>(z, pos, emb, W_in, b_in, h16);

    const int MB  = (N + 127) / 128;          // 157
    const int MB3 = (3 * N + 127) / 128;      // 469

    // ---- layers ----
    for (int l = 0; l < 4; ++l) {
        u16* bh = whi + (size_t)l * LS;
        u16* bl = wlo + (size_t)l * LS;
        const float* bnd_l = b_nd + (size_t)l * 256;
        const float* gam_l = gam  + (size_t)l * 256;
        const float* tbl_l = f_table + (size_t)l * 4097 * 128;

        // q16/kv8 = h @ [Wq|Wk|Wv]   (bf16-only weights; mixed epilogue)
        mfma_gemm<3,false,false,false,false><<<dim3(3, MB), 256, 0, stream>>>(
            h16, bh + OFF_QKV, nullptr, nullptr, q16, kv8, N, 256, 384);

        edge_attn_kernel<<<N, 128, 0, stream>>>(i_rowp, i_perm, ei, q16, kv8,
                                                f_eg, tbl_l, msg16, U16);

        // vfeat (+)= U @ W_vgate   (bf16-only weights)
        if (l == 0)
            mfma_gemm<1,false,false,false,false><<<dim3(2, MB3), 256, 0, stream>>>(
                U16, bh + OFF_VG, nullptr, nullptr, vf16, nullptr, 3 * N, 128, 256);
        else
            mfma_gemm<2,false,false,false,false><<<dim3(2, MB3), 256, 0, stream>>>(
                U16, bh + OFF_VG, nullptr, nullptr, vf16, nullptr, 3 * N, 128, 256);

        // b1 = bf16(gelu(msg @ W_msg))   (bf16-only weights)
        mfma_gemm<1,false,false,true,false><<<dim3(2, MB), 256, 0, stream>>>(
            msg16, bh + OFF_MSG, nullptr, nullptr, b1_16, nullptr, N, 128, 256);
        // b2 = gelu(b1 @ W_node + b_node)   f32 (split weights)
        mfma_gemm<0,false,true,true,true><<<dim3(2, MB), 256, 0, stream>>>(
            b1_16, bh + OFF_ND, bl + OFF_ND, bnd_l, f_b2, nullptr, N, 256, 256);
        // vn16 = bf16(vnorm(vfeat))
        vnorm_kernel<<<N, 256, 0, stream>>>(vf16, vn16);
        // b2 += vnorm @ W_vs   (split weights)
        mfma_gemm<0,true,false,false,true><<<dim3(2, MB), 256, 0, stream>>>(
            vn16, bh + OFF_VS, bl + OFF_VS, nullptr, f_b2, nullptr, N, 256, 256);

        ln_kernel<<<N, 256, 0, stream>>>(h16, f_b2, gam_l);
    }

    // ---- readout ----
    pool_kernel<<<G, 256, 0, stream>>>(h16, watt, i_gptr, pool16);
    mfma_gemm<0,false,true,false,true><<<dim3(4, (G + 127) / 128), 256, 0, stream>>>(
        pool16, whi + OFF_OUT, wlo + OFF_OUT, b_out, (float*)d_out, nullptr, G, 256, 512);
}

// Round 10
// 955.675 us; speedup vs baseline: 1.4793x; 1.0784x over previous
//
#include <hip/hip_runtime.h>
#include <math.h>

typedef unsigned char  u8;
typedef unsigned short u16;
typedef unsigned int   u32;
typedef __attribute__((ext_vector_type(8))) unsigned short ushort8;
typedef __attribute__((ext_vector_type(4))) unsigned short ushort4v;
typedef __attribute__((ext_vector_type(8))) short short8v;   // 8 bf16 (4 VGPRs)
typedef __attribute__((ext_vector_type(4))) float f32x4;
typedef __attribute__((ext_vector_type(2))) float f32x2;

__device__ __forceinline__ float gelu_f(float x) {
    const float c = 0.7978845608028654f;   // sqrt(2/pi)
    float x3 = x * x * x;
    float t = tanhf(c * (x + 0.044715f * x3));
    return 0.5f * x * (1.0f + t);
}

__device__ __forceinline__ u16 f2b(float f) {
    u32 u = __float_as_uint(f);
    return (u16)((u + 0x7FFFu + ((u >> 16) & 1u)) >> 16);
}
__device__ __forceinline__ float b2f(u16 u) {
    return __uint_as_float(((u32)u) << 16);
}

// fp8 e4m3fn software fallback
__device__ __forceinline__ u32 f2fp8_sw(float f) {
    u32 u = __float_as_uint(f);
    u32 s = (u >> 31) << 7;
    float af = fabsf(f);
    if (af >= 448.0f) return s | 0x7E;
    if (af < 0.015625f) {
        int m = __float2int_rn(af * 512.0f);
        if (m >= 8) return s | 0x08;
        return s | (u32)m;
    }
    u32 a = __float_as_uint(af);
    u32 r = a + 0xFFFFFu + ((a >> 20) & 1u);
    int e8 = (int)(r >> 23) - 120;
    u32 m3 = (r >> 20) & 7u;
    if (e8 >= 16) return s | 0x7E;
    return s | ((u32)e8 << 3) | m3;
}
__device__ __forceinline__ float fp8d_sw(u32 b) {
    u32 lo = b & 0x7Fu;
    u32 nb = (lo << 20) + 0x3C000000u;
    float n = __uint_as_float(nb | ((b & 0x80u) << 24));
    float sub = (float)(b & 7u) * 0.001953125f;
    sub = (b & 0x80u) ? -sub : sub;
    return (lo & 0x78u) ? n : sub;
}
__device__ __forceinline__ u8 f2fp8(float v) {
#if __has_builtin(__builtin_amdgcn_cvt_pk_fp8_f32)
    return (u8)(__builtin_amdgcn_cvt_pk_fp8_f32(v, v, 0, false) & 0xFF);
#else
    return (u8)f2fp8_sw(v);
#endif
}
__device__ __forceinline__ f32x2 kvdec(u32 pair) {
#if __has_builtin(__builtin_amdgcn_cvt_pk_f32_fp8)
    return __builtin_amdgcn_cvt_pk_f32_fp8((int)pair, false);
#else
    f32x2 r;
    r[0] = fp8d_sw(pair & 0xFF);
    r[1] = fp8d_sw((pair >> 8) & 0xFF);
    return r;
#endif
}

__device__ __forceinline__ void split_bf16(float f, u16& h, u16& l) {
    u32 u = __float_as_uint(f);
    u32 r = (u + 0x7FFFu + ((u >> 16) & 1u)) >> 16;
    h = (u16)r;
    float hf = __uint_as_float(r << 16);
    float d = f - hf;
    u32 u2 = __float_as_uint(d);
    l = (u16)((u2 + 0x7FFFu + ((u2 >> 16) & 1u)) >> 16);
}

// bijective XCD-chunked swizzle (m204)
__device__ __forceinline__ int xcd_swz(int orig, int nwg) {
    int q8 = nwg >> 3, r8 = nwg & 7;
    int xcd = orig & 7, ii = orig >> 3;
    return (xcd < r8 ? xcd * (q8 + 1) : r8 * (q8 + 1) + (xcd - r8) * q8) + ii;
}

// ---------------------------------------------------------------------------
__global__ __launch_bounds__(256) void zero_i32(int* __restrict__ p, int n) {
    int i = blockIdx.x * 256 + threadIdx.x;
    if (i < n) p[i] = 0;
}

// ---------------------------------------------------------------------------
// Weight pre-pass: transpose [K][N] f32 -> [N][K] split bf16 hi/lo
// ---------------------------------------------------------------------------
struct TEntry { const float* src; u16* dh; u16* dl; int K; int N; };
struct TDesc  { TEntry e[29]; };

__global__ __launch_bounds__(256) void transpose_split(TDesc desc) {
    __shared__ float tile[32][33];
    TEntry en = desc.e[blockIdx.y];
    int tk = en.K >> 5, tn = en.N >> 5;
    int bx = blockIdx.x;
    if (bx >= tk * tn) return;
    int k0 = (bx % tk) * 32, n0 = (bx / tk) * 32;
    int tx = threadIdx.x & 31, ty = threadIdx.x >> 5;
    #pragma unroll
    for (int yy = 0; yy < 32; yy += 8)
        tile[ty + yy][tx] = en.src[(size_t)(k0 + ty + yy) * en.N + (n0 + tx)];
    __syncthreads();
    #pragma unroll
    for (int yy = 0; yy < 32; yy += 8) {
        int n = n0 + ty + yy, k = k0 + tx;
        float f = tile[tx][ty + yy];
        u16 h, l;
        split_bf16(f, h, l);
        en.dh[(size_t)n * en.K + k] = h;
        en.dl[(size_t)n * en.K + k] = l;
    }
}

// ---------------------------------------------------------------------------
// RBF lookup tables, 4098 bins per layer
// ---------------------------------------------------------------------------
__global__ __launch_bounds__(128) void build_rbf_table(
    const float* __restrict__ W_rbf, float* __restrict__ table)
{
    int k = blockIdx.x, l = blockIdx.y, m = threadIdx.x;
    const float* Wrbf_l = W_rbf + (size_t)l * 32 * 128;
    float* tbl = table + (size_t)l * 4098 * 128;
    const float PI = 3.14159265358979323846f;
    float d = fmaxf((float)k * (6.0f / 4096.0f), 1e-9f);
    float th = d * (PI / 6.0f);
    float s1, c1;
    __sincosf(th, &s1, &c1);
    float env = (d < 6.0f) ? (0.5f * c1 + 0.5f) : 0.0f;
    float invd = 1.0f / d;
    float two_c = 2.0f * c1;
    float sp = 0.f, sc = s1, dot = 0.f;
    #pragma unroll
    for (int r = 0; r < 32; ++r) {
        dot = fmaf(sc, Wrbf_l[r * 128 + m], dot);
        float sn = fmaf(two_c, sc, -sp);
        sp = sc; sc = sn;
    }
    tbl[(size_t)k * 128 + m] = dot * invd * env;
}

// ---------------------------------------------------------------------------
// MFMA GEMM, 1D swizzled grid. A bf16 [M][K]; BH (+BL) transposed bf16 [N][K].
// OMODE: 0 f32 out (ACCUM f32 +=), 1 bf16 out, 2 bf16 out + bf16 accum,
//        3 qkv mixed (Q bf16 / K,V fp8 pairs)
// ---------------------------------------------------------------------------
template<int OMODE, bool ACCUM, bool BIAS, bool DOGELU, bool SPLITB>
__global__ __launch_bounds__(256) void mfma_gemm(
    const u16* __restrict__ A, const u16* __restrict__ BH,
    const u16* __restrict__ BL, const float* __restrict__ bias,
    void* __restrict__ Cv, void* __restrict__ Cv2,
    int Mrows, int K, int Nc, int gx)
{
    __shared__ __align__(16) u16 sA [128][40];
    __shared__ __align__(16) u16 sBh[128][40];
    __shared__ __align__(16) u16 sBl[SPLITB ? 128 : 1][SPLITB ? 40 : 1];

    const int wg = xcd_swz(blockIdx.x, gridDim.x);
    const int r0 = (wg / gx) * 128, c0 = (wg % gx) * 128;

    const int t = threadIdx.x;
    const int lane = t & 63, wid = t >> 6;
    const int wr = (wid >> 1) * 64, wc = (wid & 1) * 64;

    f32x4 acc[4][4] = {};

    const int srow = t >> 1;
    const int skc  = (t & 1) * 16;

    for (int k0 = 0; k0 < K; k0 += 32) {
        {
            int gr = r0 + srow;
            ushort8 h0, h1;
            if (gr < Mrows) {
                const u16* p = A + (size_t)gr * K + (k0 + skc);
                h0 = *(const ushort8*)p;
                h1 = *(const ushort8*)(p + 8);
            } else {
                #pragma unroll
                for (int j = 0; j < 8; ++j) { h0[j] = 0; h1[j] = 0; }
            }
            *(ushort8*)&sA[srow][skc]     = h0;
            *(ushort8*)&sA[srow][skc + 8] = h1;
        }
        {
            int cg = c0 + srow;
            const u16* ph = BH + (size_t)cg * K + (k0 + skc);
            *(ushort8*)&sBh[srow][skc]     = *(const ushort8*)(ph);
            *(ushort8*)&sBh[srow][skc + 8] = *(const ushort8*)(ph + 8);
            if constexpr (SPLITB) {
                const u16* pl = BL + (size_t)cg * K + (k0 + skc);
                *(ushort8*)&sBl[srow][skc]     = *(const ushort8*)(pl);
                *(ushort8*)&sBl[srow][skc + 8] = *(const ushort8*)(pl + 8);
            }
        }
        __syncthreads();

        const int arow = wr + (lane & 15);
        const int koff = (lane >> 4) * 8;
        short8v ah[4];
        #pragma unroll
        for (int fr = 0; fr < 4; ++fr)
            ah[fr] = *(const short8v*)&sA[arow + fr * 16][koff];
        #pragma unroll
        for (int fc = 0; fc < 4; ++fc) {
            int bcol = wc + fc * 16 + (lane & 15);
            short8v bh = *(const short8v*)&sBh[bcol][koff];
            #pragma unroll
            for (int fr = 0; fr < 4; ++fr)
                acc[fr][fc] = __builtin_amdgcn_mfma_f32_16x16x32_bf16(ah[fr], bh, acc[fr][fc], 0, 0, 0);
            if constexpr (SPLITB) {
                short8v bl = *(const short8v*)&sBl[bcol][koff];
                #pragma unroll
                for (int fr = 0; fr < 4; ++fr)
                    acc[fr][fc] = __builtin_amdgcn_mfma_f32_16x16x32_bf16(ah[fr], bl, acc[fr][fc], 0, 0, 0);
            }
        }
        __syncthreads();
    }

    #pragma unroll
    for (int fr = 0; fr < 4; ++fr) {
        int rbase = r0 + wr + fr * 16 + (lane >> 4) * 4;
        #pragma unroll
        for (int fc = 0; fc < 4; ++fc) {
            int col = c0 + wc + fc * 16 + (lane & 15);
            #pragma unroll
            for (int reg = 0; reg < 4; ++reg) {
                int gr = rbase + reg;
                if (gr >= Mrows) continue;
                float v = acc[fr][fc][reg];
                if (BIAS)   v += bias[col];
                if (DOGELU) v = gelu_f(v);
                if (OMODE == 0) {
                    float* pc = (float*)Cv + (size_t)gr * Nc + col;
                    if (ACCUM) v += *pc;
                    *pc = v;
                } else if (OMODE == 1) {
                    ((u16*)Cv)[(size_t)gr * Nc + col] = f2b(v);
                } else if (OMODE == 2) {
                    u16* pc = (u16*)Cv + (size_t)gr * Nc + col;
                    *pc = f2b(v + b2f(*pc));
                } else {   // OMODE 3: qkv mixed
                    if (col < 128)
                        ((u16*)Cv)[(size_t)gr * 128 + col] = f2b(v);
                    else if (col < 256)
                        ((u8*)Cv2)[(size_t)gr * 256 + (col - 128) * 2] = f2fp8(v);
                    else
                        ((u8*)Cv2)[(size_t)gr * 256 + (col - 256) * 2 + 1] = f2fp8(v);
                }
            }
        }
    }
}

// ---------------------------------------------------------------------------
// Fused vs-GEMM + LayerNorm: h16 = bf16(LN(h16 + b2 + vn@Wvs) * gamma)
// A = vn16 [N][256] bf16, B split [256][256]. BM=128, BN=256, 512 threads.
// ---------------------------------------------------------------------------
__global__ __launch_bounds__(512) void vs_ln_kernel(
    const u16* __restrict__ A, const u16* __restrict__ BH,
    const u16* __restrict__ BL, const float* __restrict__ b2,
    const float* __restrict__ gamma_l, u16* __restrict__ h16, int Mrows)
{
    __shared__ __align__(16) u16 sA [128][40];
    __shared__ __align__(16) u16 sBh[256][40];
    __shared__ __align__(16) u16 sBl[256][40];
    __shared__ float sSum[128][4];
    __shared__ float sSq [128][4];

    const int r0 = blockIdx.x * 128;
    const int t = threadIdx.x;
    const int lane = t & 63, wid = t >> 6;          // 8 waves
    const int wr = (wid >> 2) * 64, wc = (wid & 3) * 64;

    f32x4 acc[4][4] = {};
    const int K = 256;
    const int srow = t >> 2;          // 0..127
    const int skc  = (t & 3) * 8;     // 0,8,16,24

    for (int k0 = 0; k0 < K; k0 += 32) {
        {
            int gr = r0 + srow;
            ushort8 h0;
            #pragma unroll
            for (int j = 0; j < 8; ++j) h0[j] = 0;
            if (gr < Mrows) h0 = *(const ushort8*)(A + (size_t)gr * K + k0 + skc);
            *(ushort8*)&sA[srow][skc] = h0;
        }
        {
            *(ushort8*)&sBh[srow][skc]       = *(const ushort8*)(BH + (size_t)srow * K + k0 + skc);
            *(ushort8*)&sBh[srow + 128][skc] = *(const ushort8*)(BH + (size_t)(srow + 128) * K + k0 + skc);
            *(ushort8*)&sBl[srow][skc]       = *(const ushort8*)(BL + (size_t)srow * K + k0 + skc);
            *(ushort8*)&sBl[srow + 128][skc] = *(const ushort8*)(BL + (size_t)(srow + 128) * K + k0 + skc);
        }
        __syncthreads();

        const int arow = wr + (lane & 15);
        const int koff = (lane >> 4) * 8;
        short8v ah[4];
        #pragma unroll
        for (int fr = 0; fr < 4; ++fr)
            ah[fr] = *(const short8v*)&sA[arow + fr * 16][koff];
        #pragma unroll
        for (int fc = 0; fc < 4; ++fc) {
            int bcol = wc + fc * 16 + (lane & 15);
            short8v bh = *(const short8v*)&sBh[bcol][koff];
            short8v bl = *(const short8v*)&sBl[bcol][koff];
            #pragma unroll
            for (int fr = 0; fr < 4; ++fr) {
                acc[fr][fc] = __builtin_amdgcn_mfma_f32_16x16x32_bf16(ah[fr], bh, acc[fr][fc], 0, 0, 0);
                acc[fr][fc] = __builtin_amdgcn_mfma_f32_16x16x32_bf16(ah[fr], bl, acc[fr][fc], 0, 0, 0);
            }
        }
        __syncthreads();
    }

    // epilogue: x = h_old + b2 + vsout; row stats over 256 cols, then LN
    float psum[4][4] = {}, psq[4][4] = {};
    #pragma unroll
    for (int fr = 0; fr < 4; ++fr) {
        #pragma unroll
        for (int fc = 0; fc < 4; ++fc) {
            int col = wc + fc * 16 + (lane & 15);
            #pragma unroll
            for (int reg = 0; reg < 4; ++reg) {
                int gr = r0 + wr + fr * 16 + (lane >> 4) * 4 + reg;
                float x = 0.f;
                if (gr < Mrows) {
                    size_t ix = (size_t)gr * 256 + col;
                    x = acc[fr][fc][reg] + b2[ix] + b2f(h16[ix]);
                }
                acc[fr][fc][reg] = x;
                psum[fr][reg] += x;
                psq[fr][reg]  = fmaf(x, x, psq[fr][reg]);
            }
        }
    }
    #pragma unroll
    for (int fr = 0; fr < 4; ++fr) {
        #pragma unroll
        for (int reg = 0; reg < 4; ++reg) {
            float s = psum[fr][reg], sq = psq[fr][reg];
            #pragma unroll
            for (int off = 8; off; off >>= 1) {
                s  += __shfl_xor(s, off);
                sq += __shfl_xor(sq, off);
            }
            psum[fr][reg] = s; psq[fr][reg] = sq;
        }
    }
    if ((lane & 15) == 0) {
        int qg = lane >> 4;
        #pragma unroll
        for (int fr = 0; fr < 4; ++fr) {
            #pragma unroll
            for (int reg = 0; reg < 4; ++reg) {
                int row = wr + fr * 16 + qg * 4 + reg;
                sSum[row][wc >> 6] = psum[fr][reg];
                sSq [row][wc >> 6] = psq[fr][reg];
            }
        }
    }
    __syncthreads();
    #pragma unroll
    for (int fr = 0; fr < 4; ++fr) {
        #pragma unroll
        for (int reg = 0; reg < 4; ++reg) {
            int row = wr + fr * 16 + (lane >> 4) * 4 + reg;
            int gr = r0 + row;
            if (gr >= Mrows) continue;
            float S = sSum[row][0] + sSum[row][1] + sSum[row][2] + sSum[row][3];
            float Q = sSq[row][0] + sSq[row][1] + sSq[row][2] + sSq[row][3];
            float mu = S * (1.0f / 256.0f);
            float var = fmaxf(Q * (1.0f / 256.0f) - mu * mu, 0.0f);
            float rs = rsqrtf(var + 1e-5f);
            #pragma unroll
            for (int fc = 0; fc < 4; ++fc) {
                int col = wc + fc * 16 + (lane & 15);
                float y = (acc[fr][fc][reg] - mu) * rs * gamma_l[col];
                h16[(size_t)gr * 256 + col] = f2b(y);
            }
        }
    }
}

// ---------------------------------------------------------------------------
// CSR construction
// ---------------------------------------------------------------------------
__global__ void hist_edges(const int* __restrict__ ei, int* __restrict__ deg, int E_) {
    int e = blockIdx.x * 256 + threadIdx.x;
    if (e < E_) atomicAdd(&deg[ei[E_ + e]], 1);
}
__global__ void hist_nodes(const int* __restrict__ batch, int* __restrict__ gcnt, int n) {
    int i = blockIdx.x * 256 + threadIdx.x;
    if (i < n) atomicAdd(&gcnt[batch[i]], 1);
}

__global__ __launch_bounds__(1024) void scan_kernel(
    const int* __restrict__ cnt, int n, int* __restrict__ out, int* __restrict__ cursor)
{
    __shared__ int part[1024];
    int t = threadIdx.x;
    int chunk = (n + 1023) / 1024;
    int base = t * chunk;
    int s = 0;
    for (int k = 0; k < chunk; ++k) { int i = base + k; if (i < n) s += cnt[i]; }
    part[t] = s;
    __syncthreads();
    for (int off = 1; off < 1024; off <<= 1) {
        int u = (t >= off) ? part[t - off] : 0;
        __syncthreads();
        part[t] += u;
        __syncthreads();
    }
    int run = part[t] - s;
    for (int k = 0; k < chunk; ++k) {
        int i = base + k;
        if (i < n) {
            out[i] = run;
            if (cursor) cursor[i] = run;
            run += cnt[i];
        }
    }
    if (t == 1023) out[n] = part[1023];
}

// perm payload: (edge id, src node)
__global__ void scatter_kernel(const int* __restrict__ ei, int* __restrict__ cursor,
                               int2* __restrict__ perm2, int E_) {
    int e = blockIdx.x * 256 + threadIdx.x;
    if (e < E_) {
        int p = atomicAdd(&cursor[ei[E_ + e]], 1);
        perm2[p] = make_int2(e, ei[e]);
    }
}

// ---------------------------------------------------------------------------
// Edge geometry packed: eg[e] = (ux, uy, uz, dist)
// ---------------------------------------------------------------------------
__global__ __launch_bounds__(256) void geom_kernel(
    const float* __restrict__ pos, const int* __restrict__ ei,
    float4* __restrict__ eg, int E_)
{
    int e = blockIdx.x * 256 + threadIdx.x;
    if (e >= E_) return;
    int s = ei[e], dn = ei[E_ + e];
    float dx = pos[s * 3 + 0] - pos[dn * 3 + 0];
    float dy = pos[s * 3 + 1] - pos[dn * 3 + 1];
    float dz = pos[s * 3 + 2] - pos[dn * 3 + 2];
    float d = sqrtf(dx * dx + dy * dy + dz * dz + 1e-12f);
    float invd = 1.0f / d;
    eg[e] = make_float4(dx * invd, dy * invd, dz * invd, d);
}

// ---------------------------------------------------------------------------
// h init -> bf16
// ---------------------------------------------------------------------------
__global__ __launch_bounds__(256) void init_h_kernel(
    const int* __restrict__ z, const float* __restrict__ pos,
    const float* __restrict__ emb, const float* __restrict__ W_in,
    const float* __restrict__ b_in, u16* __restrict__ h16)
{
    int i = blockIdx.x, d = threadIdx.x;
    float acc = b_in[d];
    int zi = z[i];
    #pragma unroll 8
    for (int k = 0; k < 32; ++k)
        acc += emb[zi * 32 + k] * W_in[k * 256 + d];
    #pragma unroll
    for (int x = 0; x < 3; ++x)
        acc += pos[i * 3 + x] * W_in[(32 + x) * 256 + d];
    h16[(size_t)i * 256 + d] = f2b(acc);
}

// ---------------------------------------------------------------------------
// Per-dst-node edge attention, online softmax, 8 edges/iter.
// q16 bf16 [N][128]; kv8 fp8 pairs [N][128]; perm2 = (e, src).
// ---------------------------------------------------------------------------
__global__ __launch_bounds__(128) void edge_attn_kernel(
    const int* __restrict__ rowptr, const int2* __restrict__ perm2,
    const u16* __restrict__ q16, const u16* __restrict__ kv8,
    const float4* __restrict__ eg, const float* __restrict__ table_l,
    u16* __restrict__ msg, u16* __restrict__ U)
{
    int m = threadIdx.x;
    int i = blockIdx.x;

    int p0 = rowptr[i], p1 = rowptr[i + 1];
    float q = b2f(q16[(size_t)i * 128 + m]);
    float Mx = -1e30f, S = 0.f, am = 0.f, a0 = 0.f, a1 = 0.f, a2 = 0.f;
    const float iscale = 0.1767766952966369f;   // 1/sqrt(32)

    for (int p = p0; p < p1; p += 8) {
        int rem = p1 - p;
        int ee[8], jj[8];
        #pragma unroll
        for (int u = 0; u < 8; ++u) {
            int pp = p + (u < rem ? u : 0);
            int2 pe = perm2[pp];
            ee[u] = __builtin_amdgcn_readfirstlane(pe.x);
            jj[u] = __builtin_amdgcn_readfirstlane(pe.y);
        }
        u32 kv[8];
        float4 g[8];
        #pragma unroll
        for (int u = 0; u < 8; ++u) {
            kv[u] = kv8[(size_t)jj[u] * 128 + m];
            g[u]  = eg[ee[u]];
        }
        float lg[8], vd[8];
        #pragma unroll
        for (int u = 0; u < 8; ++u) {
            f32x2 c = kvdec(kv[u]);
            vd[u] = c[1];
            float pr = q * c[0];
            #pragma unroll
            for (int off = 16; off; off >>= 1) pr += __shfl_xor(pr, off);
            lg[u] = pr * iscale;
        }
        float ew[8];
        #pragma unroll
        for (int u = 0; u < 8; ++u) {
            float x = fminf(g[u].w * (4096.0f / 6.0f), 4096.0f);
            int b = (int)x;
            float tf = x - (float)b;
            float f0 = table_l[(size_t)b * 128 + m];
            float f1 = table_l[(size_t)(b + 1) * 128 + m];
            ew[u] = fmaf(tf, f1 - f0, f0);
        }
        float Mb = Mx;
        #pragma unroll
        for (int u = 0; u < 8; ++u) Mb = fmaxf(Mb, lg[u]);
        float sc = __expf(Mx - Mb);
        float w[8];
        #pragma unroll
        for (int u = 0; u < 8; ++u)
            w[u] = (u < rem) ? __expf(lg[u] - Mb) : 0.f;
        float ws = 0.f, wvs = 0.f, wx = 0.f, wy = 0.f, wz = 0.f;
        #pragma unroll
        for (int u = 0; u < 8; ++u) {
            float wv = w[u] * vd[u] * ew[u];
            ws  += w[u];
            wvs += wv;
            wx = fmaf(wv, g[u].x, wx);
            wy = fmaf(wv, g[u].y, wy);
            wz = fmaf(wv, g[u].z, wz);
        }
        S  = S  * sc + ws;
        am = am * sc + wvs;
        a0 = a0 * sc + wx;
        a1 = a1 * sc + wy;
        a2 = a2 * sc + wz;
        Mx = Mb;
    }
    float inv = 1.0f / (S + 1e-12f);
    msg[(size_t)i * 128 + m] = f2b(am * inv);
    U[((size_t)i * 3 + 0) * 128 + m] = f2b(a0 * inv);
    U[((size_t)i * 3 + 1) * 128 + m] = f2b(a1 * inv);
    U[((size_t)i * 3 + 2) * 128 + m] = f2b(a2 * inv);
}

// ---------------------------------------------------------------------------
// vnorm from bf16 vfeat -> bf16
// ---------------------------------------------------------------------------
__global__ __launch_bounds__(256) void vnorm_kernel(
    const u16* __restrict__ vf16, u16* __restrict__ vn)
{
    int i = blockIdx.x, d = threadIdx.x;
    float v0 = b2f(vf16[((size_t)i * 3 + 0) * 256 + d]);
    float v1 = b2f(vf16[((size_t)i * 3 + 1) * 256 + d]);
    float v2 = b2f(vf16[((size_t)i * 3 + 2) * 256 + d]);
    vn[(size_t)i * 256 + d] = f2b(sqrtf(v0 * v0 + v1 * v1 + v2 * v2 + 1e-8f));
}

// ---------------------------------------------------------------------------
// Graph pooling, wave-parallel (block = graph)
// ---------------------------------------------------------------------------
__global__ __launch_bounds__(256) void pool_kernel(
    const u16* __restrict__ h16, const float* __restrict__ w_att,
    const int* __restrict__ gptr, u16* __restrict__ pooled)
{
    __shared__ float sM[4], sS[4];
    __shared__ float sAcc[4][256];
    int g = blockIdx.x;
    int t = threadIdx.x, w = t >> 6, lane = t & 63;
    int c0 = lane * 4;
    int n0 = gptr[g], n1 = gptr[g + 1];
    float4 wa = *(const float4*)(w_att + c0);
    float M = -1e30f, S = 0.f, a0 = 0.f, a1 = 0.f, a2 = 0.f, a3 = 0.f;
    for (int i = n0 + w; i < n1; i += 4) {
        ushort4v hv = *(const ushort4v*)(h16 + (size_t)i * 256 + c0);
        float h0 = b2f(hv[0]), h1 = b2f(hv[1]), h2 = b2f(hv[2]), h3 = b2f(hv[3]);
        float p = h0 * wa.x + h1 * wa.y + h2 * wa.z + h3 * wa.w;
        #pragma unroll
        for (int off = 32; off; off >>= 1) p += __shfl_xor(p, off);
        float nM = fmaxf(M, p);
        float sc = __expf(M - nM), wg = __expf(p - nM);
        S = S * sc + wg;
        a0 = a0 * sc + wg * h0;
        a1 = a1 * sc + wg * h1;
        a2 = a2 * sc + wg * h2;
        a3 = a3 * sc + wg * h3;
        M = nM;
    }
    sAcc[w][c0 + 0] = a0; sAcc[w][c0 + 1] = a1;
    sAcc[w][c0 + 2] = a2; sAcc[w][c0 + 3] = a3;
    if (lane == 0) { sM[w] = M; sS[w] = S; }
    __syncthreads();
    if (w == 0) {
        float Mg = fmaxf(fmaxf(sM[0], sM[1]), fmaxf(sM[2], sM[3]));
        float e0 = __expf(sM[0] - Mg), e1 = __expf(sM[1] - Mg);
        float e2 = __expf(sM[2] - Mg), e3 = __expf(sM[3] - Mg);
        float St = sS[0] * e0 + sS[1] * e1 + sS[2] * e2 + sS[3] * e3;
        float inv = 1.0f / (St + 1e-12f);
        #pragma unroll
        for (int c = 0; c < 4; ++c) {
            float v = sAcc[0][c0 + c] * e0 + sAcc[1][c0 + c] * e1
                    + sAcc[2][c0 + c] * e2 + sAcc[3][c0 + c] * e3;
            pooled[(size_t)g * 256 + c0 + c] = f2b(v * inv);
        }
    }
}

// ---------------------------------------------------------------------------
extern "C" void kernel_launch(void* const* d_in, const int* in_sizes, int n_in,
                              void* d_out, int out_size, void* d_ws, size_t ws_size,
                              hipStream_t stream)
{
    const float* pos   = (const float*)d_in[0];
    const int*   z     = (const int*)d_in[1];
    const int*   batch = (const int*)d_in[2];
    const int*   ei    = (const int*)d_in[3];
    const float* emb   = (const float*)d_in[4];
    const float* W_in  = (const float*)d_in[5];
    const float* b_in  = (const float*)d_in[6];
    const float* Wq    = (const float*)d_in[7];
    const float* Wk    = (const float*)d_in[8];
    const float* Wv    = (const float*)d_in[9];
    const float* W_rbf = (const float*)d_in[10];
    const float* W_msg = (const float*)d_in[11];
    const float* W_vg  = (const float*)d_in[12];
    const float* W_vs  = (const float*)d_in[13];
    const float* W_nd  = (const float*)d_in[14];
    const float* b_nd  = (const float*)d_in[15];
    const float* gam   = (const float*)d_in[16];
    const float* watt  = (const float*)d_in[17];
    const float* W_out = (const float*)d_in[18];
    const float* b_out = (const float*)d_in[19];

    const int N = in_sizes[0] / 3;      // 20000
    const int E = in_sizes[3] / 2;      // 320000
    const int G = out_size / 512;       // 500

    char* ws = (char*)d_ws;
    size_t o = 0;
    auto alloc = [&](size_t bytes) -> char* {
        o = (o + 255) & ~(size_t)255;
        char* r = ws + o;
        o += bytes;
        return r;
    };
    float4* f_eg   = (float4*)alloc((size_t)E * 16);
    u16*   h16     = (u16*)  alloc((size_t)N * 256 * 2);
    u16*   vf16    = (u16*)  alloc((size_t)N * 3 * 256 * 2);
    u16*   q16     = (u16*)  alloc((size_t)N * 128 * 2);
    u16*   kv8     = (u16*)  alloc((size_t)N * 128 * 2);
    u16*   umb     = (u16*)  alloc((size_t)N * 4 * 128 * 2);
    u16*   b1_16   = (u16*)  alloc((size_t)N * 256 * 2);
    float* f_b2    = (float*)alloc((size_t)N * 256 * 4);
    u16*   vn16    = (u16*)  alloc((size_t)N * 256 * 2);
    u16*   pool16  = (u16*)  alloc((size_t)G * 256 * 2);
    float* f_table = (float*)alloc((size_t)4 * 4098 * 128 * 4);
    const size_t LS = 384 * 256 + 2 * (256 * 128) + 2 * (256 * 256);
    const size_t OFF_QKV = 0, OFF_VG = 384 * 256, OFF_MSG = OFF_VG + 256 * 128,
                 OFF_ND = OFF_MSG + 256 * 128, OFF_VS = OFF_ND + 256 * 256;
    const size_t OFF_OUT = LS * 4;
    u16* whi = (u16*)alloc((LS * 4 + 512 * 256) * sizeof(u16));
    u16* wlo = (u16*)alloc((LS * 4 + 512 * 256) * sizeof(u16));
    int*  i_deg   = (int*)alloc((size_t)N * 4);
    int*  i_rowp  = (int*)alloc((size_t)(N + 1) * 4);
    int*  i_cur   = (int*)alloc((size_t)(N + 1) * 4);
    int2* i_perm2 = (int2*)alloc((size_t)E * 8);
    int*  i_gcnt  = (int*)alloc((size_t)G * 4);
    int*  i_gptr  = (int*)alloc((size_t)(G + 1) * 4);

    u16* U16   = umb;                         // [3N,128]
    u16* msg16 = umb + (size_t)3 * N * 128;   // [N,128]

    // ---- weight pre-pass descriptor ----
    TDesc td;
    int idx = 0;
    for (int l = 0; l < 4; ++l) {
        u16* bh = whi + (size_t)l * LS;
        u16* bl = wlo + (size_t)l * LS;
        td.e[idx++] = { Wq   + (size_t)l * 256 * 128, bh + OFF_QKV,             bl + OFF_QKV,             256, 128 };
        td.e[idx++] = { Wk   + (size_t)l * 256 * 128, bh + OFF_QKV + 128 * 256, bl + OFF_QKV + 128 * 256, 256, 128 };
        td.e[idx++] = { Wv   + (size_t)l * 256 * 128, bh + OFF_QKV + 256 * 256, bl + OFF_QKV + 256 * 256, 256, 128 };
        td.e[idx++] = { W_vg + (size_t)l * 128 * 256, bh + OFF_VG,  bl + OFF_VG,  128, 256 };
        td.e[idx++] = { W_msg+ (size_t)l * 128 * 256, bh + OFF_MSG, bl + OFF_MSG, 128, 256 };
        td.e[idx++] = { W_nd + (size_t)l * 256 * 256, bh + OFF_ND,  bl + OFF_ND,  256, 256 };
        td.e[idx++] = { W_vs + (size_t)l * 256 * 256, bh + OFF_VS,  bl + OFF_VS,  256, 256 };
    }
    td.e[idx++] = { W_out, whi + OFF_OUT, wlo + OFF_OUT, 256, 512 };

    // ---- setup ----
    zero_i32<<<(N + 255) / 256, 256, 0, stream>>>(i_deg, N);
    zero_i32<<<(G + 255) / 256, 256, 0, stream>>>(i_gcnt, G);
    transpose_split<<<dim3(128, 29), 256, 0, stream>>>(td);
    build_rbf_table<<<dim3(4098, 4), 128, 0, stream>>>(W_rbf, f_table);

    hist_edges<<<(E + 255) / 256, 256, 0, stream>>>(ei, i_deg, E);
    scan_kernel<<<1, 1024, 0, stream>>>(i_deg, N, i_rowp, i_cur);
    scatter_kernel<<<(E + 255) / 256, 256, 0, stream>>>(ei, i_cur, i_perm2, E);
    hist_nodes<<<(N + 255) / 256, 256, 0, stream>>>(batch, i_gcnt, N);
    scan_kernel<<<1, 1024, 0, stream>>>(i_gcnt, G, i_gptr, (int*)nullptr);
    geom_kernel<<<(E + 255) / 256, 256, 0, stream>>>(pos, ei, f_eg, E);
    init_h_kernel<<<N, 256, 0, stream>>>(z, pos, emb, W_in, b_in, h16);

    const int MB  = (N + 127) / 128;          // 157
    const int MB3 = (3 * N + 127) / 128;      // 469
    const int MBG = (G + 127) / 128;          // 4

    // ---- layers ----
    for (int l = 0; l < 4; ++l) {
        u16* bh = whi + (size_t)l * LS;
        u16* bl = wlo + (size_t)l * LS;
        const float* bnd_l = b_nd + (size_t)l * 256;
        const float* gam_l = gam  + (size_t)l * 256;
        const float* tbl_l = f_table + (size_t)l * 4098 * 128;

        // q16/kv8 = h @ [Wq|Wk|Wv]
        mfma_gemm<3,false,false,false,false><<<3 * MB, 256, 0, stream>>>(
            h16, bh + OFF_QKV, nullptr, nullptr, q16, kv8, N, 256, 384, 3);

        edge_attn_kernel<<<N, 128, 0, stream>>>(i_rowp, i_perm2, q16, kv8,
                                                f_eg, tbl_l, msg16, U16);

        // vfeat (+)= U @ W_vgate
        if (l == 0)
            mfma_gemm<1,false,false,false,false><<<2 * MB3, 256, 0, stream>>>(
                U16, bh + OFF_VG, nullptr, nullptr, vf16, nullptr, 3 * N, 128, 256, 2);
        else
            mfma_gemm<2,false,false,false,false><<<2 * MB3, 256, 0, stream>>>(
                U16, bh + OFF_VG, nullptr, nullptr, vf16, nullptr, 3 * N, 128, 256, 2);

        // b1 = bf16(gelu(msg @ W_msg))
        mfma_gemm<1,false,false,true,false><<<2 * MB, 256, 0, stream>>>(
            msg16, bh + OFF_MSG, nullptr, nullptr, b1_16, nullptr, N, 128, 256, 2);
        // b2 = gelu(b1 @ W_node + b_node)   f32 (split weights)
        mfma_gemm<0,false,true,true,true><<<2 * MB, 256, 0, stream>>>(
            b1_16, bh + OFF_ND, bl + OFF_ND, bnd_l, f_b2, nullptr, N, 256, 256, 2);
        // vn16 = bf16(vnorm(vfeat))
        vnorm_kernel<<<N, 256, 0, stream>>>(vf16, vn16);
        // h16 = LN(h16 + b2 + vn @ W_vs) * gamma    (fused, split weights)
        vs_ln_kernel<<<MB, 512, 0, stream>>>(
            vn16, bh + OFF_VS, bl + OFF_VS, f_b2, gam_l, h16, N);
    }

    // ---- readout ----
    pool_kernel<<<G, 256, 0, stream>>>(h16, watt, i_gptr, pool16);
    mfma_gemm<0,false,true,false,true><<<4 * MBG, 256, 0, stream>>>(
        pool16, whi + OFF_OUT, wlo + OFF_OUT, b_out, (float*)d_out, nullptr, G, 256, 512, 4);
}

// Round 11
// 834.633 us; speedup vs baseline: 1.6938x; 1.1450x over previous
//
#include <hip/hip_runtime.h>
#include <math.h>

typedef unsigned char  u8;
typedef unsigned short u16;
typedef unsigned int   u32;
typedef __attribute__((ext_vector_type(8))) unsigned short ushort8;
typedef __attribute__((ext_vector_type(4))) unsigned short ushort4v;
typedef __attribute__((ext_vector_type(8))) short short8v;   // 8 bf16 (4 VGPRs)
typedef __attribute__((ext_vector_type(4))) float f32x4;
typedef __attribute__((ext_vector_type(2))) float f32x2;

__device__ __forceinline__ float gelu_f(float x) {
    const float c = 0.7978845608028654f;   // sqrt(2/pi)
    float x3 = x * x * x;
    float t = tanhf(c * (x + 0.044715f * x3));
    return 0.5f * x * (1.0f + t);
}

__device__ __forceinline__ u16 f2b(float f) {
    u32 u = __float_as_uint(f);
    return (u16)((u + 0x7FFFu + ((u >> 16) & 1u)) >> 16);
}
__device__ __forceinline__ float b2f(u16 u) {
    return __uint_as_float(((u32)u) << 16);
}

// fp8 e4m3fn software fallback
__device__ __forceinline__ u32 f2fp8_sw(float f) {
    u32 u = __float_as_uint(f);
    u32 s = (u >> 31) << 7;
    float af = fabsf(f);
    if (af >= 448.0f) return s | 0x7E;
    if (af < 0.015625f) {
        int m = __float2int_rn(af * 512.0f);
        if (m >= 8) return s | 0x08;
        return s | (u32)m;
    }
    u32 a = __float_as_uint(af);
    u32 r = a + 0xFFFFFu + ((a >> 20) & 1u);
    int e8 = (int)(r >> 23) - 120;
    u32 m3 = (r >> 20) & 7u;
    if (e8 >= 16) return s | 0x7E;
    return s | ((u32)e8 << 3) | m3;
}
__device__ __forceinline__ float fp8d_sw(u32 b) {
    u32 lo = b & 0x7Fu;
    u32 nb = (lo << 20) + 0x3C000000u;
    float n = __uint_as_float(nb | ((b & 0x80u) << 24));
    float sub = (float)(b & 7u) * 0.001953125f;
    sub = (b & 0x80u) ? -sub : sub;
    return (lo & 0x78u) ? n : sub;
}
__device__ __forceinline__ u8 f2fp8(float v) {
#if __has_builtin(__builtin_amdgcn_cvt_pk_fp8_f32)
    return (u8)(__builtin_amdgcn_cvt_pk_fp8_f32(v, v, 0, false) & 0xFF);
#else
    return (u8)f2fp8_sw(v);
#endif
}
__device__ __forceinline__ f32x2 kvdec(u32 pair) {
#if __has_builtin(__builtin_amdgcn_cvt_pk_f32_fp8)
    return __builtin_amdgcn_cvt_pk_f32_fp8((int)pair, false);
#else
    f32x2 r;
    r[0] = fp8d_sw(pair & 0xFF);
    r[1] = fp8d_sw((pair >> 8) & 0xFF);
    return r;
#endif
}

__device__ __forceinline__ void split_bf16(float f, u16& h, u16& l) {
    u32 u = __float_as_uint(f);
    u32 r = (u + 0x7FFFu + ((u >> 16) & 1u)) >> 16;
    h = (u16)r;
    float hf = __uint_as_float(r << 16);
    float d = f - hf;
    u32 u2 = __float_as_uint(d);
    l = (u16)((u2 + 0x7FFFu + ((u2 >> 16) & 1u)) >> 16);
}

// bijective XCD-chunked swizzle (m204)
__device__ __forceinline__ int xcd_swz(int orig, int nwg) {
    int q8 = nwg >> 3, r8 = nwg & 7;
    int xcd = orig & 7, ii = orig >> 3;
    return (xcd < r8 ? xcd * (q8 + 1) : r8 * (q8 + 1) + (xcd - r8) * q8) + ii;
}

// ---------------------------------------------------------------------------
__global__ __launch_bounds__(256) void zero2_i32(int* __restrict__ a, int na,
                                                 int* __restrict__ b, int nb) {
    int i = blockIdx.x * 256 + threadIdx.x;
    if (i < na) a[i] = 0;
    else if (i - na < nb) b[i - na] = 0;
}

// ---------------------------------------------------------------------------
// Weight pre-pass: transpose [K][N] f32 -> [N][K] split bf16 hi/lo
// ---------------------------------------------------------------------------
struct TEntry { const float* src; u16* dh; u16* dl; int K; int N; };
struct TDesc  { TEntry e[29]; };

__global__ __launch_bounds__(256) void transpose_split(TDesc desc) {
    __shared__ float tile[32][33];
    TEntry en = desc.e[blockIdx.y];
    int tk = en.K >> 5, tn = en.N >> 5;
    int bx = blockIdx.x;
    if (bx >= tk * tn) return;
    int k0 = (bx % tk) * 32, n0 = (bx / tk) * 32;
    int tx = threadIdx.x & 31, ty = threadIdx.x >> 5;
    #pragma unroll
    for (int yy = 0; yy < 32; yy += 8)
        tile[ty + yy][tx] = en.src[(size_t)(k0 + ty + yy) * en.N + (n0 + tx)];
    __syncthreads();
    #pragma unroll
    for (int yy = 0; yy < 32; yy += 8) {
        int n = n0 + ty + yy, k = k0 + tx;
        float f = tile[tx][ty + yy];
        u16 h, l;
        split_bf16(f, h, l);
        en.dh[(size_t)n * en.K + k] = h;
        en.dl[(size_t)n * en.K + k] = l;
    }
}

// ---------------------------------------------------------------------------
// RBF lookup tables, 4098 bins per layer
// ---------------------------------------------------------------------------
__global__ __launch_bounds__(128) void build_rbf_table(
    const float* __restrict__ W_rbf, float* __restrict__ table)
{
    int k = blockIdx.x, l = blockIdx.y, m = threadIdx.x;
    const float* Wrbf_l = W_rbf + (size_t)l * 32 * 128;
    float* tbl = table + (size_t)l * 4098 * 128;
    const float PI = 3.14159265358979323846f;
    float d = fmaxf((float)k * (6.0f / 4096.0f), 1e-9f);
    float th = d * (PI / 6.0f);
    float s1, c1;
    __sincosf(th, &s1, &c1);
    float env = (d < 6.0f) ? (0.5f * c1 + 0.5f) : 0.0f;
    float invd = 1.0f / d;
    float two_c = 2.0f * c1;
    float sp = 0.f, sc = s1, dot = 0.f;
    #pragma unroll
    for (int r = 0; r < 32; ++r) {
        dot = fmaf(sc, Wrbf_l[r * 128 + m], dot);
        float sn = fmaf(two_c, sc, -sp);
        sp = sc; sc = sn;
    }
    tbl[(size_t)k * 128 + m] = dot * invd * env;
}

// ---------------------------------------------------------------------------
// MFMA GEMM, 1D swizzled grid. A bf16 [M][K]; BH (+BL) transposed bf16 [N][K].
// OMODE: 0 f32 out (ACCUM f32 +=), 1 bf16 out, 2 bf16 out + bf16 accum,
//        3 qkv mixed (Q bf16 / K,V fp8 pairs)
// OMODE 1/2 use an LDS-staged coalesced epilogue (16B/lane stores).
// ---------------------------------------------------------------------------
template<int OMODE, bool ACCUM, bool BIAS, bool DOGELU, bool SPLITB>
__global__ __launch_bounds__(256) void mfma_gemm(
    const u16* __restrict__ A, const u16* __restrict__ BH,
    const u16* __restrict__ BL, const float* __restrict__ bias,
    void* __restrict__ Cv, void* __restrict__ Cv2,
    int Mrows, int K, int Nc, int gx)
{
    constexpr bool STAGE_OUT = (OMODE == 1 || OMODE == 2);
    constexpr int MAIN_B = 128 * 40 * 2 * (SPLITB ? 3 : 2);
    constexpr int OUT_B  = STAGE_OUT ? 128 * 136 * 2 : 0;
    constexpr int SMEM_B = (MAIN_B > OUT_B) ? MAIN_B : OUT_B;
    __shared__ __align__(16) char smem[SMEM_B];
    u16 (*sA)[40]  = (u16(*)[40])smem;
    u16 (*sBh)[40] = (u16(*)[40])(smem + 128 * 40 * 2);
    u16 (*sBl)[40] = (u16(*)[40])(smem + 2 * 128 * 40 * 2);
    u16 (*sOut)[136] = (u16(*)[136])smem;

    const int wg = xcd_swz(blockIdx.x, gridDim.x);
    const int r0 = (wg / gx) * 128, c0 = (wg % gx) * 128;

    const int t = threadIdx.x;
    const int lane = t & 63, wid = t >> 6;
    const int wr = (wid >> 1) * 64, wc = (wid & 1) * 64;

    f32x4 acc[4][4] = {};

    const int srow = t >> 1;
    const int skc  = (t & 1) * 16;

    for (int k0 = 0; k0 < K; k0 += 32) {
        {
            int gr = r0 + srow;
            ushort8 h0, h1;
            if (gr < Mrows) {
                const u16* p = A + (size_t)gr * K + (k0 + skc);
                h0 = *(const ushort8*)p;
                h1 = *(const ushort8*)(p + 8);
            } else {
                #pragma unroll
                for (int j = 0; j < 8; ++j) { h0[j] = 0; h1[j] = 0; }
            }
            *(ushort8*)&sA[srow][skc]     = h0;
            *(ushort8*)&sA[srow][skc + 8] = h1;
        }
        {
            int cg = c0 + srow;
            const u16* ph = BH + (size_t)cg * K + (k0 + skc);
            *(ushort8*)&sBh[srow][skc]     = *(const ushort8*)(ph);
            *(ushort8*)&sBh[srow][skc + 8] = *(const ushort8*)(ph + 8);
            if constexpr (SPLITB) {
                const u16* pl = BL + (size_t)cg * K + (k0 + skc);
                *(ushort8*)&sBl[srow][skc]     = *(const ushort8*)(pl);
                *(ushort8*)&sBl[srow][skc + 8] = *(const ushort8*)(pl + 8);
            }
        }
        __syncthreads();

        const int arow = wr + (lane & 15);
        const int koff = (lane >> 4) * 8;
        short8v ah[4];
        #pragma unroll
        for (int fr = 0; fr < 4; ++fr)
            ah[fr] = *(const short8v*)&sA[arow + fr * 16][koff];
        #pragma unroll
        for (int fc = 0; fc < 4; ++fc) {
            int bcol = wc + fc * 16 + (lane & 15);
            short8v bh = *(const short8v*)&sBh[bcol][koff];
            #pragma unroll
            for (int fr = 0; fr < 4; ++fr)
                acc[fr][fc] = __builtin_amdgcn_mfma_f32_16x16x32_bf16(ah[fr], bh, acc[fr][fc], 0, 0, 0);
            if constexpr (SPLITB) {
                short8v bl = *(const short8v*)&sBl[bcol][koff];
                #pragma unroll
                for (int fr = 0; fr < 4; ++fr)
                    acc[fr][fc] = __builtin_amdgcn_mfma_f32_16x16x32_bf16(ah[fr], bl, acc[fr][fc], 0, 0, 0);
            }
        }
        __syncthreads();
    }

    if constexpr (STAGE_OUT) {
        // stage bf16 tile in LDS, then coalesced 16B/lane stores (RMW if OMODE2)
        #pragma unroll
        for (int fr = 0; fr < 4; ++fr) {
            int rbase = wr + fr * 16 + (lane >> 4) * 4;
            #pragma unroll
            for (int fc = 0; fc < 4; ++fc) {
                int col = wc + fc * 16 + (lane & 15);
                #pragma unroll
                for (int reg = 0; reg < 4; ++reg) {
                    float v = acc[fr][fc][reg];
                    if (BIAS)   v += bias[c0 + col];
                    if (DOGELU) v = gelu_f(v);
                    sOut[rbase + reg][col] = f2b(v);
                }
            }
        }
        __syncthreads();
        #pragma unroll
        for (int p = 0; p < 4; ++p) {
            int row = p * 32 + (t >> 3);
            int cch = (t & 7) * 16;
            int gr = r0 + row;
            if (gr < Mrows) {
                u16* gp = (u16*)Cv + (size_t)gr * Nc + c0 + cch;
                ushort8 v0 = *(ushort8*)&sOut[row][cch];
                ushort8 v1 = *(ushort8*)&sOut[row][cch + 8];
                if (OMODE == 2) {
                    ushort8 o0 = *(const ushort8*)gp;
                    ushort8 o1 = *(const ushort8*)(gp + 8);
                    #pragma unroll
                    for (int j = 0; j < 8; ++j) {
                        v0[j] = f2b(b2f(v0[j]) + b2f(o0[j]));
                        v1[j] = f2b(b2f(v1[j]) + b2f(o1[j]));
                    }
                }
                *(ushort8*)gp       = v0;
                *(ushort8*)(gp + 8) = v1;
            }
        }
    } else {
        #pragma unroll
        for (int fr = 0; fr < 4; ++fr) {
            int rbase = r0 + wr + fr * 16 + (lane >> 4) * 4;
            #pragma unroll
            for (int fc = 0; fc < 4; ++fc) {
                int col = c0 + wc + fc * 16 + (lane & 15);
                #pragma unroll
                for (int reg = 0; reg < 4; ++reg) {
                    int gr = rbase + reg;
                    if (gr >= Mrows) continue;
                    float v = acc[fr][fc][reg];
                    if (BIAS)   v += bias[col];
                    if (DOGELU) v = gelu_f(v);
                    if (OMODE == 0) {
                        float* pc = (float*)Cv + (size_t)gr * Nc + col;
                        if (ACCUM) v += *pc;
                        *pc = v;
                    } else {   // OMODE 3: qkv mixed
                        if (col < 128)
                            ((u16*)Cv)[(size_t)gr * 128 + col] = f2b(v);
                        else if (col < 256)
                            ((u8*)Cv2)[(size_t)gr * 256 + (col - 128) * 2] = f2fp8(v);
                        else
                            ((u8*)Cv2)[(size_t)gr * 256 + (col - 256) * 2 + 1] = f2fp8(v);
                    }
                }
            }
        }
    }
}

// ---------------------------------------------------------------------------
// Fused vs-GEMM + LayerNorm: h16 = bf16(LN(h16 + b2 + vn@Wvs) * gamma)
// A = vn16 [N][256] bf16, B split [256][256], b2 bf16. BM=128, 512 threads.
// ---------------------------------------------------------------------------
__global__ __launch_bounds__(512) void vs_ln_kernel(
    const u16* __restrict__ A, const u16* __restrict__ BH,
    const u16* __restrict__ BL, const u16* __restrict__ b2,
    const float* __restrict__ gamma_l, u16* __restrict__ h16, int Mrows)
{
    __shared__ __align__(16) u16 sA [128][40];
    __shared__ __align__(16) u16 sBh[256][40];
    __shared__ __align__(16) u16 sBl[256][40];
    __shared__ float sSum[128][4];
    __shared__ float sSq [128][4];

    const int r0 = blockIdx.x * 128;
    const int t = threadIdx.x;
    const int lane = t & 63, wid = t >> 6;          // 8 waves
    const int wr = (wid >> 2) * 64, wc = (wid & 3) * 64;

    f32x4 acc[4][4] = {};
    const int K = 256;
    const int srow = t >> 2;          // 0..127
    const int skc  = (t & 3) * 8;     // 0,8,16,24

    for (int k0 = 0; k0 < K; k0 += 32) {
        {
            int gr = r0 + srow;
            ushort8 h0;
            #pragma unroll
            for (int j = 0; j < 8; ++j) h0[j] = 0;
            if (gr < Mrows) h0 = *(const ushort8*)(A + (size_t)gr * K + k0 + skc);
            *(ushort8*)&sA[srow][skc] = h0;
        }
        {
            *(ushort8*)&sBh[srow][skc]       = *(const ushort8*)(BH + (size_t)srow * K + k0 + skc);
            *(ushort8*)&sBh[srow + 128][skc] = *(const ushort8*)(BH + (size_t)(srow + 128) * K + k0 + skc);
            *(ushort8*)&sBl[srow][skc]       = *(const ushort8*)(BL + (size_t)srow * K + k0 + skc);
            *(ushort8*)&sBl[srow + 128][skc] = *(const ushort8*)(BL + (size_t)(srow + 128) * K + k0 + skc);
        }
        __syncthreads();

        const int arow = wr + (lane & 15);
        const int koff = (lane >> 4) * 8;
        short8v ah[4];
        #pragma unroll
        for (int fr = 0; fr < 4; ++fr)
            ah[fr] = *(const short8v*)&sA[arow + fr * 16][koff];
        #pragma unroll
        for (int fc = 0; fc < 4; ++fc) {
            int bcol = wc + fc * 16 + (lane & 15);
            short8v bh = *(const short8v*)&sBh[bcol][koff];
            short8v bl = *(const short8v*)&sBl[bcol][koff];
            #pragma unroll
            for (int fr = 0; fr < 4; ++fr) {
                acc[fr][fc] = __builtin_amdgcn_mfma_f32_16x16x32_bf16(ah[fr], bh, acc[fr][fc], 0, 0, 0);
                acc[fr][fc] = __builtin_amdgcn_mfma_f32_16x16x32_bf16(ah[fr], bl, acc[fr][fc], 0, 0, 0);
            }
        }
        __syncthreads();
    }

    // epilogue: x = h_old + b2 + vsout; row stats over 256 cols, then LN
    float psum[4][4] = {}, psq[4][4] = {};
    #pragma unroll
    for (int fr = 0; fr < 4; ++fr) {
        #pragma unroll
        for (int fc = 0; fc < 4; ++fc) {
            int col = wc + fc * 16 + (lane & 15);
            #pragma unroll
            for (int reg = 0; reg < 4; ++reg) {
                int gr = r0 + wr + fr * 16 + (lane >> 4) * 4 + reg;
                float x = 0.f;
                if (gr < Mrows) {
                    size_t ix = (size_t)gr * 256 + col;
                    x = acc[fr][fc][reg] + b2f(b2[ix]) + b2f(h16[ix]);
                }
                acc[fr][fc][reg] = x;
                psum[fr][reg] += x;
                psq[fr][reg]  = fmaf(x, x, psq[fr][reg]);
            }
        }
    }
    #pragma unroll
    for (int fr = 0; fr < 4; ++fr) {
        #pragma unroll
        for (int reg = 0; reg < 4; ++reg) {
            float s = psum[fr][reg], sq = psq[fr][reg];
            #pragma unroll
            for (int off = 8; off; off >>= 1) {
                s  += __shfl_xor(s, off);
                sq += __shfl_xor(sq, off);
            }
            psum[fr][reg] = s; psq[fr][reg] = sq;
        }
    }
    if ((lane & 15) == 0) {
        int qg = lane >> 4;
        #pragma unroll
        for (int fr = 0; fr < 4; ++fr) {
            #pragma unroll
            for (int reg = 0; reg < 4; ++reg) {
                int row = wr + fr * 16 + qg * 4 + reg;
                sSum[row][wc >> 6] = psum[fr][reg];
                sSq [row][wc >> 6] = psq[fr][reg];
            }
        }
    }
    __syncthreads();
    #pragma unroll
    for (int fr = 0; fr < 4; ++fr) {
        #pragma unroll
        for (int reg = 0; reg < 4; ++reg) {
            int row = wr + fr * 16 + (lane >> 4) * 4 + reg;
            int gr = r0 + row;
            if (gr >= Mrows) continue;
            float S = sSum[row][0] + sSum[row][1] + sSum[row][2] + sSum[row][3];
            float Q = sSq[row][0] + sSq[row][1] + sSq[row][2] + sSq[row][3];
            float mu = S * (1.0f / 256.0f);
            float var = fmaxf(Q * (1.0f / 256.0f) - mu * mu, 0.0f);
            float rs = rsqrtf(var + 1e-5f);
            #pragma unroll
            for (int fc = 0; fc < 4; ++fc) {
                int col = wc + fc * 16 + (lane & 15);
                float y = (acc[fr][fc][reg] - mu) * rs * gamma_l[col];
                h16[(size_t)gr * 256 + col] = f2b(y);
            }
        }
    }
}

// ---------------------------------------------------------------------------
// CSR construction
// ---------------------------------------------------------------------------
__global__ void hist_edges(const int* __restrict__ ei, int* __restrict__ deg, int E_) {
    int e = blockIdx.x * 256 + threadIdx.x;
    if (e < E_) atomicAdd(&deg[ei[E_ + e]], 1);
}
__global__ void hist_nodes(const int* __restrict__ batch, int* __restrict__ gcnt, int n) {
    int i = blockIdx.x * 256 + threadIdx.x;
    if (i < n) atomicAdd(&gcnt[batch[i]], 1);
}

__global__ __launch_bounds__(1024) void scan_kernel(
    const int* __restrict__ cnt, int n, int* __restrict__ out, int* __restrict__ cursor)
{
    __shared__ int part[1024];
    int t = threadIdx.x;
    int chunk = (n + 1023) / 1024;
    int base = t * chunk;
    int s = 0;
    for (int k = 0; k < chunk; ++k) { int i = base + k; if (i < n) s += cnt[i]; }
    part[t] = s;
    __syncthreads();
    for (int off = 1; off < 1024; off <<= 1) {
        int u = (t >= off) ? part[t - off] : 0;
        __syncthreads();
        part[t] += u;
        __syncthreads();
    }
    int run = part[t] - s;
    for (int k = 0; k < chunk; ++k) {
        int i = base + k;
        if (i < n) {
            out[i] = run;
            if (cursor) cursor[i] = run;
            run += cnt[i];
        }
    }
    if (t == 1023) out[n] = part[1023];
}

// perm payload: (edge id, src node)
__global__ void scatter_kernel(const int* __restrict__ ei, int* __restrict__ cursor,
                               int2* __restrict__ perm2, int E_) {
    int e = blockIdx.x * 256 + threadIdx.x;
    if (e < E_) {
        int p = atomicAdd(&cursor[ei[E_ + e]], 1);
        perm2[p] = make_int2(e, ei[e]);
    }
}

// ---------------------------------------------------------------------------
// Edge geometry packed: eg[e] = (ux, uy, uz, dist)
// ---------------------------------------------------------------------------
__global__ __launch_bounds__(256) void geom_kernel(
    const float* __restrict__ pos, const int* __restrict__ ei,
    float4* __restrict__ eg, int E_)
{
    int e = blockIdx.x * 256 + threadIdx.x;
    if (e >= E_) return;
    int s = ei[e], dn = ei[E_ + e];
    float dx = pos[s * 3 + 0] - pos[dn * 3 + 0];
    float dy = pos[s * 3 + 1] - pos[dn * 3 + 1];
    float dz = pos[s * 3 + 2] - pos[dn * 3 + 2];
    float d = sqrtf(dx * dx + dy * dy + dz * dz + 1e-12f);
    float invd = 1.0f / d;
    eg[e] = make_float4(dx * invd, dy * invd, dz * invd, d);
}

// ---------------------------------------------------------------------------
// h init -> bf16
// ---------------------------------------------------------------------------
__global__ __launch_bounds__(256) void init_h_kernel(
    const int* __restrict__ z, const float* __restrict__ pos,
    const float* __restrict__ emb, const float* __restrict__ W_in,
    const float* __restrict__ b_in, u16* __restrict__ h16)
{
    int i = blockIdx.x, d = threadIdx.x;
    float acc = b_in[d];
    int zi = z[i];
    #pragma unroll 8
    for (int k = 0; k < 32; ++k)
        acc += emb[zi * 32 + k] * W_in[k * 256 + d];
    #pragma unroll
    for (int x = 0; x < 3; ++x)
        acc += pos[i * 3 + x] * W_in[(32 + x) * 256 + d];
    h16[(size_t)i * 256 + d] = f2b(acc);
}

// ---------------------------------------------------------------------------
// Per-dst-node edge attention, online softmax, 8 edges/iter.
// q16 bf16 [N][128]; kv8 fp8 pairs [N][128]; perm2 = (e, src).
// ---------------------------------------------------------------------------
__global__ __launch_bounds__(128) void edge_attn_kernel(
    const int* __restrict__ rowptr, const int2* __restrict__ perm2,
    const u16* __restrict__ q16, const u16* __restrict__ kv8,
    const float4* __restrict__ eg, const float* __restrict__ table_l,
    u16* __restrict__ msg, u16* __restrict__ U)
{
    int m = threadIdx.x;
    int i = blockIdx.x;

    int p0 = rowptr[i], p1 = rowptr[i + 1];
    float q = b2f(q16[(size_t)i * 128 + m]);
    float Mx = -1e30f, S = 0.f, am = 0.f, a0 = 0.f, a1 = 0.f, a2 = 0.f;
    const float iscale = 0.1767766952966369f;   // 1/sqrt(32)

    for (int p = p0; p < p1; p += 8) {
        int rem = p1 - p;
        int ee[8], jj[8];
        #pragma unroll
        for (int u = 0; u < 8; ++u) {
            int pp = p + (u < rem ? u : 0);
            int2 pe = perm2[pp];
            ee[u] = __builtin_amdgcn_readfirstlane(pe.x);
            jj[u] = __builtin_amdgcn_readfirstlane(pe.y);
        }
        u32 kv[8];
        float4 g[8];
        #pragma unroll
        for (int u = 0; u < 8; ++u) {
            kv[u] = kv8[(size_t)jj[u] * 128 + m];
            g[u]  = eg[ee[u]];
        }
        float lg[8], vd[8];
        #pragma unroll
        for (int u = 0; u < 8; ++u) {
            f32x2 c = kvdec(kv[u]);
            vd[u] = c[1];
            float pr = q * c[0];
            #pragma unroll
            for (int off = 16; off; off >>= 1) pr += __shfl_xor(pr, off);
            lg[u] = pr * iscale;
        }
        float ew[8];
        #pragma unroll
        for (int u = 0; u < 8; ++u) {
            float x = fminf(g[u].w * (4096.0f / 6.0f), 4096.0f);
            int b = (int)x;
            float tf = x - (float)b;
            float f0 = table_l[(size_t)b * 128 + m];
            float f1 = table_l[(size_t)(b + 1) * 128 + m];
            ew[u] = fmaf(tf, f1 - f0, f0);
        }
        float Mb = Mx;
        #pragma unroll
        for (int u = 0; u < 8; ++u) Mb = fmaxf(Mb, lg[u]);
        float sc = __expf(Mx - Mb);
        float w[8];
        #pragma unroll
        for (int u = 0; u < 8; ++u)
            w[u] = (u < rem) ? __expf(lg[u] - Mb) : 0.f;
        float ws = 0.f, wvs = 0.f, wx = 0.f, wy = 0.f, wz = 0.f;
        #pragma unroll
        for (int u = 0; u < 8; ++u) {
            float wv = w[u] * vd[u] * ew[u];
            ws  += w[u];
            wvs += wv;
            wx = fmaf(wv, g[u].x, wx);
            wy = fmaf(wv, g[u].y, wy);
            wz = fmaf(wv, g[u].z, wz);
        }
        S  = S  * sc + ws;
        am = am * sc + wvs;
        a0 = a0 * sc + wx;
        a1 = a1 * sc + wy;
        a2 = a2 * sc + wz;
        Mx = Mb;
    }
    float inv = 1.0f / (S + 1e-12f);
    msg[(size_t)i * 128 + m] = f2b(am * inv);
    U[((size_t)i * 3 + 0) * 128 + m] = f2b(a0 * inv);
    U[((size_t)i * 3 + 1) * 128 + m] = f2b(a1 * inv);
    U[((size_t)i * 3 + 2) * 128 + m] = f2b(a2 * inv);
}

// ---------------------------------------------------------------------------
// vnorm from bf16 vfeat -> bf16
// ---------------------------------------------------------------------------
__global__ __launch_bounds__(256) void vnorm_kernel(
    const u16* __restrict__ vf16, u16* __restrict__ vn)
{
    int i = blockIdx.x, d = threadIdx.x;
    float v0 = b2f(vf16[((size_t)i * 3 + 0) * 256 + d]);
    float v1 = b2f(vf16[((size_t)i * 3 + 1) * 256 + d]);
    float v2 = b2f(vf16[((size_t)i * 3 + 2) * 256 + d]);
    vn[(size_t)i * 256 + d] = f2b(sqrtf(v0 * v0 + v1 * v1 + v2 * v2 + 1e-8f));
}

// ---------------------------------------------------------------------------
// Graph pooling, wave-parallel (block = graph)
// ---------------------------------------------------------------------------
__global__ __launch_bounds__(256) void pool_kernel(
    const u16* __restrict__ h16, const float* __restrict__ w_att,
    const int* __restrict__ gptr, u16* __restrict__ pooled)
{
    __shared__ float sM[4], sS[4];
    __shared__ float sAcc[4][256];
    int g = blockIdx.x;
    int t = threadIdx.x, w = t >> 6, lane = t & 63;
    int c0 = lane * 4;
    int n0 = gptr[g], n1 = gptr[g + 1];
    float4 wa = *(const float4*)(w_att + c0);
    float M = -1e30f, S = 0.f, a0 = 0.f, a1 = 0.f, a2 = 0.f, a3 = 0.f;
    for (int i = n0 + w; i < n1; i += 4) {
        ushort4v hv = *(const ushort4v*)(h16 + (size_t)i * 256 + c0);
        float h0 = b2f(hv[0]), h1 = b2f(hv[1]), h2 = b2f(hv[2]), h3 = b2f(hv[3]);
        float p = h0 * wa.x + h1 * wa.y + h2 * wa.z + h3 * wa.w;
        #pragma unroll
        for (int off = 32; off; off >>= 1) p += __shfl_xor(p, off);
        float nM = fmaxf(M, p);
        float sc = __expf(M - nM), wg = __expf(p - nM);
        S = S * sc + wg;
        a0 = a0 * sc + wg * h0;
        a1 = a1 * sc + wg * h1;
        a2 = a2 * sc + wg * h2;
        a3 = a3 * sc + wg * h3;
        M = nM;
    }
    sAcc[w][c0 + 0] = a0; sAcc[w][c0 + 1] = a1;
    sAcc[w][c0 + 2] = a2; sAcc[w][c0 + 3] = a3;
    if (lane == 0) { sM[w] = M; sS[w] = S; }
    __syncthreads();
    if (w == 0) {
        float Mg = fmaxf(fmaxf(sM[0], sM[1]), fmaxf(sM[2], sM[3]));
        float e0 = __expf(sM[0] - Mg), e1 = __expf(sM[1] - Mg);
        float e2 = __expf(sM[2] - Mg), e3 = __expf(sM[3] - Mg);
        float St = sS[0] * e0 + sS[1] * e1 + sS[2] * e2 + sS[3] * e3;
        float inv = 1.0f / (St + 1e-12f);
        #pragma unroll
        for (int c = 0; c < 4; ++c) {
            float v = sAcc[0][c0 + c] * e0 + sAcc[1][c0 + c] * e1
                    + sAcc[2][c0 + c] * e2 + sAcc[3][c0 + c] * e3;
            pooled[(size_t)g * 256 + c0 + c] = f2b(v * inv);
        }
    }
}

// ---------------------------------------------------------------------------
extern "C" void kernel_launch(void* const* d_in, const int* in_sizes, int n_in,
                              void* d_out, int out_size, void* d_ws, size_t ws_size,
                              hipStream_t stream)
{
    const float* pos   = (const float*)d_in[0];
    const int*   z     = (const int*)d_in[1];
    const int*   batch = (const int*)d_in[2];
    const int*   ei    = (const int*)d_in[3];
    const float* emb   = (const float*)d_in[4];
    const float* W_in  = (const float*)d_in[5];
    const float* b_in  = (const float*)d_in[6];
    const float* Wq    = (const float*)d_in[7];
    const float* Wk    = (const float*)d_in[8];
    const float* Wv    = (const float*)d_in[9];
    const float* W_rbf = (const float*)d_in[10];
    const float* W_msg = (const float*)d_in[11];
    const float* W_vg  = (const float*)d_in[12];
    const float* W_vs  = (const float*)d_in[13];
    const float* W_nd  = (const float*)d_in[14];
    const float* b_nd  = (const float*)d_in[15];
    const float* gam   = (const float*)d_in[16];
    const float* watt  = (const float*)d_in[17];
    const float* W_out = (const float*)d_in[18];
    const float* b_out = (const float*)d_in[19];

    const int N = in_sizes[0] / 3;      // 20000
    const int E = in_sizes[3] / 2;      // 320000
    const int G = out_size / 512;       // 500

    char* ws = (char*)d_ws;
    size_t o = 0;
    auto alloc = [&](size_t bytes) -> char* {
        o = (o + 255) & ~(size_t)255;
        char* r = ws + o;
        o += bytes;
        return r;
    };
    float4* f_eg   = (float4*)alloc((size_t)E * 16);
    u16*   h16     = (u16*)  alloc((size_t)N * 256 * 2);
    u16*   vf16    = (u16*)  alloc((size_t)N * 3 * 256 * 2);
    u16*   q16     = (u16*)  alloc((size_t)N * 128 * 2);
    u16*   kv8     = (u16*)  alloc((size_t)N * 128 * 2);
    u16*   umb     = (u16*)  alloc((size_t)N * 4 * 128 * 2);
    u16*   b1_16   = (u16*)  alloc((size_t)N * 256 * 2);
    u16*   b2_16   = (u16*)  alloc((size_t)N * 256 * 2);
    u16*   vn16    = (u16*)  alloc((size_t)N * 256 * 2);
    u16*   pool16  = (u16*)  alloc((size_t)G * 256 * 2);
    float* f_table = (float*)alloc((size_t)4 * 4098 * 128 * 4);
    const size_t LS = 384 * 256 + 2 * (256 * 128) + 2 * (256 * 256);
    const size_t OFF_QKV = 0, OFF_VG = 384 * 256, OFF_MSG = OFF_VG + 256 * 128,
                 OFF_ND = OFF_MSG + 256 * 128, OFF_VS = OFF_ND + 256 * 256;
    const size_t OFF_OUT = LS * 4;
    u16* whi = (u16*)alloc((LS * 4 + 512 * 256) * sizeof(u16));
    u16* wlo = (u16*)alloc((LS * 4 + 512 * 256) * sizeof(u16));
    int*  i_deg   = (int*)alloc((size_t)N * 4);
    int*  i_rowp  = (int*)alloc((size_t)(N + 1) * 4);
    int*  i_cur   = (int*)alloc((size_t)(N + 1) * 4);
    int2* i_perm2 = (int2*)alloc((size_t)E * 8);
    int*  i_gcnt  = (int*)alloc((size_t)G * 4);
    int*  i_gptr  = (int*)alloc((size_t)(G + 1) * 4);

    u16* U16   = umb;                         // [3N,128]
    u16* msg16 = umb + (size_t)3 * N * 128;   // [N,128]

    // ---- weight pre-pass descriptor ----
    TDesc td;
    int idx = 0;
    for (int l = 0; l < 4; ++l) {
        u16* bh = whi + (size_t)l * LS;
        u16* bl = wlo + (size_t)l * LS;
        td.e[idx++] = { Wq   + (size_t)l * 256 * 128, bh + OFF_QKV,             bl + OFF_QKV,             256, 128 };
        td.e[idx++] = { Wk   + (size_t)l * 256 * 128, bh + OFF_QKV + 128 * 256, bl + OFF_QKV + 128 * 256, 256, 128 };
        td.e[idx++] = { Wv   + (size_t)l * 256 * 128, bh + OFF_QKV + 256 * 256, bl + OFF_QKV + 256 * 256, 256, 128 };
        td.e[idx++] = { W_vg + (size_t)l * 128 * 256, bh + OFF_VG,  bl + OFF_VG,  128, 256 };
        td.e[idx++] = { W_msg+ (size_t)l * 128 * 256, bh + OFF_MSG, bl + OFF_MSG, 128, 256 };
        td.e[idx++] = { W_nd + (size_t)l * 256 * 256, bh + OFF_ND,  bl + OFF_ND,  256, 256 };
        td.e[idx++] = { W_vs + (size_t)l * 256 * 256, bh + OFF_VS,  bl + OFF_VS,  256, 256 };
    }
    td.e[idx++] = { W_out, whi + OFF_OUT, wlo + OFF_OUT, 256, 512 };

    // ---- setup ----
    zero2_i32<<<(N + G + 255) / 256, 256, 0, stream>>>(i_deg, N, i_gcnt, G);
    transpose_split<<<dim3(128, 29), 256, 0, stream>>>(td);
    build_rbf_table<<<dim3(4098, 4), 128, 0, stream>>>(W_rbf, f_table);

    hist_edges<<<(E + 255) / 256, 256, 0, stream>>>(ei, i_deg, E);
    scan_kernel<<<1, 1024, 0, stream>>>(i_deg, N, i_rowp, i_cur);
    scatter_kernel<<<(E + 255) / 256, 256, 0, stream>>>(ei, i_cur, i_perm2, E);
    hist_nodes<<<(N + 255) / 256, 256, 0, stream>>>(batch, i_gcnt, N);
    scan_kernel<<<1, 1024, 0, stream>>>(i_gcnt, G, i_gptr, (int*)nullptr);
    geom_kernel<<<(E + 255) / 256, 256, 0, stream>>>(pos, ei, f_eg, E);
    init_h_kernel<<<N, 256, 0, stream>>>(z, pos, emb, W_in, b_in, h16);

    const int MB  = (N + 127) / 128;          // 157
    const int MB3 = (3 * N + 127) / 128;      // 469
    const int MBG = (G + 127) / 128;          // 4

    // ---- layers ----
    for (int l = 0; l < 4; ++l) {
        u16* bh = whi + (size_t)l * LS;
        u16* bl = wlo + (size_t)l * LS;
        const float* bnd_l = b_nd + (size_t)l * 256;
        const float* gam_l = gam  + (size_t)l * 256;
        const float* tbl_l = f_table + (size_t)l * 4098 * 128;

        // q16/kv8 = h @ [Wq|Wk|Wv]
        mfma_gemm<3,false,false,false,false><<<3 * MB, 256, 0, stream>>>(
            h16, bh + OFF_QKV, nullptr, nullptr, q16, kv8, N, 256, 384, 3);

        edge_attn_kernel<<<N, 128, 0, stream>>>(i_rowp, i_perm2, q16, kv8,
                                                f_eg, tbl_l, msg16, U16);

        // vfeat (+)= U @ W_vgate   (staged coalesced epilogue)
        if (l == 0)
            mfma_gemm<1,false,false,false,false><<<2 * MB3, 256, 0, stream>>>(
                U16, bh + OFF_VG, nullptr, nullptr, vf16, nullptr, 3 * N, 128, 256, 2);
        else
            mfma_gemm<2,false,false,false,false><<<2 * MB3, 256, 0, stream>>>(
                U16, bh + OFF_VG, nullptr, nullptr, vf16, nullptr, 3 * N, 128, 256, 2);

        // b1 = bf16(gelu(msg @ W_msg))
        mfma_gemm<1,false,false,true,false><<<2 * MB, 256, 0, stream>>>(
            msg16, bh + OFF_MSG, nullptr, nullptr, b1_16, nullptr, N, 128, 256, 2);
        // b2 = bf16(gelu(b1 @ W_node + b_node))   (split weights)
        mfma_gemm<1,false,true,true,true><<<2 * MB, 256, 0, stream>>>(
            b1_16, bh + OFF_ND, bl + OFF_ND, bnd_l, b2_16, nullptr, N, 256, 256, 2);
        // vn16 = bf16(vnorm(vfeat))
        vnorm_kernel<<<N, 256, 0, stream>>>(vf16, vn16);
        // h16 = LN(h16 + b2 + vn @ W_vs) * gamma    (fused, split weights)
        vs_ln_kernel<<<MB, 512, 0, stream>>>(
            vn16, bh + OFF_VS, bl + OFF_VS, b2_16, gam_l, h16, N);
    }

    // ---- readout ----
    pool_kernel<<<G, 256, 0, stream>>>(h16, watt, i_gptr, pool16);
    mfma_gemm<0,false,true,false,true><<<4 * MBG, 256, 0, stream>>>(
        pool16, whi + OFF_OUT, wlo + OFF_OUT, b_out, (float*)d_out, nullptr, G, 256, 512, 4);
}

// Round 12
// 785.604 us; speedup vs baseline: 1.7995x; 1.0624x over previous
//
#include <hip/hip_runtime.h>
#include <math.h>

typedef unsigned char  u8;
typedef unsigned short u16;
typedef unsigned int   u32;
typedef __attribute__((ext_vector_type(8))) unsigned short ushort8;
typedef __attribute__((ext_vector_type(4))) unsigned short ushort4v;
typedef __attribute__((ext_vector_type(8))) short short8v;   // 8 bf16 (4 VGPRs)
typedef __attribute__((ext_vector_type(4))) float f32x4;
typedef __attribute__((ext_vector_type(2))) float f32x2;

__device__ __forceinline__ float gelu_f(float x) {
    const float c = 0.7978845608028654f;   // sqrt(2/pi)
    float x3 = x * x * x;
    float t = tanhf(c * (x + 0.044715f * x3));
    return 0.5f * x * (1.0f + t);
}

__device__ __forceinline__ u16 f2b(float f) {
    u32 u = __float_as_uint(f);
    return (u16)((u + 0x7FFFu + ((u >> 16) & 1u)) >> 16);
}
__device__ __forceinline__ float b2f(u16 u) {
    return __uint_as_float(((u32)u) << 16);
}

// fp8 e4m3fn software fallback
__device__ __forceinline__ u32 f2fp8_sw(float f) {
    u32 u = __float_as_uint(f);
    u32 s = (u >> 31) << 7;
    float af = fabsf(f);
    if (af >= 448.0f) return s | 0x7E;
    if (af < 0.015625f) {
        int m = __float2int_rn(af * 512.0f);
        if (m >= 8) return s | 0x08;
        return s | (u32)m;
    }
    u32 a = __float_as_uint(af);
    u32 r = a + 0xFFFFFu + ((a >> 20) & 1u);
    int e8 = (int)(r >> 23) - 120;
    u32 m3 = (r >> 20) & 7u;
    if (e8 >= 16) return s | 0x7E;
    return s | ((u32)e8 << 3) | m3;
}
__device__ __forceinline__ float fp8d_sw(u32 b) {
    u32 lo = b & 0x7Fu;
    u32 nb = (lo << 20) + 0x3C000000u;
    float n = __uint_as_float(nb | ((b & 0x80u) << 24));
    float sub = (float)(b & 7u) * 0.001953125f;
    sub = (b & 0x80u) ? -sub : sub;
    return (lo & 0x78u) ? n : sub;
}
__device__ __forceinline__ u8 f2fp8(float v) {
#if __has_builtin(__builtin_amdgcn_cvt_pk_fp8_f32)
    return (u8)(__builtin_amdgcn_cvt_pk_fp8_f32(v, v, 0, false) & 0xFF);
#else
    return (u8)f2fp8_sw(v);
#endif
}
__device__ __forceinline__ f32x2 kvdec(u32 pair) {
#if __has_builtin(__builtin_amdgcn_cvt_pk_f32_fp8)
    return __builtin_amdgcn_cvt_pk_f32_fp8((int)pair, false);
#else
    f32x2 r;
    r[0] = fp8d_sw(pair & 0xFF);
    r[1] = fp8d_sw((pair >> 8) & 0xFF);
    return r;
#endif
}

__device__ __forceinline__ void split_bf16(float f, u16& h, u16& l) {
    u32 u = __float_as_uint(f);
    u32 r = (u + 0x7FFFu + ((u >> 16) & 1u)) >> 16;
    h = (u16)r;
    float hf = __uint_as_float(r << 16);
    float d = f - hf;
    u32 u2 = __float_as_uint(d);
    l = (u16)((u2 + 0x7FFFu + ((u2 >> 16) & 1u)) >> 16);
}

// bijective XCD-chunked swizzle (m204)
__device__ __forceinline__ int xcd_swz(int orig, int nwg) {
    int q8 = nwg >> 3, r8 = nwg & 7;
    int xcd = orig & 7, ii = orig >> 3;
    return (xcd < r8 ? xcd * (q8 + 1) : r8 * (q8 + 1) + (xcd - r8) * q8) + ii;
}

// ---------------------------------------------------------------------------
__global__ __launch_bounds__(256) void zero2_i32(int* __restrict__ a, int na,
                                                 int* __restrict__ b, int nb) {
    int i = blockIdx.x * 256 + threadIdx.x;
    if (i < na) a[i] = 0;
    else if (i - na < nb) b[i - na] = 0;
}

// ---------------------------------------------------------------------------
// Weight pre-pass: transpose [K][N] f32 -> [N][K] split bf16 hi/lo
// ---------------------------------------------------------------------------
struct TEntry { const float* src; u16* dh; u16* dl; int K; int N; };
struct TDesc  { TEntry e[29]; };

__global__ __launch_bounds__(256) void transpose_split(TDesc desc) {
    __shared__ float tile[32][33];
    TEntry en = desc.e[blockIdx.y];
    int tk = en.K >> 5, tn = en.N >> 5;
    int bx = blockIdx.x;
    if (bx >= tk * tn) return;
    int k0 = (bx % tk) * 32, n0 = (bx / tk) * 32;
    int tx = threadIdx.x & 31, ty = threadIdx.x >> 5;
    #pragma unroll
    for (int yy = 0; yy < 32; yy += 8)
        tile[ty + yy][tx] = en.src[(size_t)(k0 + ty + yy) * en.N + (n0 + tx)];
    __syncthreads();
    #pragma unroll
    for (int yy = 0; yy < 32; yy += 8) {
        int n = n0 + ty + yy, k = k0 + tx;
        float f = tile[tx][ty + yy];
        u16 h, l;
        split_bf16(f, h, l);
        en.dh[(size_t)n * en.K + k] = h;
        en.dl[(size_t)n * en.K + k] = l;
    }
}

// ---------------------------------------------------------------------------
// RBF lookup tables, 4098 bins per layer
// ---------------------------------------------------------------------------
__global__ __launch_bounds__(128) void build_rbf_table(
    const float* __restrict__ W_rbf, float* __restrict__ table)
{
    int k = blockIdx.x, l = blockIdx.y, m = threadIdx.x;
    const float* Wrbf_l = W_rbf + (size_t)l * 32 * 128;
    float* tbl = table + (size_t)l * 4098 * 128;
    const float PI = 3.14159265358979323846f;
    float d = fmaxf((float)k * (6.0f / 4096.0f), 1e-9f);
    float th = d * (PI / 6.0f);
    float s1, c1;
    __sincosf(th, &s1, &c1);
    float env = (d < 6.0f) ? (0.5f * c1 + 0.5f) : 0.0f;
    float invd = 1.0f / d;
    float two_c = 2.0f * c1;
    float sp = 0.f, sc = s1, dot = 0.f;
    #pragma unroll
    for (int r = 0; r < 32; ++r) {
        dot = fmaf(sc, Wrbf_l[r * 128 + m], dot);
        float sn = fmaf(two_c, sc, -sp);
        sp = sc; sc = sn;
    }
    tbl[(size_t)k * 128 + m] = dot * invd * env;
}

// ---------------------------------------------------------------------------
// MFMA GEMM, 1D swizzled grid. A bf16 [M][K]; BH (+BL) transposed bf16 [N][K].
// OMODE: 0 f32 out (ACCUM f32 +=), 1 bf16 out, 2 bf16 out + bf16 accum,
//        3 qkv mixed (Q bf16 / K,V fp8 pairs)
// OMODE 1/2 use an LDS-staged coalesced epilogue (16B/lane stores).
// ---------------------------------------------------------------------------
template<int OMODE, bool ACCUM, bool BIAS, bool DOGELU, bool SPLITB>
__global__ __launch_bounds__(256) void mfma_gemm(
    const u16* __restrict__ A, const u16* __restrict__ BH,
    const u16* __restrict__ BL, const float* __restrict__ bias,
    void* __restrict__ Cv, void* __restrict__ Cv2,
    int Mrows, int K, int Nc, int gx)
{
    constexpr bool STAGE_OUT = (OMODE == 1 || OMODE == 2);
    constexpr int MAIN_B = 128 * 40 * 2 * (SPLITB ? 3 : 2);
    constexpr int OUT_B  = STAGE_OUT ? 128 * 136 * 2 : 0;
    constexpr int SMEM_B = (MAIN_B > OUT_B) ? MAIN_B : OUT_B;
    __shared__ __align__(16) char smem[SMEM_B];
    u16 (*sA)[40]  = (u16(*)[40])smem;
    u16 (*sBh)[40] = (u16(*)[40])(smem + 128 * 40 * 2);
    u16 (*sBl)[40] = (u16(*)[40])(smem + 2 * 128 * 40 * 2);
    u16 (*sOut)[136] = (u16(*)[136])smem;

    const int wg = xcd_swz(blockIdx.x, gridDim.x);
    const int r0 = (wg / gx) * 128, c0 = (wg % gx) * 128;

    const int t = threadIdx.x;
    const int lane = t & 63, wid = t >> 6;
    const int wr = (wid >> 1) * 64, wc = (wid & 1) * 64;

    f32x4 acc[4][4] = {};

    const int srow = t >> 1;
    const int skc  = (t & 1) * 16;

    for (int k0 = 0; k0 < K; k0 += 32) {
        {
            int gr = r0 + srow;
            ushort8 h0, h1;
            if (gr < Mrows) {
                const u16* p = A + (size_t)gr * K + (k0 + skc);
                h0 = *(const ushort8*)p;
                h1 = *(const ushort8*)(p + 8);
            } else {
                #pragma unroll
                for (int j = 0; j < 8; ++j) { h0[j] = 0; h1[j] = 0; }
            }
            *(ushort8*)&sA[srow][skc]     = h0;
            *(ushort8*)&sA[srow][skc + 8] = h1;
        }
        {
            int cg = c0 + srow;
            const u16* ph = BH + (size_t)cg * K + (k0 + skc);
            *(ushort8*)&sBh[srow][skc]     = *(const ushort8*)(ph);
            *(ushort8*)&sBh[srow][skc + 8] = *(const ushort8*)(ph + 8);
            if constexpr (SPLITB) {
                const u16* pl = BL + (size_t)cg * K + (k0 + skc);
                *(ushort8*)&sBl[srow][skc]     = *(const ushort8*)(pl);
                *(ushort8*)&sBl[srow][skc + 8] = *(const ushort8*)(pl + 8);
            }
        }
        __syncthreads();

        const int arow = wr + (lane & 15);
        const int koff = (lane >> 4) * 8;
        short8v ah[4];
        #pragma unroll
        for (int fr = 0; fr < 4; ++fr)
            ah[fr] = *(const short8v*)&sA[arow + fr * 16][koff];
        #pragma unroll
        for (int fc = 0; fc < 4; ++fc) {
            int bcol = wc + fc * 16 + (lane & 15);
            short8v bh = *(const short8v*)&sBh[bcol][koff];
            #pragma unroll
            for (int fr = 0; fr < 4; ++fr)
                acc[fr][fc] = __builtin_amdgcn_mfma_f32_16x16x32_bf16(ah[fr], bh, acc[fr][fc], 0, 0, 0);
            if constexpr (SPLITB) {
                short8v bl = *(const short8v*)&sBl[bcol][koff];
                #pragma unroll
                for (int fr = 0; fr < 4; ++fr)
                    acc[fr][fc] = __builtin_amdgcn_mfma_f32_16x16x32_bf16(ah[fr], bl, acc[fr][fc], 0, 0, 0);
            }
        }
        __syncthreads();
    }

    if constexpr (STAGE_OUT) {
        #pragma unroll
        for (int fr = 0; fr < 4; ++fr) {
            int rbase = wr + fr * 16 + (lane >> 4) * 4;
            #pragma unroll
            for (int fc = 0; fc < 4; ++fc) {
                int col = wc + fc * 16 + (lane & 15);
                #pragma unroll
                for (int reg = 0; reg < 4; ++reg) {
                    float v = acc[fr][fc][reg];
                    if (BIAS)   v += bias[c0 + col];
                    if (DOGELU) v = gelu_f(v);
                    sOut[rbase + reg][col] = f2b(v);
                }
            }
        }
        __syncthreads();
        #pragma unroll
        for (int p = 0; p < 4; ++p) {
            int row = p * 32 + (t >> 3);
            int cch = (t & 7) * 16;
            int gr = r0 + row;
            if (gr < Mrows) {
                u16* gp = (u16*)Cv + (size_t)gr * Nc + c0 + cch;
                ushort8 v0 = *(ushort8*)&sOut[row][cch];
                ushort8 v1 = *(ushort8*)&sOut[row][cch + 8];
                if (OMODE == 2) {
                    ushort8 o0 = *(const ushort8*)gp;
                    ushort8 o1 = *(const ushort8*)(gp + 8);
                    #pragma unroll
                    for (int j = 0; j < 8; ++j) {
                        v0[j] = f2b(b2f(v0[j]) + b2f(o0[j]));
                        v1[j] = f2b(b2f(v1[j]) + b2f(o1[j]));
                    }
                }
                *(ushort8*)gp       = v0;
                *(ushort8*)(gp + 8) = v1;
            }
        }
    } else {
        #pragma unroll
        for (int fr = 0; fr < 4; ++fr) {
            int rbase = r0 + wr + fr * 16 + (lane >> 4) * 4;
            #pragma unroll
            for (int fc = 0; fc < 4; ++fc) {
                int col = c0 + wc + fc * 16 + (lane & 15);
                #pragma unroll
                for (int reg = 0; reg < 4; ++reg) {
                    int gr = rbase + reg;
                    if (gr >= Mrows) continue;
                    float v = acc[fr][fc][reg];
                    if (BIAS)   v += bias[col];
                    if (DOGELU) v = gelu_f(v);
                    if (OMODE == 0) {
                        float* pc = (float*)Cv + (size_t)gr * Nc + col;
                        if (ACCUM) v += *pc;
                        *pc = v;
                    } else {   // OMODE 3: qkv mixed
                        if (col < 128)
                            ((u16*)Cv)[(size_t)gr * 128 + col] = f2b(v);
                        else if (col < 256)
                            ((u8*)Cv2)[(size_t)gr * 256 + (col - 128) * 2] = f2fp8(v);
                        else
                            ((u8*)Cv2)[(size_t)gr * 256 + (col - 256) * 2 + 1] = f2fp8(v);
                    }
                }
            }
        }
    }
}

// ---------------------------------------------------------------------------
// Fused MLP: b2 = gelu(gelu(msg@Wmsg) @ Wnd + bnd).  BM=128, BN=256, 8 waves.
// Phase 1 result b1 lives in LDS only.  Wmsg bf16 [256][128]; Wnd split.
// ---------------------------------------------------------------------------
__global__ __launch_bounds__(512) void mlp_kernel(
    const u16* __restrict__ msg, const u16* __restrict__ Wmsg,
    const u16* __restrict__ WndH, const u16* __restrict__ WndL,
    const float* __restrict__ bnd, u16* __restrict__ b2out, int Mrows)
{
    __shared__ __align__(16) u16 b1[128][264];           // 67.6 KB
    __shared__ __align__(16) char sbuf[256 * 40 * 2 * 2]; // 41 KB staging
    u16 (*sA)[40]   = (u16(*)[40])sbuf;                   // phase1 A
    u16 (*sB)[40]   = (u16(*)[40])(sbuf + 128 * 40 * 2);  // phase1 B
    u16 (*sBh)[40]  = (u16(*)[40])sbuf;                   // phase2 B hi
    u16 (*sBl)[40]  = (u16(*)[40])(sbuf + 256 * 40 * 2);  // phase2 B lo
    u16 (*sOut)[136] = (u16(*)[136])sbuf;                 // epilogue

    const int r0 = xcd_swz(blockIdx.x, gridDim.x) * 128;
    const int t = threadIdx.x;
    const int lane = t & 63, wid = t >> 6;    // 8 waves
    const int wr = (wid >> 2) * 64, wc = (wid & 3) * 64;

    f32x4 acc[4][4] = {};
    const int srowA = t >> 2, skcA = (t & 3) * 8;   // 128 rows x 32k
    const int srowB = t >> 1, skcB = (t & 1) * 16;  // 256 rows x 32k

    // ---- phase 1: b1 = gelu(msg @ Wmsg), K=128 ----
    for (int k0 = 0; k0 < 128; k0 += 32) {
        {
            int gr = r0 + srowA;
            ushort8 h0;
            #pragma unroll
            for (int j = 0; j < 8; ++j) h0[j] = 0;
            if (gr < Mrows) h0 = *(const ushort8*)(msg + (size_t)gr * 128 + k0 + skcA);
            *(ushort8*)&sA[srowA][skcA] = h0;
        }
        {
            const u16* p = Wmsg + (size_t)srowB * 128 + k0 + skcB;
            *(ushort8*)&sB[srowB][skcB]     = *(const ushort8*)p;
            *(ushort8*)&sB[srowB][skcB + 8] = *(const ushort8*)(p + 8);
        }
        __syncthreads();
        const int arow = wr + (lane & 15);
        const int koff = (lane >> 4) * 8;
        short8v ah[4];
        #pragma unroll
        for (int fr = 0; fr < 4; ++fr)
            ah[fr] = *(const short8v*)&sA[arow + fr * 16][koff];
        #pragma unroll
        for (int fc = 0; fc < 4; ++fc) {
            int bcol = wc + fc * 16 + (lane & 15);
            short8v bh = *(const short8v*)&sB[bcol][koff];
            #pragma unroll
            for (int fr = 0; fr < 4; ++fr)
                acc[fr][fc] = __builtin_amdgcn_mfma_f32_16x16x32_bf16(ah[fr], bh, acc[fr][fc], 0, 0, 0);
        }
        __syncthreads();
    }
    // write b1 to LDS (gelu)
    #pragma unroll
    for (int fr = 0; fr < 4; ++fr) {
        int rbase = wr + fr * 16 + (lane >> 4) * 4;
        #pragma unroll
        for (int fc = 0; fc < 4; ++fc) {
            int col = wc + fc * 16 + (lane & 15);
            #pragma unroll
            for (int reg = 0; reg < 4; ++reg) {
                b1[rbase + reg][col] = f2b(gelu_f(acc[fr][fc][reg]));
                acc[fr][fc][reg] = 0.0f;
            }
        }
    }
    __syncthreads();

    // ---- phase 2: b2 = gelu(b1 @ Wnd + bnd), K=256, A from LDS ----
    for (int k0 = 0; k0 < 256; k0 += 32) {
        {
            const u16* ph = WndH + (size_t)srowB * 256 + k0 + skcB;
            const u16* pl = WndL + (size_t)srowB * 256 + k0 + skcB;
            *(ushort8*)&sBh[srowB][skcB]     = *(const ushort8*)ph;
            *(ushort8*)&sBh[srowB][skcB + 8] = *(const ushort8*)(ph + 8);
            *(ushort8*)&sBl[srowB][skcB]     = *(const ushort8*)pl;
            *(ushort8*)&sBl[srowB][skcB + 8] = *(const ushort8*)(pl + 8);
        }
        __syncthreads();
        const int arow = wr + (lane & 15);
        const int koff = (lane >> 4) * 8;
        short8v ah[4];
        #pragma unroll
        for (int fr = 0; fr < 4; ++fr)
            ah[fr] = *(const short8v*)&b1[arow + fr * 16][k0 + koff];
        #pragma unroll
        for (int fc = 0; fc < 4; ++fc) {
            int bcol = wc + fc * 16 + (lane & 15);
            short8v bh = *(const short8v*)&sBh[bcol][koff];
            short8v bl = *(const short8v*)&sBl[bcol][koff];
            #pragma unroll
            for (int fr = 0; fr < 4; ++fr) {
                acc[fr][fc] = __builtin_amdgcn_mfma_f32_16x16x32_bf16(ah[fr], bh, acc[fr][fc], 0, 0, 0);
                acc[fr][fc] = __builtin_amdgcn_mfma_f32_16x16x32_bf16(ah[fr], bl, acc[fr][fc], 0, 0, 0);
            }
        }
        __syncthreads();
    }

    // ---- epilogue: bias + gelu -> coalesced bf16 store ----
    #pragma unroll
    for (int fr = 0; fr < 4; ++fr) {
        int rbase = wr + fr * 16 + (lane >> 4) * 4;
        #pragma unroll
        for (int fc = 0; fc < 4; ++fc) {
            int col = wc + fc * 16 + (lane & 15);
            #pragma unroll
            for (int reg = 0; reg < 4; ++reg)
                sOut[rbase + reg][col] = f2b(gelu_f(acc[fr][fc][reg] + bnd[col]));
        }
    }
    __syncthreads();
    #pragma unroll
    for (int p = 0; p < 2; ++p) {
        int row = p * 64 + (t >> 3);
        int cch = (t & 7) * 16;
        int gr = r0 + row;
        if (gr < Mrows) {
            u16* gp = b2out + (size_t)gr * 256 + cch;
            *(ushort8*)gp       = *(ushort8*)&sOut[row][cch];
            *(ushort8*)(gp + 8) = *(ushort8*)&sOut[row][cch + 8];
        }
    }
}

// ---------------------------------------------------------------------------
// Fused vs-GEMM + LayerNorm, vnorm inline:
// h16 = bf16(LN(h16 + b2 + vnorm(vf)@Wvs) * gamma).  BM=128, 512 threads.
// ---------------------------------------------------------------------------
__global__ __launch_bounds__(512) void vs_ln_kernel(
    const u16* __restrict__ vf, const u16* __restrict__ BH,
    const u16* __restrict__ BL, const u16* __restrict__ b2,
    const float* __restrict__ gamma_l, u16* __restrict__ h16, int Mrows)
{
    __shared__ __align__(16) u16 sA [128][40];
    __shared__ __align__(16) u16 sBh[256][40];
    __shared__ __align__(16) u16 sBl[256][40];
    __shared__ float sSum[128][4];
    __shared__ float sSq [128][4];

    const int r0 = blockIdx.x * 128;
    const int t = threadIdx.x;
    const int lane = t & 63, wid = t >> 6;          // 8 waves
    const int wr = (wid >> 2) * 64, wc = (wid & 3) * 64;

    f32x4 acc[4][4] = {};
    const int K = 256;
    const int srow = t >> 2;          // 0..127
    const int skc  = (t & 3) * 8;     // 0,8,16,24

    for (int k0 = 0; k0 < K; k0 += 32) {
        {
            int gr = r0 + srow;
            ushort8 h0;
            #pragma unroll
            for (int j = 0; j < 8; ++j) h0[j] = 0;
            if (gr < Mrows) {
                const u16* base = vf + ((size_t)gr * 3) * 256 + k0 + skc;
                ushort8 v0 = *(const ushort8*)(base);
                ushort8 v1 = *(const ushort8*)(base + 256);
                ushort8 v2 = *(const ushort8*)(base + 512);
                #pragma unroll
                for (int j = 0; j < 8; ++j) {
                    float a = b2f(v0[j]), b = b2f(v1[j]), c = b2f(v2[j]);
                    h0[j] = f2b(sqrtf(a * a + b * b + c * c + 1e-8f));
                }
            }
            *(ushort8*)&sA[srow][skc] = h0;
        }
        {
            *(ushort8*)&sBh[srow][skc]       = *(const ushort8*)(BH + (size_t)srow * K + k0 + skc);
            *(ushort8*)&sBh[srow + 128][skc] = *(const ushort8*)(BH + (size_t)(srow + 128) * K + k0 + skc);
            *(ushort8*)&sBl[srow][skc]       = *(const ushort8*)(BL + (size_t)srow * K + k0 + skc);
            *(ushort8*)&sBl[srow + 128][skc] = *(const ushort8*)(BL + (size_t)(srow + 128) * K + k0 + skc);
        }
        __syncthreads();

        const int arow = wr + (lane & 15);
        const int koff = (lane >> 4) * 8;
        short8v ah[4];
        #pragma unroll
        for (int fr = 0; fr < 4; ++fr)
            ah[fr] = *(const short8v*)&sA[arow + fr * 16][koff];
        #pragma unroll
        for (int fc = 0; fc < 4; ++fc) {
            int bcol = wc + fc * 16 + (lane & 15);
            short8v bh = *(const short8v*)&sBh[bcol][koff];
            short8v bl = *(const short8v*)&sBl[bcol][koff];
            #pragma unroll
            for (int fr = 0; fr < 4; ++fr) {
                acc[fr][fc] = __builtin_amdgcn_mfma_f32_16x16x32_bf16(ah[fr], bh, acc[fr][fc], 0, 0, 0);
                acc[fr][fc] = __builtin_amdgcn_mfma_f32_16x16x32_bf16(ah[fr], bl, acc[fr][fc], 0, 0, 0);
            }
        }
        __syncthreads();
    }

    // epilogue: x = h_old + b2 + vsout; row stats, LN, write
    float psum[4][4] = {}, psq[4][4] = {};
    #pragma unroll
    for (int fr = 0; fr < 4; ++fr) {
        #pragma unroll
        for (int fc = 0; fc < 4; ++fc) {
            int col = wc + fc * 16 + (lane & 15);
            #pragma unroll
            for (int reg = 0; reg < 4; ++reg) {
                int gr = r0 + wr + fr * 16 + (lane >> 4) * 4 + reg;
                float x = 0.f;
                if (gr < Mrows) {
                    size_t ix = (size_t)gr * 256 + col;
                    x = acc[fr][fc][reg] + b2f(b2[ix]) + b2f(h16[ix]);
                }
                acc[fr][fc][reg] = x;
                psum[fr][reg] += x;
                psq[fr][reg]  = fmaf(x, x, psq[fr][reg]);
            }
        }
    }
    #pragma unroll
    for (int fr = 0; fr < 4; ++fr) {
        #pragma unroll
        for (int reg = 0; reg < 4; ++reg) {
            float s = psum[fr][reg], sq = psq[fr][reg];
            #pragma unroll
            for (int off = 8; off; off >>= 1) {
                s  += __shfl_xor(s, off);
                sq += __shfl_xor(sq, off);
            }
            psum[fr][reg] = s; psq[fr][reg] = sq;
        }
    }
    if ((lane & 15) == 0) {
        int qg = lane >> 4;
        #pragma unroll
        for (int fr = 0; fr < 4; ++fr) {
            #pragma unroll
            for (int reg = 0; reg < 4; ++reg) {
                int row = wr + fr * 16 + qg * 4 + reg;
                sSum[row][wc >> 6] = psum[fr][reg];
                sSq [row][wc >> 6] = psq[fr][reg];
            }
        }
    }
    __syncthreads();
    #pragma unroll
    for (int fr = 0; fr < 4; ++fr) {
        #pragma unroll
        for (int reg = 0; reg < 4; ++reg) {
            int row = wr + fr * 16 + (lane >> 4) * 4 + reg;
            int gr = r0 + row;
            if (gr >= Mrows) continue;
            float S = sSum[row][0] + sSum[row][1] + sSum[row][2] + sSum[row][3];
            float Q = sSq[row][0] + sSq[row][1] + sSq[row][2] + sSq[row][3];
            float mu = S * (1.0f / 256.0f);
            float var = fmaxf(Q * (1.0f / 256.0f) - mu * mu, 0.0f);
            float rs = rsqrtf(var + 1e-5f);
            #pragma unroll
            for (int fc = 0; fc < 4; ++fc) {
                int col = wc + fc * 16 + (lane & 15);
                float y = (acc[fr][fc][reg] - mu) * rs * gamma_l[col];
                h16[(size_t)gr * 256 + col] = f2b(y);
            }
        }
    }
}

// ---------------------------------------------------------------------------
// Setup: per-edge degree hist + geometry, per-node graph hist (one kernel)
// ---------------------------------------------------------------------------
__global__ __launch_bounds__(256) void setup_edges(
    const int* __restrict__ ei, const int* __restrict__ batch,
    const float* __restrict__ pos, int E_, int Nn,
    int* __restrict__ deg, int* __restrict__ gcnt, float4* __restrict__ eg)
{
    int x = blockIdx.x * 256 + threadIdx.x;
    if (x < E_) {
        int s = ei[x], dn = ei[E_ + x];
        atomicAdd(&deg[dn], 1);
        float dx = pos[s * 3 + 0] - pos[dn * 3 + 0];
        float dy = pos[s * 3 + 1] - pos[dn * 3 + 1];
        float dz = pos[s * 3 + 2] - pos[dn * 3 + 2];
        float d = sqrtf(dx * dx + dy * dy + dz * dz + 1e-12f);
        float invd = 1.0f / d;
        eg[x] = make_float4(dx * invd, dy * invd, dz * invd, d);
    }
    if (x < Nn) atomicAdd(&gcnt[batch[x]], 1);
}

// two scans in one launch: block 0 -> (cntA,nA), block 1 -> (cntB,nB)
__global__ __launch_bounds__(1024) void scan2_kernel(
    const int* __restrict__ cntA, int nA, int* __restrict__ outA, int* __restrict__ curA,
    const int* __restrict__ cntB, int nB, int* __restrict__ outB)
{
    __shared__ int part[1024];
    const int* cnt = (blockIdx.x == 0) ? cntA : cntB;
    int n          = (blockIdx.x == 0) ? nA : nB;
    int* out       = (blockIdx.x == 0) ? outA : outB;
    int* cursor    = (blockIdx.x == 0) ? curA : (int*)nullptr;
    int t = threadIdx.x;
    int chunk = (n + 1023) / 1024;
    int base = t * chunk;
    int s = 0;
    for (int k = 0; k < chunk; ++k) { int i = base + k; if (i < n) s += cnt[i]; }
    part[t] = s;
    __syncthreads();
    for (int off = 1; off < 1024; off <<= 1) {
        int u = (t >= off) ? part[t - off] : 0;
        __syncthreads();
        part[t] += u;
        __syncthreads();
    }
    int run = part[t] - s;
    for (int k = 0; k < chunk; ++k) {
        int i = base + k;
        if (i < n) {
            out[i] = run;
            if (cursor) cursor[i] = run;
            run += cnt[i];
        }
    }
    if (t == 1023) out[n] = part[1023];
}

// perm payload: (edge id, src node)
__global__ void scatter_kernel(const int* __restrict__ ei, int* __restrict__ cursor,
                               int2* __restrict__ perm2, int E_) {
    int e = blockIdx.x * 256 + threadIdx.x;
    if (e < E_) {
        int p = atomicAdd(&cursor[ei[E_ + e]], 1);
        perm2[p] = make_int2(e, ei[e]);
    }
}

// ---------------------------------------------------------------------------
// h init -> bf16
// ---------------------------------------------------------------------------
__global__ __launch_bounds__(256) void init_h_kernel(
    const int* __restrict__ z, const float* __restrict__ pos,
    const float* __restrict__ emb, const float* __restrict__ W_in,
    const float* __restrict__ b_in, u16* __restrict__ h16)
{
    int i = blockIdx.x, d = threadIdx.x;
    float acc = b_in[d];
    int zi = z[i];
    #pragma unroll 8
    for (int k = 0; k < 32; ++k)
        acc += emb[zi * 32 + k] * W_in[k * 256 + d];
    #pragma unroll
    for (int x = 0; x < 3; ++x)
        acc += pos[i * 3 + x] * W_in[(32 + x) * 256 + d];
    h16[(size_t)i * 256 + d] = f2b(acc);
}

// ---------------------------------------------------------------------------
// Per-dst-node edge attention, online softmax, 8 edges/iter.
// ---------------------------------------------------------------------------
__global__ __launch_bounds__(128) void edge_attn_kernel(
    const int* __restrict__ rowptr, const int2* __restrict__ perm2,
    const u16* __restrict__ q16, const u16* __restrict__ kv8,
    const float4* __restrict__ eg, const float* __restrict__ table_l,
    u16* __restrict__ msg, u16* __restrict__ U)
{
    int m = threadIdx.x;
    int i = blockIdx.x;

    int p0 = rowptr[i], p1 = rowptr[i + 1];
    float q = b2f(q16[(size_t)i * 128 + m]);
    float Mx = -1e30f, S = 0.f, am = 0.f, a0 = 0.f, a1 = 0.f, a2 = 0.f;
    const float iscale = 0.1767766952966369f;   // 1/sqrt(32)

    for (int p = p0; p < p1; p += 8) {
        int rem = p1 - p;
        int ee[8], jj[8];
        #pragma unroll
        for (int u = 0; u < 8; ++u) {
            int pp = p + (u < rem ? u : 0);
            int2 pe = perm2[pp];
            ee[u] = __builtin_amdgcn_readfirstlane(pe.x);
            jj[u] = __builtin_amdgcn_readfirstlane(pe.y);
        }
        u32 kv[8];
        float4 g[8];
        #pragma unroll
        for (int u = 0; u < 8; ++u) {
            kv[u] = kv8[(size_t)jj[u] * 128 + m];
            g[u]  = eg[ee[u]];
        }
        float lg[8], vd[8];
        #pragma unroll
        for (int u = 0; u < 8; ++u) {
            f32x2 c = kvdec(kv[u]);
            vd[u] = c[1];
            float pr = q * c[0];
            #pragma unroll
            for (int off = 16; off; off >>= 1) pr += __shfl_xor(pr, off);
            lg[u] = pr * iscale;
        }
        float ew[8];
        #pragma unroll
        for (int u = 0; u < 8; ++u) {
            float x = fminf(g[u].w * (4096.0f / 6.0f), 4096.0f);
            int b = (int)x;
            float tf = x - (float)b;
            float f0 = table_l[(size_t)b * 128 + m];
            float f1 = table_l[(size_t)(b + 1) * 128 + m];
            ew[u] = fmaf(tf, f1 - f0, f0);
        }
        float Mb = Mx;
        #pragma unroll
        for (int u = 0; u < 8; ++u) Mb = fmaxf(Mb, lg[u]);
        float sc = __expf(Mx - Mb);
        float w[8];
        #pragma unroll
        for (int u = 0; u < 8; ++u)
            w[u] = (u < rem) ? __expf(lg[u] - Mb) : 0.f;
        float ws = 0.f, wvs = 0.f, wx = 0.f, wy = 0.f, wz = 0.f;
        #pragma unroll
        for (int u = 0; u < 8; ++u) {
            float wv = w[u] * vd[u] * ew[u];
            ws  += w[u];
            wvs += wv;
            wx = fmaf(wv, g[u].x, wx);
            wy = fmaf(wv, g[u].y, wy);
            wz = fmaf(wv, g[u].z, wz);
        }
        S  = S  * sc + ws;
        am = am * sc + wvs;
        a0 = a0 * sc + wx;
        a1 = a1 * sc + wy;
        a2 = a2 * sc + wz;
        Mx = Mb;
    }
    float inv = 1.0f / (S + 1e-12f);
    msg[(size_t)i * 128 + m] = f2b(am * inv);
    U[((size_t)i * 3 + 0) * 128 + m] = f2b(a0 * inv);
    U[((size_t)i * 3 + 1) * 128 + m] = f2b(a1 * inv);
    U[((size_t)i * 3 + 2) * 128 + m] = f2b(a2 * inv);
}

// ---------------------------------------------------------------------------
// Graph pooling, wave-parallel (block = graph)
// ---------------------------------------------------------------------------
__global__ __launch_bounds__(256) void pool_kernel(
    const u16* __restrict__ h16, const float* __restrict__ w_att,
    const int* __restrict__ gptr, u16* __restrict__ pooled)
{
    __shared__ float sM[4], sS[4];
    __shared__ float sAcc[4][256];
    int g = blockIdx.x;
    int t = threadIdx.x, w = t >> 6, lane = t & 63;
    int c0 = lane * 4;
    int n0 = gptr[g], n1 = gptr[g + 1];
    float4 wa = *(const float4*)(w_att + c0);
    float M = -1e30f, S = 0.f, a0 = 0.f, a1 = 0.f, a2 = 0.f, a3 = 0.f;
    for (int i = n0 + w; i < n1; i += 4) {
        ushort4v hv = *(const ushort4v*)(h16 + (size_t)i * 256 + c0);
        float h0 = b2f(hv[0]), h1 = b2f(hv[1]), h2 = b2f(hv[2]), h3 = b2f(hv[3]);
        float p = h0 * wa.x + h1 * wa.y + h2 * wa.z + h3 * wa.w;
        #pragma unroll
        for (int off = 32; off; off >>= 1) p += __shfl_xor(p, off);
        float nM = fmaxf(M, p);
        float sc = __expf(M - nM), wg = __expf(p - nM);
        S = S * sc + wg;
        a0 = a0 * sc + wg * h0;
        a1 = a1 * sc + wg * h1;
        a2 = a2 * sc + wg * h2;
        a3 = a3 * sc + wg * h3;
        M = nM;
    }
    sAcc[w][c0 + 0] = a0; sAcc[w][c0 + 1] = a1;
    sAcc[w][c0 + 2] = a2; sAcc[w][c0 + 3] = a3;
    if (lane == 0) { sM[w] = M; sS[w] = S; }
    __syncthreads();
    if (w == 0) {
        float Mg = fmaxf(fmaxf(sM[0], sM[1]), fmaxf(sM[2], sM[3]));
        float e0 = __expf(sM[0] - Mg), e1 = __expf(sM[1] - Mg);
        float e2 = __expf(sM[2] - Mg), e3 = __expf(sM[3] - Mg);
        float St = sS[0] * e0 + sS[1] * e1 + sS[2] * e2 + sS[3] * e3;
        float inv = 1.0f / (St + 1e-12f);
        #pragma unroll
        for (int c = 0; c < 4; ++c) {
            float v = sAcc[0][c0 + c] * e0 + sAcc[1][c0 + c] * e1
                    + sAcc[2][c0 + c] * e2 + sAcc[3][c0 + c] * e3;
            pooled[(size_t)g * 256 + c0 + c] = f2b(v * inv);
        }
    }
}

// ---------------------------------------------------------------------------
extern "C" void kernel_launch(void* const* d_in, const int* in_sizes, int n_in,
                              void* d_out, int out_size, void* d_ws, size_t ws_size,
                              hipStream_t stream)
{
    const float* pos   = (const float*)d_in[0];
    const int*   z     = (const int*)d_in[1];
    const int*   batch = (const int*)d_in[2];
    const int*   ei    = (const int*)d_in[3];
    const float* emb   = (const float*)d_in[4];
    const float* W_in  = (const float*)d_in[5];
    const float* b_in  = (const float*)d_in[6];
    const float* Wq    = (const float*)d_in[7];
    const float* Wk    = (const float*)d_in[8];
    const float* Wv    = (const float*)d_in[9];
    const float* W_rbf = (const float*)d_in[10];
    const float* W_msg = (const float*)d_in[11];
    const float* W_vg  = (const float*)d_in[12];
    const float* W_vs  = (const float*)d_in[13];
    const float* W_nd  = (const float*)d_in[14];
    const float* b_nd  = (const float*)d_in[15];
    const float* gam   = (const float*)d_in[16];
    const float* watt  = (const float*)d_in[17];
    const float* W_out = (const float*)d_in[18];
    const float* b_out = (const float*)d_in[19];

    const int N = in_sizes[0] / 3;      // 20000
    const int E = in_sizes[3] / 2;      // 320000
    const int G = out_size / 512;       // 500

    char* ws = (char*)d_ws;
    size_t o = 0;
    auto alloc = [&](size_t bytes) -> char* {
        o = (o + 255) & ~(size_t)255;
        char* r = ws + o;
        o += bytes;
        return r;
    };
    float4* f_eg   = (float4*)alloc((size_t)E * 16);
    u16*   h16     = (u16*)  alloc((size_t)N * 256 * 2);
    u16*   vf16    = (u16*)  alloc((size_t)N * 3 * 256 * 2);
    u16*   q16     = (u16*)  alloc((size_t)N * 128 * 2);
    u16*   kv8     = (u16*)  alloc((size_t)N * 128 * 2);
    u16*   umb     = (u16*)  alloc((size_t)N * 4 * 128 * 2);
    u16*   b2_16   = (u16*)  alloc((size_t)N * 256 * 2);
    u16*   pool16  = (u16*)  alloc((size_t)G * 256 * 2);
    float* f_table = (float*)alloc((size_t)4 * 4098 * 128 * 4);
    const size_t LS = 384 * 256 + 2 * (256 * 128) + 2 * (256 * 256);
    const size_t OFF_QKV = 0, OFF_VG = 384 * 256, OFF_MSG = OFF_VG + 256 * 128,
                 OFF_ND = OFF_MSG + 256 * 128, OFF_VS = OFF_ND + 256 * 256;
    const size_t OFF_OUT = LS * 4;
    u16* whi = (u16*)alloc((LS * 4 + 512 * 256) * sizeof(u16));
    u16* wlo = (u16*)alloc((LS * 4 + 512 * 256) * sizeof(u16));
    int*  i_deg   = (int*)alloc((size_t)N * 4);
    int*  i_rowp  = (int*)alloc((size_t)(N + 1) * 4);
    int*  i_cur   = (int*)alloc((size_t)(N + 1) * 4);
    int2* i_perm2 = (int2*)alloc((size_t)E * 8);
    int*  i_gcnt  = (int*)alloc((size_t)G * 4);
    int*  i_gptr  = (int*)alloc((size_t)(G + 1) * 4);

    u16* U16   = umb;                         // [3N,128]
    u16* msg16 = umb + (size_t)3 * N * 128;   // [N,128]

    // ---- weight pre-pass descriptor ----
    TDesc td;
    int idx = 0;
    for (int l = 0; l < 4; ++l) {
        u16* bh = whi + (size_t)l * LS;
        u16* bl = wlo + (size_t)l * LS;
        td.e[idx++] = { Wq   + (size_t)l * 256 * 128, bh + OFF_QKV,             bl + OFF_QKV,             256, 128 };
        td.e[idx++] = { Wk   + (size_t)l * 256 * 128, bh + OFF_QKV + 128 * 256, bl + OFF_QKV + 128 * 256, 256, 128 };
        td.e[idx++] = { Wv   + (size_t)l * 256 * 128, bh + OFF_QKV + 256 * 256, bl + OFF_QKV + 256 * 256, 256, 128 };
        td.e[idx++] = { W_vg + (size_t)l * 128 * 256, bh + OFF_VG,  bl + OFF_VG,  128, 256 };
        td.e[idx++] = { W_msg+ (size_t)l * 128 * 256, bh + OFF_MSG, bl + OFF_MSG, 128, 256 };
        td.e[idx++] = { W_nd + (size_t)l * 256 * 256, bh + OFF_ND,  bl + OFF_ND,  256, 256 };
        td.e[idx++] = { W_vs + (size_t)l * 256 * 256, bh + OFF_VS,  bl + OFF_VS,  256, 256 };
    }
    td.e[idx++] = { W_out, whi + OFF_OUT, wlo + OFF_OUT, 256, 512 };

    // ---- setup ----
    zero2_i32<<<(N + G + 255) / 256, 256, 0, stream>>>(i_deg, N, i_gcnt, G);
    transpose_split<<<dim3(128, 29), 256, 0, stream>>>(td);
    build_rbf_table<<<dim3(4098, 4), 128, 0, stream>>>(W_rbf, f_table);

    setup_edges<<<(E + 255) / 256, 256, 0, stream>>>(ei, batch, pos, E, N,
                                                     i_deg, i_gcnt, f_eg);
    scan2_kernel<<<2, 1024, 0, stream>>>(i_deg, N, i_rowp, i_cur, i_gcnt, G, i_gptr);
    scatter_kernel<<<(E + 255) / 256, 256, 0, stream>>>(ei, i_cur, i_perm2, E);
    init_h_kernel<<<N, 256, 0, stream>>>(z, pos, emb, W_in, b_in, h16);

    const int MB  = (N + 127) / 128;          // 157
    const int MB3 = (3 * N + 127) / 128;      // 469
    const int MBG = (G + 127) / 128;          // 4

    // ---- layers ----
    for (int l = 0; l < 4; ++l) {
        u16* bh = whi + (size_t)l * LS;
        u16* bl = wlo + (size_t)l * LS;
        const float* bnd_l = b_nd + (size_t)l * 256;
        const float* gam_l = gam  + (size_t)l * 256;
        const float* tbl_l = f_table + (size_t)l * 4098 * 128;

        // q16/kv8 = h @ [Wq|Wk|Wv]
        mfma_gemm<3,false,false,false,false><<<3 * MB, 256, 0, stream>>>(
            h16, bh + OFF_QKV, nullptr, nullptr, q16, kv8, N, 256, 384, 3);

        edge_attn_kernel<<<N, 128, 0, stream>>>(i_rowp, i_perm2, q16, kv8,
                                                f_eg, tbl_l, msg16, U16);

        // vfeat (+)= U @ W_vgate   (staged coalesced epilogue)
        if (l == 0)
            mfma_gemm<1,false,false,false,false><<<2 * MB3, 256, 0, stream>>>(
                U16, bh + OFF_VG, nullptr, nullptr, vf16, nullptr, 3 * N, 128, 256, 2);
        else
            mfma_gemm<2,false,false,false,false><<<2 * MB3, 256, 0, stream>>>(
                U16, bh + OFF_VG, nullptr, nullptr, vf16, nullptr, 3 * N, 128, 256, 2);

        // b2 = gelu(gelu(msg@Wmsg) @ Wnd + bnd)   (fused MLP, b1 in LDS)
        mlp_kernel<<<MB, 512, 0, stream>>>(
            msg16, bh + OFF_MSG, bh + OFF_ND, bl + OFF_ND, bnd_l, b2_16, N);

        // h16 = LN(h16 + b2 + vnorm(vf)@Wvs) * gamma   (fused, inline vnorm)
        vs_ln_kernel<<<MB, 512, 0, stream>>>(
            vf16, bh + OFF_VS, bl + OFF_VS, b2_16, gam_l, h16, N);
    }

    // ---- readout ----
    pool_kernel<<<G, 256, 0, stream>>>(h16, watt, i_gptr, pool16);
    mfma_gemm<0,false,true,false,true><<<4 * MBG, 256, 0, stream>>>(
        pool16, whi + OFF_OUT, wlo + OFF_OUT, b_out, (float*)d_out, nullptr, G, 256, 512, 4);
}